// Round 1
// baseline (2757.011 us; speedup 1.0000x reference)
//
#include <hip/hip_runtime.h>
#include <cstddef>

#define NB 4
#define SEQL 2048
#define DMODEL 768
#define DSTATE 128
#define HEADDIM 64
#define NHEADS 24
#define DINNER 1536
#define CONVDIM 1792
#define DINPROJ 3352
#define BLROWS (NB*SEQL)
#define RMS_EPS 1e-5f

__device__ __forceinline__ float sigmoidf_(float x){ return 1.f/(1.f+expf(-x)); }
__device__ __forceinline__ float siluf_(float x){ return x * sigmoidf_(x); }
__device__ __forceinline__ float softplusf_(float x){ return x > 20.f ? x : log1pf(expf(x)); }

// C[M,N] = A[M,K] @ W[N,K]^T, optional epilogue scale sigmoid(*gptr).
// 128x128 tile, BK=16, 256 threads, 8x8 per thread (split 4+4 to keep LDS reads 2-way max).
__global__ __launch_bounds__(256) void gemm_atb(
    const float* __restrict__ A, const float* __restrict__ W,
    float* __restrict__ C, int M, int N, int K, const float* __restrict__ gptr)
{
    __shared__ __align__(16) float As[16][128];
    __shared__ __align__(16) float Ws[16][128];
    const int tid = threadIdx.x;
    const int tx = tid & 15, ty = tid >> 4;
    const int m0 = blockIdx.y * 128, n0 = blockIdx.x * 128;
    const int lr = tid >> 1;          // 0..127 row to stage
    const int lk = (tid & 1) * 8;     // k offset 0 or 8
    const float* Ap = A + (size_t)(m0 + lr) * K + lk;
    const bool wv = (n0 + lr) < N;
    const float* Wp = W + (size_t)(wv ? (n0 + lr) : 0) * K + lk;

    float acc[8][8];
#pragma unroll
    for (int i = 0; i < 8; ++i)
#pragma unroll
        for (int j = 0; j < 8; ++j) acc[i][j] = 0.f;

    for (int kt = 0; kt < K; kt += 16) {
        float4 a0 = *(const float4*)(Ap + kt);
        float4 a1 = *(const float4*)(Ap + kt + 4);
        float4 w0 = make_float4(0.f,0.f,0.f,0.f), w1 = make_float4(0.f,0.f,0.f,0.f);
        if (wv) { w0 = *(const float4*)(Wp + kt); w1 = *(const float4*)(Wp + kt + 4); }
        __syncthreads();
        As[lk+0][lr]=a0.x; As[lk+1][lr]=a0.y; As[lk+2][lr]=a0.z; As[lk+3][lr]=a0.w;
        As[lk+4][lr]=a1.x; As[lk+5][lr]=a1.y; As[lk+6][lr]=a1.z; As[lk+7][lr]=a1.w;
        Ws[lk+0][lr]=w0.x; Ws[lk+1][lr]=w0.y; Ws[lk+2][lr]=w0.z; Ws[lk+3][lr]=w0.w;
        Ws[lk+4][lr]=w1.x; Ws[lk+5][lr]=w1.y; Ws[lk+6][lr]=w1.z; Ws[lk+7][lr]=w1.w;
        __syncthreads();
#pragma unroll
        for (int kk = 0; kk < 16; ++kk) {
            const float4 va0 = *(const float4*)&As[kk][tx*4];
            const float4 va1 = *(const float4*)&As[kk][64 + tx*4];
            const float4 vb0 = *(const float4*)&Ws[kk][ty*4];
            const float4 vb1 = *(const float4*)&Ws[kk][64 + ty*4];
            const float av[8] = {va0.x,va0.y,va0.z,va0.w,va1.x,va1.y,va1.z,va1.w};
            const float bv[8] = {vb0.x,vb0.y,vb0.z,vb0.w,vb1.x,vb1.y,vb1.z,vb1.w};
#pragma unroll
            for (int i = 0; i < 8; ++i)
#pragma unroll
                for (int j = 0; j < 8; ++j)
                    acc[i][j] = fmaf(av[i], bv[j], acc[i][j]);
        }
    }
    float scale = 1.f;
    if (gptr) scale = sigmoidf_(*gptr);
#pragma unroll
    for (int i = 0; i < 8; ++i) {
        const int m = m0 + ((i < 4) ? (tx*4 + i) : (64 + tx*4 + (i - 4)));
        float* crow = C + (size_t)m * N;
        const int nA = n0 + ty*4;
        const int nB = n0 + 64 + ty*4;
        if (nA + 4 <= N) {
            float4 o = make_float4(acc[i][0]*scale, acc[i][1]*scale, acc[i][2]*scale, acc[i][3]*scale);
            *(float4*)(crow + nA) = o;
        }
        if (nB + 4 <= N) {
            float4 o = make_float4(acc[i][4]*scale, acc[i][5]*scale, acc[i][6]*scale, acc[i][7]*scale);
            *(float4*)(crow + nB) = o;
        }
    }
}

// causal depthwise conv1d (k=4, left pad 3) + bias + silu over xBC part of zxbcdt
__global__ __launch_bounds__(448) void conv_kernel(
    const float* __restrict__ zxbcdt, const float* __restrict__ conv_w,
    const float* __restrict__ conv_b, float* __restrict__ xconv)
{
    const int c4 = threadIdx.x;          // 0..447 (float4 over 1792 channels)
    const int bl = blockIdx.x;           // 0..8191
    const int l = bl & (SEQL - 1);
    float w[4][4];
#pragma unroll
    for (int j = 0; j < 4; ++j) {
        float4 wr = *(const float4*)(conv_w + (c4*4 + j)*4);
        w[j][0]=wr.x; w[j][1]=wr.y; w[j][2]=wr.z; w[j][3]=wr.w;
    }
    float4 bias = *(const float4*)(conv_b + c4*4);
    float s[4] = {bias.x, bias.y, bias.z, bias.w};
#pragma unroll
    for (int k = 0; k < 4; ++k) {
        const int ls = l - 3 + k;
        if (ls >= 0) {
            const float4 xv = *(const float4*)(zxbcdt + (size_t)(bl - 3 + k)*DINPROJ + DINNER + c4*4);
            s[0] = fmaf(xv.x, w[0][k], s[0]);
            s[1] = fmaf(xv.y, w[1][k], s[1]);
            s[2] = fmaf(xv.z, w[2][k], s[2]);
            s[3] = fmaf(xv.w, w[3][k], s[3]);
        }
    }
    float4 o = make_float4(siluf_(s[0]), siluf_(s[1]), siluf_(s[2]), siluf_(s[3]));
    *(float4*)(xconv + (size_t)bl*CONVDIM + c4*4) = o;
}

// dt = softplus(dt_raw + bias), dA = exp(dt * -exp(A_log))
__global__ __launch_bounds__(256) void dt_kernel(
    const float* __restrict__ zxbcdt, const float* __restrict__ dt_bias,
    const float* __restrict__ A_log, float* __restrict__ dtp, float* __restrict__ dAv)
{
    const int idx = blockIdx.x * 256 + threadIdx.x;     // exactly BLROWS*NHEADS
    const int bl = idx / NHEADS, h = idx % NHEADS;
    float x = zxbcdt[(size_t)bl*DINPROJ + DINNER + CONVDIM + h] + dt_bias[h];
    float d = softplusf_(x);
    dtp[idx] = d;
    dAv[idx] = expf(-expf(A_log[h]) * d);
}

// sequential SSM scan: one block per (b,h); state 64x128 in registers (thread tile 4p x 8n)
__global__ __launch_bounds__(256) void scan_kernel(
    const float* __restrict__ xconv, const float* __restrict__ dtp,
    const float* __restrict__ dAv, const float* __restrict__ Dv,
    float* __restrict__ ybuf)
{
    const int h = blockIdx.x, b = blockIdx.y;
    const int tid = threadIdx.x;
    const int c = tid & 15, pg = tid >> 4;
    const int n0 = c * 8, p0 = pg * 4;
    __shared__ __align__(16) float sx[HEADDIM];
    __shared__ __align__(16) float sB[DSTATE];
    __shared__ __align__(16) float sC[DSTATE];
    __shared__ float sM[2];
    float hreg[4][8];
#pragma unroll
    for (int i = 0; i < 4; ++i)
#pragma unroll
        for (int j = 0; j < 8; ++j) hreg[i][j] = 0.f;
    const float Dh = Dv[h];

    float4 pf = make_float4(0.f,0.f,0.f,0.f);
    float pfs = 0.f;
    auto issue = [&](int t) {
        const size_t rb = (size_t)(b*SEQL + t) * CONVDIM;
        if (tid < 16)       pf = *(const float4*)(xconv + rb + h*HEADDIM + tid*4);
        else if (tid < 48)  pf = *(const float4*)(xconv + rb + DINNER + (tid-16)*4);
        else if (tid < 80)  pf = *(const float4*)(xconv + rb + DINNER + DSTATE + (tid-48)*4);
        else if (tid == 80) pfs = dtp[(size_t)(b*SEQL + t)*NHEADS + h];
        else if (tid == 81) pfs = dAv[(size_t)(b*SEQL + t)*NHEADS + h];
    };
    issue(0);

    for (int t = 0; t < SEQL; ++t) {
        if (tid < 16)       *(float4*)(sx + tid*4) = pf;
        else if (tid < 48)  *(float4*)(sB + (tid-16)*4) = pf;
        else if (tid < 80)  *(float4*)(sC + (tid-48)*4) = pf;
        else if (tid == 80) sM[0] = pfs;
        else if (tid == 81) sM[1] = pfs;
        __syncthreads();
        if (t + 1 < SEQL) issue(t + 1);   // prefetch overlaps compute

        const float dtv = sM[0], dAt = sM[1];
        float Bv[8], Cv[8];
#pragma unroll
        for (int j = 0; j < 8; ++j) { Bv[j] = sB[n0+j]; Cv[j] = sC[n0+j]; }
        float yp[4];
#pragma unroll
        for (int i = 0; i < 4; ++i) {
            const float xs = dtv * sx[p0 + i];
            float acc = 0.f;
#pragma unroll
            for (int j = 0; j < 8; ++j) {
                hreg[i][j] = fmaf(hreg[i][j], dAt, xs * Bv[j]);
                acc = fmaf(hreg[i][j], Cv[j], acc);
            }
            yp[i] = acc;
        }
#pragma unroll
        for (int off = 1; off < 16; off <<= 1) {
#pragma unroll
            for (int i = 0; i < 4; ++i) yp[i] += __shfl_xor(yp[i], off);
        }
        if (c == 0) {
            float4 o = make_float4(yp[0] + Dh*sx[p0+0], yp[1] + Dh*sx[p0+1],
                                   yp[2] + Dh*sx[p0+2], yp[3] + Dh*sx[p0+3]);
            *(float4*)(ybuf + (size_t)(b*SEQL + t)*DINNER + h*HEADDIM + p0) = o;
        }
        __syncthreads();
    }
}

// y = y * silu(z); y = y * rsqrt(mean(y^2)+eps) * norm_w   (in place on ybuf)
__global__ __launch_bounds__(128) void rms_kernel(
    const float* __restrict__ zxbcdt, const float* __restrict__ norm_w,
    float* __restrict__ ybuf)
{
    const int row = blockIdx.x;
    const int tid = threadIdx.x;
    const float* zr = zxbcdt + (size_t)row * DINPROJ;
    float* yr = ybuf + (size_t)row * DINNER;
    float v[12];
    float ss = 0.f;
#pragma unroll
    for (int i = 0; i < 3; ++i) {
        const int o = (tid + i*128) * 4;
        float4 yv = *(const float4*)(yr + o);
        float4 zv = *(const float4*)(zr + o);
        float a = yv.x * siluf_(zv.x);
        float b = yv.y * siluf_(zv.y);
        float cc = yv.z * siluf_(zv.z);
        float d = yv.w * siluf_(zv.w);
        v[i*4+0]=a; v[i*4+1]=b; v[i*4+2]=cc; v[i*4+3]=d;
        ss += a*a + b*b + cc*cc + d*d;
    }
#pragma unroll
    for (int off = 1; off < 64; off <<= 1) ss += __shfl_xor(ss, off);
    __shared__ float red[2];
    if ((tid & 63) == 0) red[tid >> 6] = ss;
    __syncthreads();
    const float rstd = rsqrtf((red[0] + red[1]) * (1.f/DINNER) + RMS_EPS);
#pragma unroll
    for (int i = 0; i < 3; ++i) {
        const int o = (tid + i*128) * 4;
        float4 wv = *(const float4*)(norm_w + o);
        float4 ov = make_float4(v[i*4+0]*rstd*wv.x, v[i*4+1]*rstd*wv.y,
                                v[i*4+2]*rstd*wv.z, v[i*4+3]*rstd*wv.w);
        *(float4*)(yr + o) = ov;
    }
}

extern "C" void kernel_launch(void* const* d_in, const int* in_sizes, int n_in,
                              void* d_out, int out_size, void* d_ws, size_t ws_size,
                              hipStream_t stream)
{
    const float* feature    = (const float*)d_in[0];
    const float* in_proj_w  = (const float*)d_in[1];
    const float* conv_w     = (const float*)d_in[2];
    const float* conv_b     = (const float*)d_in[3];
    const float* dt_bias    = (const float*)d_in[4];
    const float* A_log      = (const float*)d_in[5];
    const float* Dvec       = (const float*)d_in[6];
    const float* norm_w     = (const float*)d_in[7];
    const float* out_proj_w = (const float*)d_in[8];
    const float* gate1      = (const float*)d_in[9];
    float* out = (float*)d_out;

    float* zxbcdt = (float*)d_ws;                               // [8192,3352]
    float* xconv  = zxbcdt + (size_t)BLROWS * DINPROJ;          // [8192,1792]
    float* dtp    = xconv  + (size_t)BLROWS * CONVDIM;          // [8192,24]
    float* dAv    = dtp    + (size_t)BLROWS * NHEADS;           // [8192,24]
    float* ybuf   = dAv    + (size_t)BLROWS * NHEADS;           // [8192,1536]

    // 1) in_proj: zxbcdt = feature @ in_proj_w^T
    gemm_atb<<<dim3(27, 64), 256, 0, stream>>>(feature, in_proj_w, zxbcdt,
                                               BLROWS, DINPROJ, DMODEL, nullptr);
    // 2) causal depthwise conv + silu on xBC
    conv_kernel<<<dim3(BLROWS), 448, 0, stream>>>(zxbcdt, conv_w, conv_b, xconv);
    // 3) dt softplus + dA
    dt_kernel<<<dim3(768), 256, 0, stream>>>(zxbcdt, dt_bias, A_log, dtp, dAv);
    // 4) sequential SSM scan (+ D*x)
    scan_kernel<<<dim3(NHEADS, NB), 256, 0, stream>>>(xconv, dtp, dAv, Dvec, ybuf);
    // 5) gated RMSNorm (in place)
    rms_kernel<<<dim3(BLROWS), 128, 0, stream>>>(zxbcdt, norm_w, ybuf);
    // 6) out_proj + sigmoid(gate1) scale
    gemm_atb<<<dim3(6, 64), 256, 0, stream>>>(ybuf, out_proj_w, out,
                                              BLROWS, DMODEL, DINNER, gate1);
}

// Round 2
// 1125.610 us; speedup vs baseline: 2.4493x; 2.4493x over previous
//
#include <hip/hip_runtime.h>
#include <cstddef>

#define NB 4
#define SEQL 2048
#define DMODEL 768
#define DSTATE 128
#define HEADDIM 64
#define NHEADS 24
#define DINNER 1536
#define CONVDIM 1792
#define DINPROJ 3352
#define BLROWS (NB*SEQL)
#define RMS_EPS 1e-5f
#define Q 128
#define NC (SEQL/Q)

typedef unsigned int uint;
typedef unsigned short ushort;

__device__ __forceinline__ float sigmoidf_(float x){ return 1.f/(1.f+expf(-x)); }
__device__ __forceinline__ float siluf_(float x){ return x * sigmoidf_(x); }
__device__ __forceinline__ float softplusf_(float x){ return x > 20.f ? x : log1pf(expf(x)); }

__device__ __forceinline__ ushort f2bf(float f){
    union { float f; uint u; } v; v.f = f;
    uint r = (v.u + 0x7FFFu + ((v.u >> 16) & 1u)) >> 16;
    return (ushort)r;
}
__device__ __forceinline__ float bf2f(ushort s){
    union { uint u; float f; } v; v.u = ((uint)s) << 16;
    return v.f;
}
__device__ __forceinline__ uint pack2(float a, float b){
    return (uint)f2bf(a) | ((uint)f2bf(b) << 16);
}
__device__ __forceinline__ void unpack8(uint4 r, float* o){
    o[0]=bf2f((ushort)(r.x&0xffff)); o[1]=bf2f((ushort)(r.x>>16));
    o[2]=bf2f((ushort)(r.y&0xffff)); o[3]=bf2f((ushort)(r.y>>16));
    o[4]=bf2f((ushort)(r.z&0xffff)); o[5]=bf2f((ushort)(r.z>>16));
    o[6]=bf2f((ushort)(r.w&0xffff)); o[7]=bf2f((ushort)(r.w>>16));
}

// ---------------- GEMM: C[M,N] = A[M,K] @ W[N,K]^T (+ optional sigmoid(gate) scale)
__global__ __launch_bounds__(256) void gemm_atb(
    const float* __restrict__ A, const float* __restrict__ W,
    float* __restrict__ C, int M, int N, int K, const float* __restrict__ gptr)
{
    __shared__ __align__(16) float As[16][128];
    __shared__ __align__(16) float Ws[16][128];
    const int tid = threadIdx.x;
    const int tx = tid & 15, ty = tid >> 4;
    const int m0 = blockIdx.y * 128, n0 = blockIdx.x * 128;
    const int lr = tid >> 1;
    const int lk = (tid & 1) * 8;
    const float* Ap = A + (size_t)(m0 + lr) * K + lk;
    const bool wv = (n0 + lr) < N;
    const float* Wp = W + (size_t)(wv ? (n0 + lr) : 0) * K + lk;

    float acc[8][8];
#pragma unroll
    for (int i = 0; i < 8; ++i)
#pragma unroll
        for (int j = 0; j < 8; ++j) acc[i][j] = 0.f;

    for (int kt = 0; kt < K; kt += 16) {
        float4 a0 = *(const float4*)(Ap + kt);
        float4 a1 = *(const float4*)(Ap + kt + 4);
        float4 w0 = make_float4(0.f,0.f,0.f,0.f), w1 = make_float4(0.f,0.f,0.f,0.f);
        if (wv) { w0 = *(const float4*)(Wp + kt); w1 = *(const float4*)(Wp + kt + 4); }
        __syncthreads();
        As[lk+0][lr]=a0.x; As[lk+1][lr]=a0.y; As[lk+2][lr]=a0.z; As[lk+3][lr]=a0.w;
        As[lk+4][lr]=a1.x; As[lk+5][lr]=a1.y; As[lk+6][lr]=a1.z; As[lk+7][lr]=a1.w;
        Ws[lk+0][lr]=w0.x; Ws[lk+1][lr]=w0.y; Ws[lk+2][lr]=w0.z; Ws[lk+3][lr]=w0.w;
        Ws[lk+4][lr]=w1.x; Ws[lk+5][lr]=w1.y; Ws[lk+6][lr]=w1.z; Ws[lk+7][lr]=w1.w;
        __syncthreads();
#pragma unroll
        for (int kk = 0; kk < 16; ++kk) {
            const float4 va0 = *(const float4*)&As[kk][tx*4];
            const float4 va1 = *(const float4*)&As[kk][64 + tx*4];
            const float4 vb0 = *(const float4*)&Ws[kk][ty*4];
            const float4 vb1 = *(const float4*)&Ws[kk][64 + ty*4];
            const float av[8] = {va0.x,va0.y,va0.z,va0.w,va1.x,va1.y,va1.z,va1.w};
            const float bv[8] = {vb0.x,vb0.y,vb0.z,vb0.w,vb1.x,vb1.y,vb1.z,vb1.w};
#pragma unroll
            for (int i = 0; i < 8; ++i)
#pragma unroll
                for (int j = 0; j < 8; ++j)
                    acc[i][j] = fmaf(av[i], bv[j], acc[i][j]);
        }
    }
    float scale = 1.f;
    if (gptr) scale = sigmoidf_(*gptr);
#pragma unroll
    for (int i = 0; i < 8; ++i) {
        const int m = m0 + ((i < 4) ? (tx*4 + i) : (64 + tx*4 + (i - 4)));
        float* crow = C + (size_t)m * N;
        const int nA = n0 + ty*4;
        const int nB = n0 + 64 + ty*4;
        if (nA + 4 <= N) {
            float4 o = make_float4(acc[i][0]*scale, acc[i][1]*scale, acc[i][2]*scale, acc[i][3]*scale);
            *(float4*)(crow + nA) = o;
        }
        if (nB + 4 <= N) {
            float4 o = make_float4(acc[i][4]*scale, acc[i][5]*scale, acc[i][6]*scale, acc[i][7]*scale);
            *(float4*)(crow + nB) = o;
        }
    }
}

// ---------------- causal depthwise conv1d + bias + silu
__global__ __launch_bounds__(448) void conv_kernel(
    const float* __restrict__ zxbcdt, const float* __restrict__ conv_w,
    const float* __restrict__ conv_b, float* __restrict__ xconv)
{
    const int c4 = threadIdx.x;
    const int bl = blockIdx.x;
    const int l = bl & (SEQL - 1);
    float w[4][4];
#pragma unroll
    for (int j = 0; j < 4; ++j) {
        float4 wr = *(const float4*)(conv_w + (c4*4 + j)*4);
        w[j][0]=wr.x; w[j][1]=wr.y; w[j][2]=wr.z; w[j][3]=wr.w;
    }
    float4 bias = *(const float4*)(conv_b + c4*4);
    float s[4] = {bias.x, bias.y, bias.z, bias.w};
#pragma unroll
    for (int k = 0; k < 4; ++k) {
        const int ls = l - 3 + k;
        if (ls >= 0) {
            const float4 xv = *(const float4*)(zxbcdt + (size_t)(bl - 3 + k)*DINPROJ + DINNER + c4*4);
            s[0] = fmaf(xv.x, w[0][k], s[0]);
            s[1] = fmaf(xv.y, w[1][k], s[1]);
            s[2] = fmaf(xv.z, w[2][k], s[2]);
            s[3] = fmaf(xv.w, w[3][k], s[3]);
        }
    }
    float4 o = make_float4(siluf_(s[0]), siluf_(s[1]), siluf_(s[2]), siluf_(s[3]));
    *(float4*)(xconv + (size_t)bl*CONVDIM + c4*4) = o;
}

// ---------------- dt = softplus(dt+bias); clog = chunk-local inclusive cumsum of A*dt
__global__ __launch_bounds__(128) void dtscan_kernel(
    const float* __restrict__ zxbcdt, const float* __restrict__ dt_bias,
    const float* __restrict__ A_log, float* __restrict__ dtc, float* __restrict__ clog)
{
    const int c = blockIdx.x, h = blockIdx.y, b = blockIdx.z;
    const int t = threadIdx.x;
    const int bl = b*SEQL + c*Q + t;
    float draw = zxbcdt[(size_t)bl*DINPROJ + DINNER + CONVDIM + h] + dt_bias[h];
    float dtv = softplusf_(draw);
    float la = -expf(A_log[h]) * dtv;
    const int lane = t & 63;
    float v = la;
#pragma unroll
    for (int off = 1; off < 64; off <<= 1) {
        float u = __shfl_up(v, off);
        if (lane >= off) v += u;
    }
    __shared__ float w0tot;
    if (t == 63) w0tot = v;
    __syncthreads();
    if (t >= 64) v += w0tot;
    const int idx = (b*NHEADS + h)*SEQL + c*Q + t;
    dtc[idx] = dtv;
    clog[idx] = v;
}

// ---------------- G[b,c][t][s] = C_t . B_s  (full 128x128, bf16)
__global__ __launch_bounds__(256) void gcb_kernel(
    const float* __restrict__ xconv, ushort* __restrict__ G)
{
    const int c = blockIdx.x, b = blockIdx.y;
    __shared__ __align__(16) float Cs[16][128];
    __shared__ __align__(16) float Bs[16][128];
    const int tid = threadIdx.x;
    const int tx = tid & 15, ty = tid >> 4;
    const int lr = tid >> 1, lk = (tid & 1)*8;
    const float* Crow = xconv + (size_t)(b*SEQL + c*Q + lr)*CONVDIM + DINNER + DSTATE;
    const float* Brow = xconv + (size_t)(b*SEQL + c*Q + lr)*CONVDIM + DINNER;
    float acc[8][8];
#pragma unroll
    for (int i = 0; i < 8; ++i)
#pragma unroll
        for (int j = 0; j < 8; ++j) acc[i][j] = 0.f;

    for (int kt = 0; kt < DSTATE; kt += 16) {
        float4 c0 = *(const float4*)(Crow + kt + lk);
        float4 c1 = *(const float4*)(Crow + kt + lk + 4);
        float4 b0 = *(const float4*)(Brow + kt + lk);
        float4 b1 = *(const float4*)(Brow + kt + lk + 4);
        __syncthreads();
        Cs[lk+0][lr]=c0.x; Cs[lk+1][lr]=c0.y; Cs[lk+2][lr]=c0.z; Cs[lk+3][lr]=c0.w;
        Cs[lk+4][lr]=c1.x; Cs[lk+5][lr]=c1.y; Cs[lk+6][lr]=c1.z; Cs[lk+7][lr]=c1.w;
        Bs[lk+0][lr]=b0.x; Bs[lk+1][lr]=b0.y; Bs[lk+2][lr]=b0.z; Bs[lk+3][lr]=b0.w;
        Bs[lk+4][lr]=b1.x; Bs[lk+5][lr]=b1.y; Bs[lk+6][lr]=b1.z; Bs[lk+7][lr]=b1.w;
        __syncthreads();
#pragma unroll
        for (int kk = 0; kk < 16; ++kk) {
            const float4 va0 = *(const float4*)&Cs[kk][tx*4];
            const float4 va1 = *(const float4*)&Cs[kk][64 + tx*4];
            const float4 vb0 = *(const float4*)&Bs[kk][ty*4];
            const float4 vb1 = *(const float4*)&Bs[kk][64 + ty*4];
            const float av[8] = {va0.x,va0.y,va0.z,va0.w,va1.x,va1.y,va1.z,va1.w};
            const float bv[8] = {vb0.x,vb0.y,vb0.z,vb0.w,vb1.x,vb1.y,vb1.z,vb1.w};
#pragma unroll
            for (int i = 0; i < 8; ++i)
#pragma unroll
                for (int j = 0; j < 8; ++j)
                    acc[i][j] = fmaf(av[i], bv[j], acc[i][j]);
        }
    }
    ushort* gout = G + (size_t)(b*NC + c) * (Q*Q);
#pragma unroll
    for (int i = 0; i < 8; ++i) {
        const int t = (i < 4) ? (tx*4 + i) : (64 + tx*4 + (i - 4));
        uint2 oa = make_uint2(pack2(acc[i][0], acc[i][1]), pack2(acc[i][2], acc[i][3]));
        uint2 ob = make_uint2(pack2(acc[i][4], acc[i][5]), pack2(acc[i][6], acc[i][7]));
        *(uint2*)(gout + t*Q + ty*4)       = oa;
        *(uint2*)(gout + t*Q + 64 + ty*4)  = ob;
    }
}

// ---------------- local chunk state: S[p][n] = sum_s w_s * x_s[p] * B_s[n] (bf16 out)
__global__ __launch_bounds__(256) void locstate_kernel(
    const float* __restrict__ xconv, const float* __restrict__ dtc,
    const float* __restrict__ clog, ushort* __restrict__ Sloc)
{
    const int c = blockIdx.x, h = blockIdx.y, b = blockIdx.z;
    __shared__ __align__(16) float Xs[32*64];
    __shared__ __align__(16) float Bs[32*128];
    __shared__ float sw[Q];
    const int tid = threadIdx.x;
    const int p0 = (tid >> 4) * 4, n0 = (tid & 15) * 8;
    const int bh = b*NHEADS + h;
    if (tid < Q) {
        const float ce = clog[(size_t)bh*SEQL + c*Q + (Q-1)];
        const float cs = clog[(size_t)bh*SEQL + c*Q + tid];
        sw[tid] = dtc[(size_t)bh*SEQL + c*Q + tid] * expf(ce - cs);
    }
    float acc[4][8];
#pragma unroll
    for (int i = 0; i < 4; ++i)
#pragma unroll
        for (int j = 0; j < 8; ++j) acc[i][j] = 0.f;

    const size_t rowbase = (size_t)(b*SEQL + c*Q) * CONVDIM;
    for (int st = 0; st < 4; ++st) {
        __syncthreads();
#pragma unroll
        for (int k = 0; k < 2; ++k) {
            const int q = tid + k*256;
            const int s = q >> 4, p4 = (q & 15)*4;
            *(float4*)&Xs[s*64 + p4] =
                *(const float4*)(xconv + rowbase + (size_t)(st*32 + s)*CONVDIM + h*HEADDIM + p4);
        }
#pragma unroll
        for (int k = 0; k < 4; ++k) {
            const int q = tid + k*256;
            const int s = q >> 5, n4 = (q & 31)*4;
            *(float4*)&Bs[s*128 + n4] =
                *(const float4*)(xconv + rowbase + (size_t)(st*32 + s)*CONVDIM + DINNER + n4);
        }
        __syncthreads();
#pragma unroll
        for (int s = 0; s < 32; ++s) {
            const float ws = sw[st*32 + s];
            const float4 xv = *(const float4*)&Xs[s*64 + p0];
            const float4 b0 = *(const float4*)&Bs[s*128 + n0];
            const float4 b1 = *(const float4*)&Bs[s*128 + n0 + 4];
            const float xs[4] = {ws*xv.x, ws*xv.y, ws*xv.z, ws*xv.w};
            const float bv[8] = {b0.x,b0.y,b0.z,b0.w,b1.x,b1.y,b1.z,b1.w};
#pragma unroll
            for (int i = 0; i < 4; ++i)
#pragma unroll
                for (int j = 0; j < 8; ++j)
                    acc[i][j] = fmaf(xs[i], bv[j], acc[i][j]);
        }
    }
    ushort* dst = Sloc + (size_t)((b*NC + c)*NHEADS + h) * (HEADDIM*DSTATE);
#pragma unroll
    for (int i = 0; i < 4; ++i) {
        uint4 o = make_uint4(pack2(acc[i][0],acc[i][1]), pack2(acc[i][2],acc[i][3]),
                             pack2(acc[i][4],acc[i][5]), pack2(acc[i][6],acc[i][7]));
        *(uint4*)(dst + (p0 + i)*DSTATE + n0) = o;
    }
}

// ---------------- in-place sequential prefix over chunk states (16 steps)
__global__ __launch_bounds__(256) void chunkscan_kernel(
    const float* __restrict__ clog, ushort* __restrict__ S)
{
    const int h = blockIdx.x, b = blockIdx.y;
    const int tid = threadIdx.x;
    const int p0 = (tid >> 4) * 4, n0 = (tid & 15) * 8;
    const int bh = b*NHEADS + h;
    float st[4][8];
#pragma unroll
    for (int i = 0; i < 4; ++i)
#pragma unroll
        for (int j = 0; j < 8; ++j) st[i][j] = 0.f;

    for (int c = 0; c < NC; ++c) {
        const float tc = expf(clog[(size_t)bh*SEQL + c*Q + (Q-1)]);
        ushort* base = S + (size_t)((b*NC + c)*NHEADS + h) * (HEADDIM*DSTATE);
#pragma unroll
        for (int i = 0; i < 4; ++i) {
            uint4 raw = *(uint4*)(base + (p0 + i)*DSTATE + n0);
            float lv[8];
            unpack8(raw, lv);
            uint4 pre = make_uint4(pack2(st[i][0],st[i][1]), pack2(st[i][2],st[i][3]),
                                   pack2(st[i][4],st[i][5]), pack2(st[i][6],st[i][7]));
            *(uint4*)(base + (p0 + i)*DSTATE + n0) = pre;
#pragma unroll
            for (int j = 0; j < 8; ++j) st[i][j] = fmaf(tc, st[i][j], lv[j]);
        }
    }
}

// ---------------- Y = causal(G.W)@X + exp(clog)*C@Sp^T + D*x
// smem layout: [0,128) clogS | [128,256) dtcS |
// phase1: SpT [256, 256+8192) as [n][p] ; Cs [256+8192, +2048) as [nn][t]
// phase2: Gs [256, +2048) [ss][t] ; Ws [256+2048, +2048) [ss][t] ; Xs [256+4096, +1024) [s][p]
#define SMOFF 256
__global__ __launch_bounds__(256) void ychunk_kernel(
    const float* __restrict__ xconv, const float* __restrict__ dtc,
    const float* __restrict__ clog, const ushort* __restrict__ G,
    const ushort* __restrict__ Sp, const float* __restrict__ Dv,
    float* __restrict__ ybuf)
{
    __shared__ __align__(16) float sm[SMOFF + 8192 + 2048];
    const int c = blockIdx.x, h = blockIdx.y, b = blockIdx.z;
    const int tid = threadIdx.x;
    const int tg = tid >> 3, pg = tid & 7;
    const int t0 = tg*4, p0 = pg*8;
    const int bh = b*NHEADS + h;
    const int bl0 = b*SEQL + c*Q;

    if (tid < Q) {
        sm[tid]       = clog[(size_t)bh*SEQL + c*Q + tid];
        sm[Q + tid]   = dtc[(size_t)bh*SEQL + c*Q + tid];
    }
    // stage Sp transposed: SpT[n][p]
    const ushort* sp = Sp + (size_t)((b*NC + c)*NHEADS + h) * (HEADDIM*DSTATE);
#pragma unroll
    for (int k = 0; k < 4; ++k) {
        const int q = tid + k*256;
        const int p = q & 63, nn0 = (q >> 6)*8;
        uint4 raw = *(const uint4*)(sp + p*DSTATE + nn0);
        float v[8];
        unpack8(raw, v);
#pragma unroll
        for (int j = 0; j < 8; ++j) sm[SMOFF + (nn0 + j)*64 + p] = v[j];
    }

    float acc[4][8];
#pragma unroll
    for (int i = 0; i < 4; ++i)
#pragma unroll
        for (int j = 0; j < 8; ++j) acc[i][j] = 0.f;

    const int lr = tid >> 1, lk = (tid & 1)*8;
    // ---- phase 1: inter-chunk  acc = C @ Sp^T
    for (int nt = 0; nt < 8; ++nt) {
        float4 c0 = *(const float4*)(xconv + (size_t)(bl0 + lr)*CONVDIM + DINNER + DSTATE + nt*16 + lk);
        float4 c1 = *(const float4*)(xconv + (size_t)(bl0 + lr)*CONVDIM + DINNER + DSTATE + nt*16 + lk + 4);
        __syncthreads();
        float* Cs = &sm[SMOFF + 8192];
        Cs[(lk+0)*128 + lr] = c0.x; Cs[(lk+1)*128 + lr] = c0.y;
        Cs[(lk+2)*128 + lr] = c0.z; Cs[(lk+3)*128 + lr] = c0.w;
        Cs[(lk+4)*128 + lr] = c1.x; Cs[(lk+5)*128 + lr] = c1.y;
        Cs[(lk+6)*128 + lr] = c1.z; Cs[(lk+7)*128 + lr] = c1.w;
        __syncthreads();
#pragma unroll
        for (int nn = 0; nn < 16; ++nn) {
            const int n = nt*16 + nn;
            float cv[4];
#pragma unroll
            for (int i = 0; i < 4; ++i) cv[i] = Cs[nn*128 + t0 + i];
            const float4 s0 = *(const float4*)&sm[SMOFF + n*64 + p0];
            const float4 s1 = *(const float4*)&sm[SMOFF + n*64 + p0 + 4];
            const float sv[8] = {s0.x,s0.y,s0.z,s0.w,s1.x,s1.y,s1.z,s1.w};
#pragma unroll
            for (int i = 0; i < 4; ++i)
#pragma unroll
                for (int j = 0; j < 8; ++j)
                    acc[i][j] = fmaf(cv[i], sv[j], acc[i][j]);
        }
    }
    // scale by exp(clog_t)
    {
        float esc[4];
#pragma unroll
        for (int i = 0; i < 4; ++i) esc[i] = expf(sm[t0 + i]);
#pragma unroll
        for (int i = 0; i < 4; ++i)
#pragma unroll
            for (int j = 0; j < 8; ++j) acc[i][j] *= esc[i];
    }
    // ---- phase 2: intra-chunk  acc += (G .* W) @ X   (causal)
    const ushort* gp = G + (size_t)(b*NC + c) * (Q*Q);
    const int wid = tid >> 6;
    const int tbound = 2*(wid + 1);
    const int myt = tid & 127;
    const int sssel = tid >> 7;
    const float myclogt = sm[myt];
    for (int stile = 0; stile < 8; ++stile) {
        uint4 graw = *(const uint4*)(gp + lr*Q + stile*16 + lk);
        const int xs_ = tid >> 4, xp4 = (tid & 15)*4;
        float4 xrow = *(const float4*)(xconv + (size_t)(bl0 + stile*16 + xs_)*CONVDIM + h*HEADDIM + xp4);
        __syncthreads();
        {
            float gv[8];
            unpack8(graw, gv);
            float* Gs = &sm[SMOFF];
#pragma unroll
            for (int j = 0; j < 8; ++j) Gs[(lk+j)*128 + lr] = gv[j];
            *(float4*)&sm[SMOFF + 4096 + xs_*64 + xp4] = xrow;
            float* Wsm = &sm[SMOFF + 2048];
#pragma unroll
            for (int j = 0; j < 8; ++j) {
                const int ss = sssel + 2*j;
                const int s_loc = stile*16 + ss;
                float w = 0.f;
                if (s_loc <= myt) w = sm[Q + s_loc] * expf(myclogt - sm[s_loc]);
                Wsm[ss*128 + myt] = w;
            }
        }
        __syncthreads();
        if (stile < tbound) {
#pragma unroll
            for (int ss = 0; ss < 16; ++ss) {
                float gm[4];
#pragma unroll
                for (int i = 0; i < 4; ++i)
                    gm[i] = sm[SMOFF + ss*128 + t0 + i] * sm[SMOFF + 2048 + ss*128 + t0 + i];
                const float4 xa = *(const float4*)&sm[SMOFF + 4096 + ss*64 + p0];
                const float4 xb = *(const float4*)&sm[SMOFF + 4096 + ss*64 + p0 + 4];
                const float xv[8] = {xa.x,xa.y,xa.z,xa.w,xb.x,xb.y,xb.z,xb.w};
#pragma unroll
                for (int i = 0; i < 4; ++i)
#pragma unroll
                    for (int j = 0; j < 8; ++j)
                        acc[i][j] = fmaf(gm[i], xv[j], acc[i][j]);
            }
        }
    }
    // ---- epilogue: + D*x, store
    const float Dh = Dv[h];
#pragma unroll
    for (int i = 0; i < 4; ++i) {
        const int t = t0 + i;
        const float* xg = xconv + (size_t)(bl0 + t)*CONVDIM + h*HEADDIM + p0;
        const float4 xa = *(const float4*)xg;
        const float4 xb = *(const float4*)(xg + 4);
        float4 o0 = make_float4(acc[i][0] + Dh*xa.x, acc[i][1] + Dh*xa.y,
                                acc[i][2] + Dh*xa.z, acc[i][3] + Dh*xa.w);
        float4 o1 = make_float4(acc[i][4] + Dh*xb.x, acc[i][5] + Dh*xb.y,
                                acc[i][6] + Dh*xb.z, acc[i][7] + Dh*xb.w);
        float* yo = ybuf + (size_t)(bl0 + t)*DINNER + h*HEADDIM + p0;
        *(float4*)yo       = o0;
        *(float4*)(yo + 4) = o1;
    }
}

// ---------------- gated RMSNorm
__global__ __launch_bounds__(128) void rms_kernel(
    const float* __restrict__ zxbcdt, const float* __restrict__ norm_w,
    float* __restrict__ ybuf)
{
    const int row = blockIdx.x;
    const int tid = threadIdx.x;
    const float* zr = zxbcdt + (size_t)row * DINPROJ;
    float* yr = ybuf + (size_t)row * DINNER;
    float v[12];
    float ss = 0.f;
#pragma unroll
    for (int i = 0; i < 3; ++i) {
        const int o = (tid + i*128) * 4;
        float4 yv = *(const float4*)(yr + o);
        float4 zv = *(const float4*)(zr + o);
        float a = yv.x * siluf_(zv.x);
        float b = yv.y * siluf_(zv.y);
        float cc = yv.z * siluf_(zv.z);
        float d = yv.w * siluf_(zv.w);
        v[i*4+0]=a; v[i*4+1]=b; v[i*4+2]=cc; v[i*4+3]=d;
        ss += a*a + b*b + cc*cc + d*d;
    }
#pragma unroll
    for (int off = 1; off < 64; off <<= 1) ss += __shfl_xor(ss, off);
    __shared__ float red[2];
    if ((tid & 63) == 0) red[tid >> 6] = ss;
    __syncthreads();
    const float rstd = rsqrtf((red[0] + red[1]) * (1.f/DINNER) + RMS_EPS);
#pragma unroll
    for (int i = 0; i < 3; ++i) {
        const int o = (tid + i*128) * 4;
        float4 wv = *(const float4*)(norm_w + o);
        float4 ov = make_float4(v[i*4+0]*rstd*wv.x, v[i*4+1]*rstd*wv.y,
                                v[i*4+2]*rstd*wv.z, v[i*4+3]*rstd*wv.w);
        *(float4*)(yr + o) = ov;
    }
}

extern "C" void kernel_launch(void* const* d_in, const int* in_sizes, int n_in,
                              void* d_out, int out_size, void* d_ws, size_t ws_size,
                              hipStream_t stream)
{
    const float* feature    = (const float*)d_in[0];
    const float* in_proj_w  = (const float*)d_in[1];
    const float* conv_w     = (const float*)d_in[2];
    const float* conv_b     = (const float*)d_in[3];
    const float* dt_bias    = (const float*)d_in[4];
    const float* A_log      = (const float*)d_in[5];
    const float* Dvec       = (const float*)d_in[6];
    const float* norm_w     = (const float*)d_in[7];
    const float* out_proj_w = (const float*)d_in[8];
    const float* gate1      = (const float*)d_in[9];
    float* out = (float*)d_out;

    float* zxbcdt = (float*)d_ws;                               // 8192*3352
    float* xconv  = zxbcdt + (size_t)BLROWS * DINPROJ;          // 8192*1792
    float* ybuf   = xconv  + (size_t)BLROWS * CONVDIM;          // 8192*1536
    float* dtc    = ybuf   + (size_t)BLROWS * DINNER;           // [b,h,L]
    float* clog   = dtc    + (size_t)NB * NHEADS * SEQL;        // [b,h,L]
    ushort* Gbuf  = (ushort*)(clog + (size_t)NB * NHEADS * SEQL);  // [b,c,Q,Q] bf16
    ushort* Sbuf  = Gbuf + (size_t)NB * NC * Q * Q;                // [b,c,h,64,128] bf16

    // 1) in_proj
    gemm_atb<<<dim3(27, 64), 256, 0, stream>>>(feature, in_proj_w, zxbcdt,
                                               BLROWS, DINPROJ, DMODEL, nullptr);
    // 2) conv + silu
    conv_kernel<<<dim3(BLROWS), 448, 0, stream>>>(zxbcdt, conv_w, conv_b, xconv);
    // 3) dt softplus + chunk-local cumsum of log-decay
    dtscan_kernel<<<dim3(NC, NHEADS, NB), 128, 0, stream>>>(zxbcdt, dt_bias, A_log, dtc, clog);
    // 4) G = C B^T per (b,c)
    gcb_kernel<<<dim3(NC, NB), 256, 0, stream>>>(xconv, Gbuf);
    // 5) local chunk states
    locstate_kernel<<<dim3(NC, NHEADS, NB), 256, 0, stream>>>(xconv, dtc, clog, Sbuf);
    // 6) in-place prefix over chunks
    chunkscan_kernel<<<dim3(NHEADS, NB), 256, 0, stream>>>(clog, Sbuf);
    // 7) Y = intra + inter + D*x
    ychunk_kernel<<<dim3(NC, NHEADS, NB), 256, 0, stream>>>(xconv, dtc, clog, Gbuf, Sbuf, Dvec, ybuf);
    // 8) gated RMSNorm
    rms_kernel<<<dim3(BLROWS), 128, 0, stream>>>(zxbcdt, norm_w, ybuf);
    // 9) out_proj + sigmoid(gate1)
    gemm_atb<<<dim3(6, 64), 256, 0, stream>>>(ybuf, out_proj_w, out,
                                              BLROWS, DMODEL, DINNER, gate1);
}

// Round 3
// 514.421 us; speedup vs baseline: 5.3594x; 2.1881x over previous
//
#include <hip/hip_runtime.h>
#include <cstddef>

#define NB 4
#define SEQL 2048
#define DMODEL 768
#define DSTATE 128
#define HEADDIM 64
#define NHEADS 24
#define DINNER 1536
#define CONVDIM 1792
#define DINPROJ 3352
#define BLROWS (NB*SEQL)
#define RMS_EPS 1e-5f
#define Q 128
#define NC (SEQL/Q)

typedef unsigned int uint;
typedef unsigned short ushort;
typedef __attribute__((ext_vector_type(8))) short bf16x8;
typedef __attribute__((ext_vector_type(4))) float f32x4;

__device__ __forceinline__ float sigmoidf_(float x){ return 1.f/(1.f+expf(-x)); }
__device__ __forceinline__ float siluf_(float x){ return x * sigmoidf_(x); }
__device__ __forceinline__ float softplusf_(float x){ return x > 20.f ? x : log1pf(expf(x)); }

__device__ __forceinline__ ushort f2bf(float f){
    union { float f; uint u; } v; v.f = f;
    uint r = (v.u + 0x7FFFu + ((v.u >> 16) & 1u)) >> 16;
    return (ushort)r;
}
__device__ __forceinline__ float bf2f(ushort s){
    union { uint u; float f; } v; v.u = ((uint)s) << 16;
    return v.f;
}
__device__ __forceinline__ uint pack2(float a, float b){
    return (uint)f2bf(a) | ((uint)f2bf(b) << 16);
}
__device__ __forceinline__ void unpack8(uint4 r, float* o){
    o[0]=bf2f((ushort)(r.x&0xffff)); o[1]=bf2f((ushort)(r.x>>16));
    o[2]=bf2f((ushort)(r.y&0xffff)); o[3]=bf2f((ushort)(r.y>>16));
    o[4]=bf2f((ushort)(r.z&0xffff)); o[5]=bf2f((ushort)(r.z>>16));
    o[6]=bf2f((ushort)(r.w&0xffff)); o[7]=bf2f((ushort)(r.w>>16));
}

#define GLD16(g, l) __builtin_amdgcn_global_load_lds( \
    (const __attribute__((address_space(1))) void*)(g), \
    (__attribute__((address_space(3))) void*)(l), 16, 0, 0)

// ---------------- fp32 -> bf16 cast (n4 = n/4)
__global__ __launch_bounds__(256) void cast_kernel(
    const float* __restrict__ in, ushort* __restrict__ out, int n4)
{
    const int i = blockIdx.x*256 + threadIdx.x;
    if (i < n4) {
        float4 v = ((const float4*)in)[i];
        ushort4 o = make_ushort4(f2bf(v.x), f2bf(v.y), f2bf(v.z), f2bf(v.w));
        ((ushort4*)out)[i] = o;
    }
}

// ---------------- MFMA GEMM: C[M,N] = A[M,K] @ W[N,K]^T  (bf16 in, fp32 out)
// 128x128 block tile, BK=32, 4 waves (2x2 of 64x64), 16x16x32 bf16 MFMA.
// global_load_lds width=16 staging; M % 128 == 0, K % 32 == 0; N edge-guarded.
__global__ __launch_bounds__(256) void gemm_mfma(
    const ushort* __restrict__ A, const ushort* __restrict__ W,
    float* __restrict__ C, int M, int N, int K, const float* __restrict__ gptr)
{
    __shared__ __align__(16) ushort As[128*32];
    __shared__ __align__(16) ushort Bs[128*32];
    const int tid = threadIdx.x;
    const int wv = tid >> 6, ln = tid & 63;
    const int m0 = blockIdx.y * 128, n0 = blockIdx.x * 128;
    const int wm = (wv >> 1) * 64, wn = (wv & 1) * 64;

    // staging: wave wv loads rows [wv*32, wv*32+32) of each tile,
    // two GLD16 per matrix: 16 rows x 64B each; lane -> row (ln>>2), k-quad (ln&3)
    const int srow = ln >> 2;
    const int scol = (ln & 3) * 8;
    const ushort* gA0 = A + (size_t)(m0 + wv*32 +      srow) * K + scol;
    const ushort* gA1 = A + (size_t)(m0 + wv*32 + 16 + srow) * K + scol;
    int wr0 = n0 + wv*32 +      srow; if (wr0 >= N) wr0 = N - 1;
    int wr1 = n0 + wv*32 + 16 + srow; if (wr1 >= N) wr1 = N - 1;
    const ushort* gB0 = W + (size_t)wr0 * K + scol;
    const ushort* gB1 = W + (size_t)wr1 * K + scol;
    ushort* lA0 = &As[(wv*32     ) * 32];
    ushort* lA1 = &As[(wv*32 + 16) * 32];
    ushort* lB0 = &Bs[(wv*32     ) * 32];
    ushort* lB1 = &Bs[(wv*32 + 16) * 32];

    f32x4 acc[4][4];
#pragma unroll
    for (int i = 0; i < 4; ++i)
#pragma unroll
        for (int j = 0; j < 4; ++j) acc[i][j] = (f32x4){0.f, 0.f, 0.f, 0.f};

    const int fr = ln & 15;        // fragment row (m or n within 16-tile)
    const int fk = (ln >> 4) * 8;  // k offset within BK

    for (int kt = 0; kt < K; kt += 32) {
        __syncthreads();
        GLD16(gA0 + kt, lA0);
        GLD16(gA1 + kt, lA1);
        GLD16(gB0 + kt, lB0);
        GLD16(gB1 + kt, lB1);
        __syncthreads();
        bf16x8 af[4], bfr[4];
#pragma unroll
        for (int i = 0; i < 4; ++i)
            af[i] = *(const bf16x8*)&As[(wm + i*16 + fr) * 32 + fk];
#pragma unroll
        for (int j = 0; j < 4; ++j)
            bfr[j] = *(const bf16x8*)&Bs[(wn + j*16 + fr) * 32 + fk];
#pragma unroll
        for (int i = 0; i < 4; ++i)
#pragma unroll
            for (int j = 0; j < 4; ++j)
                acc[i][j] = __builtin_amdgcn_mfma_f32_16x16x32_bf16(af[i], bfr[j], acc[i][j], 0, 0, 0);
    }

    float scale = 1.f;
    if (gptr) scale = sigmoidf_(*gptr);
    const int cn = ln & 15;
    const int cr = (ln >> 4) * 4;
#pragma unroll
    for (int i = 0; i < 4; ++i) {
        const int mb = m0 + wm + i*16 + cr;
#pragma unroll
        for (int j = 0; j < 4; ++j) {
            const int n = n0 + wn + j*16 + cn;
            if (n < N) {
                float* cp = C + (size_t)mb * N + n;
                cp[0*(size_t)N] = acc[i][j].x * scale;
                cp[1*(size_t)N] = acc[i][j].y * scale;
                cp[2*(size_t)N] = acc[i][j].z * scale;
                cp[3*(size_t)N] = acc[i][j].w * scale;
            }
        }
    }
}

// ---------------- causal depthwise conv1d + bias + silu
__global__ __launch_bounds__(448) void conv_kernel(
    const float* __restrict__ zxbcdt, const float* __restrict__ conv_w,
    const float* __restrict__ conv_b, float* __restrict__ xconv)
{
    const int c4 = threadIdx.x;
    const int bl = blockIdx.x;
    const int l = bl & (SEQL - 1);
    float w[4][4];
#pragma unroll
    for (int j = 0; j < 4; ++j) {
        float4 wr = *(const float4*)(conv_w + (c4*4 + j)*4);
        w[j][0]=wr.x; w[j][1]=wr.y; w[j][2]=wr.z; w[j][3]=wr.w;
    }
    float4 bias = *(const float4*)(conv_b + c4*4);
    float s[4] = {bias.x, bias.y, bias.z, bias.w};
#pragma unroll
    for (int k = 0; k < 4; ++k) {
        const int ls = l - 3 + k;
        if (ls >= 0) {
            const float4 xv = *(const float4*)(zxbcdt + (size_t)(bl - 3 + k)*DINPROJ + DINNER + c4*4);
            s[0] = fmaf(xv.x, w[0][k], s[0]);
            s[1] = fmaf(xv.y, w[1][k], s[1]);
            s[2] = fmaf(xv.z, w[2][k], s[2]);
            s[3] = fmaf(xv.w, w[3][k], s[3]);
        }
    }
    float4 o = make_float4(siluf_(s[0]), siluf_(s[1]), siluf_(s[2]), siluf_(s[3]));
    *(float4*)(xconv + (size_t)bl*CONVDIM + c4*4) = o;
}

// ---------------- dt = softplus(dt+bias); clog = chunk-local inclusive cumsum of A*dt
__global__ __launch_bounds__(128) void dtscan_kernel(
    const float* __restrict__ zxbcdt, const float* __restrict__ dt_bias,
    const float* __restrict__ A_log, float* __restrict__ dtc, float* __restrict__ clog)
{
    const int c = blockIdx.x, h = blockIdx.y, b = blockIdx.z;
    const int t = threadIdx.x;
    const int bl = b*SEQL + c*Q + t;
    float draw = zxbcdt[(size_t)bl*DINPROJ + DINNER + CONVDIM + h] + dt_bias[h];
    float dtv = softplusf_(draw);
    float la = -expf(A_log[h]) * dtv;
    const int lane = t & 63;
    float v = la;
#pragma unroll
    for (int off = 1; off < 64; off <<= 1) {
        float u = __shfl_up(v, off);
        if (lane >= off) v += u;
    }
    __shared__ float w0tot;
    if (t == 63) w0tot = v;
    __syncthreads();
    if (t >= 64) v += w0tot;
    const int idx = (b*NHEADS + h)*SEQL + c*Q + t;
    dtc[idx] = dtv;
    clog[idx] = v;
}

// ---------------- G[b,c][t][s] = C_t . B_s  (full 128x128, bf16)
__global__ __launch_bounds__(256) void gcb_kernel(
    const float* __restrict__ xconv, ushort* __restrict__ G)
{
    const int c = blockIdx.x, b = blockIdx.y;
    __shared__ __align__(16) float Cs[16][128];
    __shared__ __align__(16) float Bs[16][128];
    const int tid = threadIdx.x;
    const int tx = tid & 15, ty = tid >> 4;
    const int lr = tid >> 1, lk = (tid & 1)*8;
    const float* Crow = xconv + (size_t)(b*SEQL + c*Q + lr)*CONVDIM + DINNER + DSTATE;
    const float* Brow = xconv + (size_t)(b*SEQL + c*Q + lr)*CONVDIM + DINNER;
    float acc[8][8];
#pragma unroll
    for (int i = 0; i < 8; ++i)
#pragma unroll
        for (int j = 0; j < 8; ++j) acc[i][j] = 0.f;

    for (int kt = 0; kt < DSTATE; kt += 16) {
        float4 c0 = *(const float4*)(Crow + kt + lk);
        float4 c1 = *(const float4*)(Crow + kt + lk + 4);
        float4 b0 = *(const float4*)(Brow + kt + lk);
        float4 b1 = *(const float4*)(Brow + kt + lk + 4);
        __syncthreads();
        Cs[lk+0][lr]=c0.x; Cs[lk+1][lr]=c0.y; Cs[lk+2][lr]=c0.z; Cs[lk+3][lr]=c0.w;
        Cs[lk+4][lr]=c1.x; Cs[lk+5][lr]=c1.y; Cs[lk+6][lr]=c1.z; Cs[lk+7][lr]=c1.w;
        Bs[lk+0][lr]=b0.x; Bs[lk+1][lr]=b0.y; Bs[lk+2][lr]=b0.z; Bs[lk+3][lr]=b0.w;
        Bs[lk+4][lr]=b1.x; Bs[lk+5][lr]=b1.y; Bs[lk+6][lr]=b1.z; Bs[lk+7][lr]=b1.w;
        __syncthreads();
#pragma unroll
        for (int kk = 0; kk < 16; ++kk) {
            const float4 va0 = *(const float4*)&Cs[kk][tx*4];
            const float4 va1 = *(const float4*)&Cs[kk][64 + tx*4];
            const float4 vb0 = *(const float4*)&Bs[kk][ty*4];
            const float4 vb1 = *(const float4*)&Bs[kk][64 + ty*4];
            const float av[8] = {va0.x,va0.y,va0.z,va0.w,va1.x,va1.y,va1.z,va1.w};
            const float bv[8] = {vb0.x,vb0.y,vb0.z,vb0.w,vb1.x,vb1.y,vb1.z,vb1.w};
#pragma unroll
            for (int i = 0; i < 8; ++i)
#pragma unroll
                for (int j = 0; j < 8; ++j)
                    acc[i][j] = fmaf(av[i], bv[j], acc[i][j]);
        }
    }
    ushort* gout = G + (size_t)(b*NC + c) * (Q*Q);
#pragma unroll
    for (int i = 0; i < 8; ++i) {
        const int t = (i < 4) ? (tx*4 + i) : (64 + tx*4 + (i - 4));
        uint2 oa = make_uint2(pack2(acc[i][0], acc[i][1]), pack2(acc[i][2], acc[i][3]));
        uint2 ob = make_uint2(pack2(acc[i][4], acc[i][5]), pack2(acc[i][6], acc[i][7]));
        *(uint2*)(gout + t*Q + ty*4)       = oa;
        *(uint2*)(gout + t*Q + 64 + ty*4)  = ob;
    }
}

// ---------------- local chunk state: S[p][n] = sum_s w_s * x_s[p] * B_s[n] (bf16 out)
__global__ __launch_bounds__(256) void locstate_kernel(
    const float* __restrict__ xconv, const float* __restrict__ dtc,
    const float* __restrict__ clog, ushort* __restrict__ Sloc)
{
    const int c = blockIdx.x, h = blockIdx.y, b = blockIdx.z;
    __shared__ __align__(16) float Xs[32*64];
    __shared__ __align__(16) float Bs[32*128];
    __shared__ float sw[Q];
    const int tid = threadIdx.x;
    const int p0 = (tid >> 4) * 4, n0 = (tid & 15) * 8;
    const int bh = b*NHEADS + h;
    if (tid < Q) {
        const float ce = clog[(size_t)bh*SEQL + c*Q + (Q-1)];
        const float cs = clog[(size_t)bh*SEQL + c*Q + tid];
        sw[tid] = dtc[(size_t)bh*SEQL + c*Q + tid] * expf(ce - cs);
    }
    float acc[4][8];
#pragma unroll
    for (int i = 0; i < 4; ++i)
#pragma unroll
        for (int j = 0; j < 8; ++j) acc[i][j] = 0.f;

    const size_t rowbase = (size_t)(b*SEQL + c*Q) * CONVDIM;
    for (int st = 0; st < 4; ++st) {
        __syncthreads();
#pragma unroll
        for (int k = 0; k < 2; ++k) {
            const int q = tid + k*256;
            const int s = q >> 4, p4 = (q & 15)*4;
            *(float4*)&Xs[s*64 + p4] =
                *(const float4*)(xconv + rowbase + (size_t)(st*32 + s)*CONVDIM + h*HEADDIM + p4);
        }
#pragma unroll
        for (int k = 0; k < 4; ++k) {
            const int q = tid + k*256;
            const int s = q >> 5, n4 = (q & 31)*4;
            *(float4*)&Bs[s*128 + n4] =
                *(const float4*)(xconv + rowbase + (size_t)(st*32 + s)*CONVDIM + DINNER + n4);
        }
        __syncthreads();
#pragma unroll
        for (int s = 0; s < 32; ++s) {
            const float ws = sw[st*32 + s];
            const float4 xv = *(const float4*)&Xs[s*64 + p0];
            const float4 b0 = *(const float4*)&Bs[s*128 + n0];
            const float4 b1 = *(const float4*)&Bs[s*128 + n0 + 4];
            const float xs[4] = {ws*xv.x, ws*xv.y, ws*xv.z, ws*xv.w};
            const float bv[8] = {b0.x,b0.y,b0.z,b0.w,b1.x,b1.y,b1.z,b1.w};
#pragma unroll
            for (int i = 0; i < 4; ++i)
#pragma unroll
                for (int j = 0; j < 8; ++j)
                    acc[i][j] = fmaf(xs[i], bv[j], acc[i][j]);
        }
    }
    ushort* dst = Sloc + (size_t)((b*NC + c)*NHEADS + h) * (HEADDIM*DSTATE);
#pragma unroll
    for (int i = 0; i < 4; ++i) {
        uint4 o = make_uint4(pack2(acc[i][0],acc[i][1]), pack2(acc[i][2],acc[i][3]),
                             pack2(acc[i][4],acc[i][5]), pack2(acc[i][6],acc[i][7]));
        *(uint4*)(dst + (p0 + i)*DSTATE + n0) = o;
    }
}

// ---------------- in-place sequential prefix over chunk states (16 steps)
__global__ __launch_bounds__(256) void chunkscan_kernel(
    const float* __restrict__ clog, ushort* __restrict__ S)
{
    const int h = blockIdx.x, b = blockIdx.y;
    const int tid = threadIdx.x;
    const int p0 = (tid >> 4) * 4, n0 = (tid & 15) * 8;
    const int bh = b*NHEADS + h;
    float st[4][8];
#pragma unroll
    for (int i = 0; i < 4; ++i)
#pragma unroll
        for (int j = 0; j < 8; ++j) st[i][j] = 0.f;

    for (int c = 0; c < NC; ++c) {
        const float tc = expf(clog[(size_t)bh*SEQL + c*Q + (Q-1)]);
        ushort* base = S + (size_t)((b*NC + c)*NHEADS + h) * (HEADDIM*DSTATE);
#pragma unroll
        for (int i = 0; i < 4; ++i) {
            uint4 raw = *(uint4*)(base + (p0 + i)*DSTATE + n0);
            float lv[8];
            unpack8(raw, lv);
            uint4 pre = make_uint4(pack2(st[i][0],st[i][1]), pack2(st[i][2],st[i][3]),
                                   pack2(st[i][4],st[i][5]), pack2(st[i][6],st[i][7]));
            *(uint4*)(base + (p0 + i)*DSTATE + n0) = pre;
#pragma unroll
            for (int j = 0; j < 8; ++j) st[i][j] = fmaf(tc, st[i][j], lv[j]);
        }
    }
}

// ---------------- Y = causal(G.W)@X + exp(clog)*C@Sp^T + D*x
#define SMOFF 256
__global__ __launch_bounds__(256) void ychunk_kernel(
    const float* __restrict__ xconv, const float* __restrict__ dtc,
    const float* __restrict__ clog, const ushort* __restrict__ G,
    const ushort* __restrict__ Sp, const float* __restrict__ Dv,
    float* __restrict__ ybuf)
{
    __shared__ __align__(16) float sm[SMOFF + 8192 + 2048];
    const int c = blockIdx.x, h = blockIdx.y, b = blockIdx.z;
    const int tid = threadIdx.x;
    const int tg = tid >> 3, pg = tid & 7;
    const int t0 = tg*4, p0 = pg*8;
    const int bh = b*NHEADS + h;
    const int bl0 = b*SEQL + c*Q;

    if (tid < Q) {
        sm[tid]       = clog[(size_t)bh*SEQL + c*Q + tid];
        sm[Q + tid]   = dtc[(size_t)bh*SEQL + c*Q + tid];
    }
    const ushort* sp = Sp + (size_t)((b*NC + c)*NHEADS + h) * (HEADDIM*DSTATE);
#pragma unroll
    for (int k = 0; k < 4; ++k) {
        const int q = tid + k*256;
        const int p = q & 63, nn0 = (q >> 6)*8;
        uint4 raw = *(const uint4*)(sp + p*DSTATE + nn0);
        float v[8];
        unpack8(raw, v);
#pragma unroll
        for (int j = 0; j < 8; ++j) sm[SMOFF + (nn0 + j)*64 + p] = v[j];
    }

    float acc[4][8];
#pragma unroll
    for (int i = 0; i < 4; ++i)
#pragma unroll
        for (int j = 0; j < 8; ++j) acc[i][j] = 0.f;

    const int lr = tid >> 1, lk = (tid & 1)*8;
    for (int nt = 0; nt < 8; ++nt) {
        float4 c0 = *(const float4*)(xconv + (size_t)(bl0 + lr)*CONVDIM + DINNER + DSTATE + nt*16 + lk);
        float4 c1 = *(const float4*)(xconv + (size_t)(bl0 + lr)*CONVDIM + DINNER + DSTATE + nt*16 + lk + 4);
        __syncthreads();
        float* Cs = &sm[SMOFF + 8192];
        Cs[(lk+0)*128 + lr] = c0.x; Cs[(lk+1)*128 + lr] = c0.y;
        Cs[(lk+2)*128 + lr] = c0.z; Cs[(lk+3)*128 + lr] = c0.w;
        Cs[(lk+4)*128 + lr] = c1.x; Cs[(lk+5)*128 + lr] = c1.y;
        Cs[(lk+6)*128 + lr] = c1.z; Cs[(lk+7)*128 + lr] = c1.w;
        __syncthreads();
#pragma unroll
        for (int nn = 0; nn < 16; ++nn) {
            const int n = nt*16 + nn;
            float cv[4];
#pragma unroll
            for (int i = 0; i < 4; ++i) cv[i] = Cs[nn*128 + t0 + i];
            const float4 s0 = *(const float4*)&sm[SMOFF + n*64 + p0];
            const float4 s1 = *(const float4*)&sm[SMOFF + n*64 + p0 + 4];
            const float sv[8] = {s0.x,s0.y,s0.z,s0.w,s1.x,s1.y,s1.z,s1.w};
#pragma unroll
            for (int i = 0; i < 4; ++i)
#pragma unroll
                for (int j = 0; j < 8; ++j)
                    acc[i][j] = fmaf(cv[i], sv[j], acc[i][j]);
        }
    }
    {
        float esc[4];
#pragma unroll
        for (int i = 0; i < 4; ++i) esc[i] = expf(sm[t0 + i]);
#pragma unroll
        for (int i = 0; i < 4; ++i)
#pragma unroll
            for (int j = 0; j < 8; ++j) acc[i][j] *= esc[i];
    }
    const ushort* gp = G + (size_t)(b*NC + c) * (Q*Q);
    const int wid = tid >> 6;
    const int tbound = 2*(wid + 1);
    const int myt = tid & 127;
    const int sssel = tid >> 7;
    const float myclogt = sm[myt];
    for (int stile = 0; stile < 8; ++stile) {
        uint4 graw = *(const uint4*)(gp + lr*Q + stile*16 + lk);
        const int xs_ = tid >> 4, xp4 = (tid & 15)*4;
        float4 xrow = *(const float4*)(xconv + (size_t)(bl0 + stile*16 + xs_)*CONVDIM + h*HEADDIM + xp4);
        __syncthreads();
        {
            float gv[8];
            unpack8(graw, gv);
            float* Gs = &sm[SMOFF];
#pragma unroll
            for (int j = 0; j < 8; ++j) Gs[(lk+j)*128 + lr] = gv[j];
            *(float4*)&sm[SMOFF + 4096 + xs_*64 + xp4] = xrow;
            float* Wsm = &sm[SMOFF + 2048];
#pragma unroll
            for (int j = 0; j < 8; ++j) {
                const int ss = sssel + 2*j;
                const int s_loc = stile*16 + ss;
                float w = 0.f;
                if (s_loc <= myt) w = sm[Q + s_loc] * expf(myclogt - sm[s_loc]);
                Wsm[ss*128 + myt] = w;
            }
        }
        __syncthreads();
        if (stile < tbound) {
#pragma unroll
            for (int ss = 0; ss < 16; ++ss) {
                float gm[4];
#pragma unroll
                for (int i = 0; i < 4; ++i)
                    gm[i] = sm[SMOFF + ss*128 + t0 + i] * sm[SMOFF + 2048 + ss*128 + t0 + i];
                const float4 xa = *(const float4*)&sm[SMOFF + 4096 + ss*64 + p0];
                const float4 xb = *(const float4*)&sm[SMOFF + 4096 + ss*64 + p0 + 4];
                const float xv[8] = {xa.x,xa.y,xa.z,xa.w,xb.x,xb.y,xb.z,xb.w};
#pragma unroll
                for (int i = 0; i < 4; ++i)
#pragma unroll
                    for (int j = 0; j < 8; ++j)
                        acc[i][j] = fmaf(gm[i], xv[j], acc[i][j]);
            }
        }
    }
    const float Dh = Dv[h];
#pragma unroll
    for (int i = 0; i < 4; ++i) {
        const int t = t0 + i;
        const float* xg = xconv + (size_t)(bl0 + t)*CONVDIM + h*HEADDIM + p0;
        const float4 xa = *(const float4*)xg;
        const float4 xb = *(const float4*)(xg + 4);
        float4 o0 = make_float4(acc[i][0] + Dh*xa.x, acc[i][1] + Dh*xa.y,
                                acc[i][2] + Dh*xa.z, acc[i][3] + Dh*xa.w);
        float4 o1 = make_float4(acc[i][4] + Dh*xb.x, acc[i][5] + Dh*xb.y,
                                acc[i][6] + Dh*xb.z, acc[i][7] + Dh*xb.w);
        float* yo = ybuf + (size_t)(bl0 + t)*DINNER + h*HEADDIM + p0;
        *(float4*)yo       = o0;
        *(float4*)(yo + 4) = o1;
    }
}

// ---------------- gated RMSNorm -> bf16 output
__global__ __launch_bounds__(128) void rms_kernel(
    const float* __restrict__ zxbcdt, const float* __restrict__ norm_w,
    const float* __restrict__ ybuf, ushort* __restrict__ ybf)
{
    const int row = blockIdx.x;
    const int tid = threadIdx.x;
    const float* zr = zxbcdt + (size_t)row * DINPROJ;
    const float* yr = ybuf + (size_t)row * DINNER;
    ushort* yo = ybf + (size_t)row * DINNER;
    float v[12];
    float ss = 0.f;
#pragma unroll
    for (int i = 0; i < 3; ++i) {
        const int o = (tid + i*128) * 4;
        float4 yv = *(const float4*)(yr + o);
        float4 zv = *(const float4*)(zr + o);
        float a = yv.x * siluf_(zv.x);
        float b = yv.y * siluf_(zv.y);
        float cc = yv.z * siluf_(zv.z);
        float d = yv.w * siluf_(zv.w);
        v[i*4+0]=a; v[i*4+1]=b; v[i*4+2]=cc; v[i*4+3]=d;
        ss += a*a + b*b + cc*cc + d*d;
    }
#pragma unroll
    for (int off = 1; off < 64; off <<= 1) ss += __shfl_xor(ss, off);
    __shared__ float red[2];
    if ((tid & 63) == 0) red[tid >> 6] = ss;
    __syncthreads();
    const float rstd = rsqrtf((red[0] + red[1]) * (1.f/DINNER) + RMS_EPS);
#pragma unroll
    for (int i = 0; i < 3; ++i) {
        const int o = (tid + i*128) * 4;
        float4 wv = *(const float4*)(norm_w + o);
        ushort4 ov = make_ushort4(f2bf(v[i*4+0]*rstd*wv.x), f2bf(v[i*4+1]*rstd*wv.y),
                                  f2bf(v[i*4+2]*rstd*wv.z), f2bf(v[i*4+3]*rstd*wv.w));
        *(ushort4*)(yo + o) = ov;
    }
}

extern "C" void kernel_launch(void* const* d_in, const int* in_sizes, int n_in,
                              void* d_out, int out_size, void* d_ws, size_t ws_size,
                              hipStream_t stream)
{
    const float* feature    = (const float*)d_in[0];
    const float* in_proj_w  = (const float*)d_in[1];
    const float* conv_w     = (const float*)d_in[2];
    const float* conv_b     = (const float*)d_in[3];
    const float* dt_bias    = (const float*)d_in[4];
    const float* A_log      = (const float*)d_in[5];
    const float* Dvec       = (const float*)d_in[6];
    const float* norm_w     = (const float*)d_in[7];
    const float* out_proj_w = (const float*)d_in[8];
    const float* gate1      = (const float*)d_in[9];
    float* out = (float*)d_out;

    float* zxbcdt = (float*)d_ws;                               // 8192*3352 fp32
    float* xconv  = zxbcdt + (size_t)BLROWS * DINPROJ;          // 8192*1792 fp32
    float* ybuf   = xconv  + (size_t)BLROWS * CONVDIM;          // 8192*1536 fp32
    float* dtc    = ybuf   + (size_t)BLROWS * DINNER;
    float* clog   = dtc    + (size_t)NB * NHEADS * SEQL;
    ushort* Gbuf  = (ushort*)(clog + (size_t)NB * NHEADS * SEQL);  // 2 MB
    ushort* Sbuf  = Gbuf + (size_t)NB * NC * Q * Q;                // 25 MB
    // aliases into the Gbuf/Sbuf region (27.3 MB):
    ushort* Abf    = Gbuf;                       // feature bf16: 12.6 MB (dead after gemm1)
    ushort* Wbf_in = Gbuf + (size_t)BLROWS * DMODEL;  // in_proj_w bf16: 5.2 MB (dead after gemm1)
    ushort* ybf    = Gbuf;                       // y bf16: 25.2 MB (written after ychunk)
    ushort* Wbf_out = (ushort*)zxbcdt;           // out_proj_w bf16 (written after rms)

    // 0) casts for in_proj
    cast_kernel<<<dim3((BLROWS*DMODEL/4 + 255)/256), 256, 0, stream>>>(feature, Abf, BLROWS*DMODEL/4);
    cast_kernel<<<dim3((DINPROJ*DMODEL/4 + 255)/256), 256, 0, stream>>>(in_proj_w, Wbf_in, DINPROJ*DMODEL/4);
    // 1) in_proj (bf16 MFMA)
    gemm_mfma<<<dim3(27, 64), 256, 0, stream>>>(Abf, Wbf_in, zxbcdt,
                                                BLROWS, DINPROJ, DMODEL, nullptr);
    // 2) conv + silu
    conv_kernel<<<dim3(BLROWS), 448, 0, stream>>>(zxbcdt, conv_w, conv_b, xconv);
    // 3) dt softplus + chunk-local cumsum of log-decay
    dtscan_kernel<<<dim3(NC, NHEADS, NB), 128, 0, stream>>>(zxbcdt, dt_bias, A_log, dtc, clog);
    // 4) G = C B^T per (b,c)   (clobbers Abf head — dead)
    gcb_kernel<<<dim3(NC, NB), 256, 0, stream>>>(xconv, Gbuf);
    // 5) local chunk states    (clobbers Abf/Wbf_in tail — dead)
    locstate_kernel<<<dim3(NC, NHEADS, NB), 256, 0, stream>>>(xconv, dtc, clog, Sbuf);
    // 6) in-place prefix over chunks
    chunkscan_kernel<<<dim3(NHEADS, NB), 256, 0, stream>>>(clog, Sbuf);
    // 7) Y = intra + inter + D*x
    ychunk_kernel<<<dim3(NC, NHEADS, NB), 256, 0, stream>>>(xconv, dtc, clog, Gbuf, Sbuf, Dvec, ybuf);
    // 8) gated RMSNorm -> bf16  (clobbers G/S — dead)
    rms_kernel<<<dim3(BLROWS), 128, 0, stream>>>(zxbcdt, norm_w, ybuf, ybf);
    // 9) cast out_proj_w into zxbcdt region (zxbcdt dead after rms)
    cast_kernel<<<dim3((DMODEL*DINNER/4 + 255)/256), 256, 0, stream>>>(out_proj_w, Wbf_out, DMODEL*DINNER/4);
    // 10) out_proj (bf16 MFMA) + sigmoid(gate1)
    gemm_mfma<<<dim3(6, 64), 256, 0, stream>>>(ybf, Wbf_out, out,
                                               BLROWS, DMODEL, DINNER, gate1);
}

// Round 4
// 451.180 us; speedup vs baseline: 6.1107x; 1.1402x over previous
//
#include <hip/hip_runtime.h>
#include <cstddef>

#define NB 4
#define SEQL 2048
#define DMODEL 768
#define DSTATE 128
#define HEADDIM 64
#define NHEADS 24
#define DINNER 1536
#define CONVDIM 1792
#define DINPROJ 3352
#define BLROWS (NB*SEQL)
#define RMS_EPS 1e-5f
#define Q 128
#define NC (SEQL/Q)
#define BOFF DINNER
#define COFF (DINNER + DSTATE)

typedef unsigned int uint;
typedef unsigned short ushort;
typedef __attribute__((ext_vector_type(8))) short bf16x8;
typedef __attribute__((ext_vector_type(4))) float f32x4;

__device__ __forceinline__ float sigmoidf_(float x){ return 1.f/(1.f+expf(-x)); }
__device__ __forceinline__ float siluf_(float x){ return x * sigmoidf_(x); }
__device__ __forceinline__ float softplusf_(float x){ return x > 20.f ? x : log1pf(expf(x)); }

__device__ __forceinline__ ushort f2bf(float f){
    union { float f; uint u; } v; v.f = f;
    uint r = (v.u + 0x7FFFu + ((v.u >> 16) & 1u)) >> 16;
    return (ushort)r;
}
__device__ __forceinline__ float bf2f(ushort s){
    union { uint u; float f; } v; v.u = ((uint)s) << 16;
    return v.f;
}
__device__ __forceinline__ uint pack2(float a, float b){
    return (uint)f2bf(a) | ((uint)f2bf(b) << 16);
}
__device__ __forceinline__ void unpack8(uint4 r, float* o){
    o[0]=bf2f((ushort)(r.x&0xffff)); o[1]=bf2f((ushort)(r.x>>16));
    o[2]=bf2f((ushort)(r.y&0xffff)); o[3]=bf2f((ushort)(r.y>>16));
    o[4]=bf2f((ushort)(r.z&0xffff)); o[5]=bf2f((ushort)(r.z>>16));
    o[6]=bf2f((ushort)(r.w&0xffff)); o[7]=bf2f((ushort)(r.w>>16));
}

#define GLD16(g, l) __builtin_amdgcn_global_load_lds( \
    (const __attribute__((address_space(1))) void*)(g), \
    (__attribute__((address_space(3))) void*)(l), 16, 0, 0)

// ---------------- fp32 -> bf16 cast
__global__ __launch_bounds__(256) void cast_kernel(
    const float* __restrict__ in, ushort* __restrict__ out, int n4)
{
    const int i = blockIdx.x*256 + threadIdx.x;
    if (i < n4) {
        float4 v = ((const float4*)in)[i];
        ushort4 o = make_ushort4(f2bf(v.x), f2bf(v.y), f2bf(v.z), f2bf(v.w));
        ((ushort4*)out)[i] = o;
    }
}

// ---------------- MFMA GEMM: C[M,N] = A[M,K] @ W[N,K]^T  (bf16 in, fp32 out)
__global__ __launch_bounds__(256) void gemm_mfma(
    const ushort* __restrict__ A, const ushort* __restrict__ W,
    float* __restrict__ C, int M, int N, int K, const float* __restrict__ gptr)
{
    __shared__ __align__(16) ushort As[128*32];
    __shared__ __align__(16) ushort Bs[128*32];
    const int tid = threadIdx.x;
    const int wv = tid >> 6, ln = tid & 63;
    const int m0 = blockIdx.y * 128, n0 = blockIdx.x * 128;
    const int wm = (wv >> 1) * 64, wn = (wv & 1) * 64;

    const int srow = ln >> 2;
    const int scol = (ln & 3) * 8;
    const ushort* gA0 = A + (size_t)(m0 + wv*32 +      srow) * K + scol;
    const ushort* gA1 = A + (size_t)(m0 + wv*32 + 16 + srow) * K + scol;
    int wr0 = n0 + wv*32 +      srow; if (wr0 >= N) wr0 = N - 1;
    int wr1 = n0 + wv*32 + 16 + srow; if (wr1 >= N) wr1 = N - 1;
    const ushort* gB0 = W + (size_t)wr0 * K + scol;
    const ushort* gB1 = W + (size_t)wr1 * K + scol;
    ushort* lA0 = &As[(wv*32     ) * 32];
    ushort* lA1 = &As[(wv*32 + 16) * 32];
    ushort* lB0 = &Bs[(wv*32     ) * 32];
    ushort* lB1 = &Bs[(wv*32 + 16) * 32];

    f32x4 acc[4][4];
#pragma unroll
    for (int i = 0; i < 4; ++i)
#pragma unroll
        for (int j = 0; j < 4; ++j) acc[i][j] = (f32x4){0.f, 0.f, 0.f, 0.f};

    const int fr = ln & 15;
    const int fk = (ln >> 4) * 8;

    for (int kt = 0; kt < K; kt += 32) {
        __syncthreads();
        GLD16(gA0 + kt, lA0);
        GLD16(gA1 + kt, lA1);
        GLD16(gB0 + kt, lB0);
        GLD16(gB1 + kt, lB1);
        __syncthreads();
        bf16x8 af[4], bfr[4];
#pragma unroll
        for (int i = 0; i < 4; ++i)
            af[i] = *(const bf16x8*)&As[(wm + i*16 + fr) * 32 + fk];
#pragma unroll
        for (int j = 0; j < 4; ++j)
            bfr[j] = *(const bf16x8*)&Bs[(wn + j*16 + fr) * 32 + fk];
#pragma unroll
        for (int i = 0; i < 4; ++i)
#pragma unroll
            for (int j = 0; j < 4; ++j)
                acc[i][j] = __builtin_amdgcn_mfma_f32_16x16x32_bf16(af[i], bfr[j], acc[i][j], 0, 0, 0);
    }

    float scale = 1.f;
    if (gptr) scale = sigmoidf_(*gptr);
    const int cn = ln & 15;
    const int cr = (ln >> 4) * 4;
#pragma unroll
    for (int i = 0; i < 4; ++i) {
        const int mb = m0 + wm + i*16 + cr;
#pragma unroll
        for (int j = 0; j < 4; ++j) {
            const int n = n0 + wn + j*16 + cn;
            if (n < N) {
                float* cp = C + (size_t)mb * N + n;
                cp[0*(size_t)N] = acc[i][j].x * scale;
                cp[1*(size_t)N] = acc[i][j].y * scale;
                cp[2*(size_t)N] = acc[i][j].z * scale;
                cp[3*(size_t)N] = acc[i][j].w * scale;
            }
        }
    }
}

// ---------------- causal depthwise conv1d + bias + silu
__global__ __launch_bounds__(448) void conv_kernel(
    const float* __restrict__ zxbcdt, const float* __restrict__ conv_w,
    const float* __restrict__ conv_b, float* __restrict__ xconv)
{
    const int c4 = threadIdx.x;
    const int bl = blockIdx.x;
    const int l = bl & (SEQL - 1);
    float w[4][4];
#pragma unroll
    for (int j = 0; j < 4; ++j) {
        float4 wr = *(const float4*)(conv_w + (c4*4 + j)*4);
        w[j][0]=wr.x; w[j][1]=wr.y; w[j][2]=wr.z; w[j][3]=wr.w;
    }
    float4 bias = *(const float4*)(conv_b + c4*4);
    float s[4] = {bias.x, bias.y, bias.z, bias.w};
#pragma unroll
    for (int k = 0; k < 4; ++k) {
        const int ls = l - 3 + k;
        if (ls >= 0) {
            const float4 xv = *(const float4*)(zxbcdt + (size_t)(bl - 3 + k)*DINPROJ + DINNER + c4*4);
            s[0] = fmaf(xv.x, w[0][k], s[0]);
            s[1] = fmaf(xv.y, w[1][k], s[1]);
            s[2] = fmaf(xv.z, w[2][k], s[2]);
            s[3] = fmaf(xv.w, w[3][k], s[3]);
        }
    }
    float4 o = make_float4(siluf_(s[0]), siluf_(s[1]), siluf_(s[2]), siluf_(s[3]));
    *(float4*)(xconv + (size_t)bl*CONVDIM + c4*4) = o;
}

// ---------------- dt = softplus(dt+bias); clog = chunk-local inclusive cumsum of A*dt
__global__ __launch_bounds__(128) void dtscan_kernel(
    const float* __restrict__ zxbcdt, const float* __restrict__ dt_bias,
    const float* __restrict__ A_log, float* __restrict__ dtc, float* __restrict__ clog)
{
    const int c = blockIdx.x, h = blockIdx.y, b = blockIdx.z;
    const int t = threadIdx.x;
    const int bl = b*SEQL + c*Q + t;
    float draw = zxbcdt[(size_t)bl*DINPROJ + DINNER + CONVDIM + h] + dt_bias[h];
    float dtv = softplusf_(draw);
    float la = -expf(A_log[h]) * dtv;
    const int lane = t & 63;
    float v = la;
#pragma unroll
    for (int off = 1; off < 64; off <<= 1) {
        float u = __shfl_up(v, off);
        if (lane >= off) v += u;
    }
    __shared__ float w0tot;
    if (t == 63) w0tot = v;
    __syncthreads();
    if (t >= 64) v += w0tot;
    const int idx = (b*NHEADS + h)*SEQL + c*Q + t;
    dtc[idx] = dtv;
    clog[idx] = v;
}

// ---------------- G[t][s] = C_t . B_s  via MFMA; block covers 64 t x 128 s
__global__ __launch_bounds__(256) void gcb_mfma(
    const float* __restrict__ xconv, ushort* __restrict__ G)
{
    __shared__ __align__(16) ushort Ca[64*32];
    __shared__ __align__(16) ushort Bb[128*32];
    const int thalf = blockIdx.x, c = blockIdx.y, b = blockIdx.z;
    const int tid = threadIdx.x;
    const int wv = tid >> 6, ln = tid & 63;
    const int fr = ln & 15, fq = ln >> 4, fk = fq*8;
    const int bl0 = b*SEQL + c*Q;
    const int th0 = thalf*64;

    const int sat = tid & 63,  sac = (tid >> 6)*8;   // Ca staging: t-row, 8-col chunk
    const int sbt = tid & 127, sbh = (tid >> 7)*16;  // Bb staging: s-row, 16-col half

    f32x4 acc[4][2];
#pragma unroll
    for (int i = 0; i < 4; ++i)
#pragma unroll
        for (int j = 0; j < 2; ++j) acc[i][j] = (f32x4){0.f,0.f,0.f,0.f};

    for (int ks = 0; ks < 4; ++ks) {
        const float* ar = xconv + (size_t)(bl0 + th0 + sat)*CONVDIM + COFF + ks*32 + sac;
        float4 a0 = *(const float4*)ar;
        float4 a1 = *(const float4*)(ar + 4);
        const float* br = xconv + (size_t)(bl0 + sbt)*CONVDIM + BOFF + ks*32 + sbh;
        float4 b0 = *(const float4*)br;
        float4 b1 = *(const float4*)(br + 4);
        float4 b2 = *(const float4*)(br + 8);
        float4 b3 = *(const float4*)(br + 12);
        __syncthreads();
        *(uint4*)&Ca[sat*32 + sac] =
            make_uint4(pack2(a0.x,a0.y), pack2(a0.z,a0.w), pack2(a1.x,a1.y), pack2(a1.z,a1.w));
        *(uint4*)&Bb[sbt*32 + sbh] =
            make_uint4(pack2(b0.x,b0.y), pack2(b0.z,b0.w), pack2(b1.x,b1.y), pack2(b1.z,b1.w));
        *(uint4*)&Bb[sbt*32 + sbh + 8] =
            make_uint4(pack2(b2.x,b2.y), pack2(b2.z,b2.w), pack2(b3.x,b3.y), pack2(b3.z,b3.w));
        __syncthreads();
        bf16x8 av[4], bv[2];
#pragma unroll
        for (int i = 0; i < 4; ++i)
            av[i] = *(const bf16x8*)&Ca[(i*16 + fr)*32 + fk];
#pragma unroll
        for (int j = 0; j < 2; ++j)
            bv[j] = *(const bf16x8*)&Bb[(wv*32 + j*16 + fr)*32 + fk];
#pragma unroll
        for (int i = 0; i < 4; ++i)
#pragma unroll
            for (int j = 0; j < 2; ++j)
                acc[i][j] = __builtin_amdgcn_mfma_f32_16x16x32_bf16(av[i], bv[j], acc[i][j], 0, 0, 0);
    }
    ushort* gout = G + (size_t)(b*NC + c)*(Q*Q);
#pragma unroll
    for (int i = 0; i < 4; ++i) {
#pragma unroll
        for (int j = 0; j < 2; ++j) {
            const int s = wv*32 + j*16 + fr;
#pragma unroll
            for (int r = 0; r < 4; ++r) {
                const int t = th0 + i*16 + fq*4 + r;
                gout[t*Q + s] = f2bf(acc[i][j][r]);
            }
        }
    }
}

// ---------------- local chunk state: S[p][n] = sum_s w_s * x_s[p] * B_s[n] (bf16 out)
__global__ __launch_bounds__(256) void locstate_kernel(
    const float* __restrict__ xconv, const float* __restrict__ dtc,
    const float* __restrict__ clog, ushort* __restrict__ Sloc)
{
    const int c = blockIdx.x, h = blockIdx.y, b = blockIdx.z;
    __shared__ __align__(16) float Xs[32*64];
    __shared__ __align__(16) float Bs[32*128];
    __shared__ float sw[Q];
    const int tid = threadIdx.x;
    const int p0 = (tid >> 4) * 4, n0 = (tid & 15) * 8;
    const int bh = b*NHEADS + h;
    if (tid < Q) {
        const float ce = clog[(size_t)bh*SEQL + c*Q + (Q-1)];
        const float cs = clog[(size_t)bh*SEQL + c*Q + tid];
        sw[tid] = dtc[(size_t)bh*SEQL + c*Q + tid] * expf(ce - cs);
    }
    float acc[4][8];
#pragma unroll
    for (int i = 0; i < 4; ++i)
#pragma unroll
        for (int j = 0; j < 8; ++j) acc[i][j] = 0.f;

    const size_t rowbase = (size_t)(b*SEQL + c*Q) * CONVDIM;
    for (int st = 0; st < 4; ++st) {
        __syncthreads();
#pragma unroll
        for (int k = 0; k < 2; ++k) {
            const int q = tid + k*256;
            const int s = q >> 4, p4 = (q & 15)*4;
            *(float4*)&Xs[s*64 + p4] =
                *(const float4*)(xconv + rowbase + (size_t)(st*32 + s)*CONVDIM + h*HEADDIM + p4);
        }
#pragma unroll
        for (int k = 0; k < 4; ++k) {
            const int q = tid + k*256;
            const int s = q >> 5, n4 = (q & 31)*4;
            *(float4*)&Bs[s*128 + n4] =
                *(const float4*)(xconv + rowbase + (size_t)(st*32 + s)*CONVDIM + DINNER + n4);
        }
        __syncthreads();
#pragma unroll
        for (int s = 0; s < 32; ++s) {
            const float ws = sw[st*32 + s];
            const float4 xv = *(const float4*)&Xs[s*64 + p0];
            const float4 b0 = *(const float4*)&Bs[s*128 + n0];
            const float4 b1 = *(const float4*)&Bs[s*128 + n0 + 4];
            const float xs[4] = {ws*xv.x, ws*xv.y, ws*xv.z, ws*xv.w};
            const float bv[8] = {b0.x,b0.y,b0.z,b0.w,b1.x,b1.y,b1.z,b1.w};
#pragma unroll
            for (int i = 0; i < 4; ++i)
#pragma unroll
                for (int j = 0; j < 8; ++j)
                    acc[i][j] = fmaf(xs[i], bv[j], acc[i][j]);
        }
    }
    ushort* dst = Sloc + (size_t)((b*NC + c)*NHEADS + h) * (HEADDIM*DSTATE);
#pragma unroll
    for (int i = 0; i < 4; ++i) {
        uint4 o = make_uint4(pack2(acc[i][0],acc[i][1]), pack2(acc[i][2],acc[i][3]),
                             pack2(acc[i][4],acc[i][5]), pack2(acc[i][6],acc[i][7]));
        *(uint4*)(dst + (p0 + i)*DSTATE + n0) = o;
    }
}

// ---------------- in-place sequential prefix over chunk states (16 steps)
__global__ __launch_bounds__(256) void chunkscan_kernel(
    const float* __restrict__ clog, ushort* __restrict__ S)
{
    const int h = blockIdx.x, b = blockIdx.y;
    const int tid = threadIdx.x;
    const int p0 = (tid >> 4) * 4, n0 = (tid & 15) * 8;
    const int bh = b*NHEADS + h;
    float st[4][8];
#pragma unroll
    for (int i = 0; i < 4; ++i)
#pragma unroll
        for (int j = 0; j < 8; ++j) st[i][j] = 0.f;

    for (int c = 0; c < NC; ++c) {
        const float tc = expf(clog[(size_t)bh*SEQL + c*Q + (Q-1)]);
        ushort* base = S + (size_t)((b*NC + c)*NHEADS + h) * (HEADDIM*DSTATE);
#pragma unroll
        for (int i = 0; i < 4; ++i) {
            uint4 raw = *(uint4*)(base + (p0 + i)*DSTATE + n0);
            float lv[8];
            unpack8(raw, lv);
            uint4 pre = make_uint4(pack2(st[i][0],st[i][1]), pack2(st[i][2],st[i][3]),
                                   pack2(st[i][4],st[i][5]), pack2(st[i][6],st[i][7]));
            *(uint4*)(base + (p0 + i)*DSTATE + n0) = pre;
#pragma unroll
            for (int j = 0; j < 8; ++j) st[i][j] = fmaf(tc, st[i][j], lv[j]);
        }
    }
}

// ---------------- Y = causal(G.W)@X + exp(clog)*C@Sp^T + D*x  — MFMA version
// block: (c,h,b); Y tile 128t x 64p; wave wv owns t in [32wv, 32wv+32).
__global__ __launch_bounds__(256) void ychunk_mfma(
    const float* __restrict__ xconv, const float* __restrict__ dtc,
    const float* __restrict__ clog, const ushort* __restrict__ G,
    const ushort* __restrict__ Sp, const float* __restrict__ Dv,
    float* __restrict__ ybuf)
{
    __shared__ __align__(16) ushort Ab[128*32];   // phase1: C bf16 ; phase2: Gw
    __shared__ __align__(16) ushort Bb[64*32];    // phase1: Sp    ; phase2: X^T
    __shared__ float s_clog[Q];
    __shared__ float s_dtc[Q];
    const int c = blockIdx.x, h = blockIdx.y, b = blockIdx.z;
    const int tid = threadIdx.x;
    const int wv = tid >> 6, ln = tid & 63;
    const int bh = b*NHEADS + h;
    const int bl0 = b*SEQL + c*Q;
    const int fr = ln & 15, fq = ln >> 4, fk = fq*8;

    if (tid < Q) {
        s_clog[tid] = clog[(size_t)bh*SEQL + c*Q + tid];
        s_dtc[tid]  = dtc [(size_t)bh*SEQL + c*Q + tid];
    }

    f32x4 acc[2][4];
#pragma unroll
    for (int i = 0; i < 2; ++i)
#pragma unroll
        for (int j = 0; j < 4; ++j) acc[i][j] = (f32x4){0.f,0.f,0.f,0.f};

    const int sgt = tid & 127, sgh = (tid >> 7)*16;  // Ab staging: row, 16-col half
    const int sbp = tid & 63,  sbc = (tid >> 6)*8;   // Bb staging: row, 8-col chunk
    const ushort* spb = Sp + (size_t)((b*NC + c)*NHEADS + h)*(HEADDIM*DSTATE);

    // ---- phase 1: acc = C @ Sp^T   (K = n = 128)
    for (int ks = 0; ks < 4; ++ks) {
        const float* cr = xconv + (size_t)(bl0 + sgt)*CONVDIM + COFF + ks*32 + sgh;
        float4 c0 = *(const float4*)cr;
        float4 c1 = *(const float4*)(cr + 4);
        float4 c2 = *(const float4*)(cr + 8);
        float4 c3 = *(const float4*)(cr + 12);
        uint4 sv = *(const uint4*)(spb + sbp*DSTATE + ks*32 + sbc);
        __syncthreads();
        *(uint4*)&Ab[sgt*32 + sgh] =
            make_uint4(pack2(c0.x,c0.y), pack2(c0.z,c0.w), pack2(c1.x,c1.y), pack2(c1.z,c1.w));
        *(uint4*)&Ab[sgt*32 + sgh + 8] =
            make_uint4(pack2(c2.x,c2.y), pack2(c2.z,c2.w), pack2(c3.x,c3.y), pack2(c3.z,c3.w));
        *(uint4*)&Bb[sbp*32 + sbc] = sv;
        __syncthreads();
        bf16x8 af[2], bv[4];
        af[0] = *(const bf16x8*)&Ab[(wv*32 +      fr)*32 + fk];
        af[1] = *(const bf16x8*)&Ab[(wv*32 + 16 + fr)*32 + fk];
#pragma unroll
        for (int j = 0; j < 4; ++j)
            bv[j] = *(const bf16x8*)&Bb[(j*16 + fr)*32 + fk];
#pragma unroll
        for (int i = 0; i < 2; ++i)
#pragma unroll
            for (int j = 0; j < 4; ++j)
                acc[i][j] = __builtin_amdgcn_mfma_f32_16x16x32_bf16(af[i], bv[j], acc[i][j], 0, 0, 0);
    }
    // scale by exp(clog_t)
#pragma unroll
    for (int i = 0; i < 2; ++i) {
        const int tb = wv*32 + i*16 + fq*4;
        float e0 = expf(s_clog[tb+0]), e1 = expf(s_clog[tb+1]);
        float e2 = expf(s_clog[tb+2]), e3 = expf(s_clog[tb+3]);
#pragma unroll
        for (int j = 0; j < 4; ++j) {
            acc[i][j].x *= e0; acc[i][j].y *= e1; acc[i][j].z *= e2; acc[i][j].w *= e3;
        }
    }

    // ---- phase 2: acc += (G .* W) @ X   (K = s = 128, causal)
    const ushort* gp = G + (size_t)(b*NC + c)*(Q*Q);
    for (int ks = 0; ks < 4; ++ks) {
        uint4 g0 = *(const uint4*)(gp + sgt*Q + ks*32 + sgh);
        uint4 g1 = *(const uint4*)(gp + sgt*Q + ks*32 + sgh + 8);
        float xv[8];
#pragma unroll
        for (int j = 0; j < 8; ++j)
            xv[j] = xconv[(size_t)(bl0 + ks*32 + sbc + j)*CONVDIM + h*HEADDIM + sbp];
        __syncthreads();
        {
            float gvals[16];
            unpack8(g0, gvals);
            unpack8(g1, gvals + 8);
            const float ct = s_clog[sgt];
            ushort gw[16];
#pragma unroll
            for (int j = 0; j < 16; ++j) {
                const int s = ks*32 + sgh + j;
                float w = 0.f;
                if (s <= sgt) w = s_dtc[s] * expf(ct - s_clog[s]);
                gw[j] = f2bf(gvals[j] * w);
            }
            uint4 w0, w1;
            w0.x = (uint)gw[0] | ((uint)gw[1]<<16);  w0.y = (uint)gw[2] | ((uint)gw[3]<<16);
            w0.z = (uint)gw[4] | ((uint)gw[5]<<16);  w0.w = (uint)gw[6] | ((uint)gw[7]<<16);
            w1.x = (uint)gw[8] | ((uint)gw[9]<<16);  w1.y = (uint)gw[10]| ((uint)gw[11]<<16);
            w1.z = (uint)gw[12]| ((uint)gw[13]<<16); w1.w = (uint)gw[14]| ((uint)gw[15]<<16);
            *(uint4*)&Ab[sgt*32 + sgh]     = w0;
            *(uint4*)&Ab[sgt*32 + sgh + 8] = w1;
            *(uint4*)&Bb[sbp*32 + sbc] =
                make_uint4(pack2(xv[0],xv[1]), pack2(xv[2],xv[3]),
                           pack2(xv[4],xv[5]), pack2(xv[6],xv[7]));
        }
        __syncthreads();
        if (ks <= wv) {
            bf16x8 af[2], bv[4];
            af[0] = *(const bf16x8*)&Ab[(wv*32 +      fr)*32 + fk];
            af[1] = *(const bf16x8*)&Ab[(wv*32 + 16 + fr)*32 + fk];
#pragma unroll
            for (int j = 0; j < 4; ++j)
                bv[j] = *(const bf16x8*)&Bb[(j*16 + fr)*32 + fk];
#pragma unroll
            for (int i = 0; i < 2; ++i)
#pragma unroll
                for (int j = 0; j < 4; ++j)
                    acc[i][j] = __builtin_amdgcn_mfma_f32_16x16x32_bf16(af[i], bv[j], acc[i][j], 0, 0, 0);
        }
    }

    // ---- epilogue: + D*x, store fp32
    const float Dh = Dv[h];
#pragma unroll
    for (int i = 0; i < 2; ++i) {
#pragma unroll
        for (int r = 0; r < 4; ++r) {
            const int t = wv*32 + i*16 + fq*4 + r;
            const float* xr = xconv + (size_t)(bl0 + t)*CONVDIM + h*HEADDIM;
            float* yr = ybuf + (size_t)(bl0 + t)*DINNER + h*HEADDIM;
#pragma unroll
            for (int j = 0; j < 4; ++j) {
                const int p = j*16 + fr;
                yr[p] = acc[i][j][r] + Dh * xr[p];
            }
        }
    }
}

// ---------------- gated RMSNorm -> bf16 output
__global__ __launch_bounds__(128) void rms_kernel(
    const float* __restrict__ zxbcdt, const float* __restrict__ norm_w,
    const float* __restrict__ ybuf, ushort* __restrict__ ybf)
{
    const int row = blockIdx.x;
    const int tid = threadIdx.x;
    const float* zr = zxbcdt + (size_t)row * DINPROJ;
    const float* yr = ybuf + (size_t)row * DINNER;
    ushort* yo = ybf + (size_t)row * DINNER;
    float v[12];
    float ss = 0.f;
#pragma unroll
    for (int i = 0; i < 3; ++i) {
        const int o = (tid + i*128) * 4;
        float4 yv = *(const float4*)(yr + o);
        float4 zv = *(const float4*)(zr + o);
        float a = yv.x * siluf_(zv.x);
        float b = yv.y * siluf_(zv.y);
        float cc = yv.z * siluf_(zv.z);
        float d = yv.w * siluf_(zv.w);
        v[i*4+0]=a; v[i*4+1]=b; v[i*4+2]=cc; v[i*4+3]=d;
        ss += a*a + b*b + cc*cc + d*d;
    }
#pragma unroll
    for (int off = 1; off < 64; off <<= 1) ss += __shfl_xor(ss, off);
    __shared__ float red[2];
    if ((tid & 63) == 0) red[tid >> 6] = ss;
    __syncthreads();
    const float rstd = rsqrtf((red[0] + red[1]) * (1.f/DINNER) + RMS_EPS);
#pragma unroll
    for (int i = 0; i < 3; ++i) {
        const int o = (tid + i*128) * 4;
        float4 wv = *(const float4*)(norm_w + o);
        ushort4 ov = make_ushort4(f2bf(v[i*4+0]*rstd*wv.x), f2bf(v[i*4+1]*rstd*wv.y),
                                  f2bf(v[i*4+2]*rstd*wv.z), f2bf(v[i*4+3]*rstd*wv.w));
        *(ushort4*)(yo + o) = ov;
    }
}

extern "C" void kernel_launch(void* const* d_in, const int* in_sizes, int n_in,
                              void* d_out, int out_size, void* d_ws, size_t ws_size,
                              hipStream_t stream)
{
    const float* feature    = (const float*)d_in[0];
    const float* in_proj_w  = (const float*)d_in[1];
    const float* conv_w     = (const float*)d_in[2];
    const float* conv_b     = (const float*)d_in[3];
    const float* dt_bias    = (const float*)d_in[4];
    const float* A_log      = (const float*)d_in[5];
    const float* Dvec       = (const float*)d_in[6];
    const float* norm_w     = (const float*)d_in[7];
    const float* out_proj_w = (const float*)d_in[8];
    const float* gate1      = (const float*)d_in[9];
    float* out = (float*)d_out;

    float* zxbcdt = (float*)d_ws;                               // 8192*3352 fp32
    float* xconv  = zxbcdt + (size_t)BLROWS * DINPROJ;          // 8192*1792 fp32
    float* ybuf   = xconv  + (size_t)BLROWS * CONVDIM;          // 8192*1536 fp32
    float* dtc    = ybuf   + (size_t)BLROWS * DINNER;
    float* clog   = dtc    + (size_t)NB * NHEADS * SEQL;
    ushort* Gbuf  = (ushort*)(clog + (size_t)NB * NHEADS * SEQL);  // 2 MB
    ushort* Sbuf  = Gbuf + (size_t)NB * NC * Q * Q;                // 25 MB
    ushort* Abf    = Gbuf;                            // feature bf16 (dead after gemm1)
    ushort* Wbf_in = Gbuf + (size_t)BLROWS * DMODEL;  // in_proj_w bf16 (dead after gemm1)
    ushort* ybf    = Gbuf;                            // y bf16 (after ychunk)
    ushort* Wbf_out = (ushort*)zxbcdt;                // out_proj_w bf16 (after rms)

    cast_kernel<<<dim3((BLROWS*DMODEL/4 + 255)/256), 256, 0, stream>>>(feature, Abf, BLROWS*DMODEL/4);
    cast_kernel<<<dim3((DINPROJ*DMODEL/4 + 255)/256), 256, 0, stream>>>(in_proj_w, Wbf_in, DINPROJ*DMODEL/4);
    gemm_mfma<<<dim3(27, 64), 256, 0, stream>>>(Abf, Wbf_in, zxbcdt,
                                                BLROWS, DINPROJ, DMODEL, nullptr);
    conv_kernel<<<dim3(BLROWS), 448, 0, stream>>>(zxbcdt, conv_w, conv_b, xconv);
    dtscan_kernel<<<dim3(NC, NHEADS, NB), 128, 0, stream>>>(zxbcdt, dt_bias, A_log, dtc, clog);
    gcb_mfma<<<dim3(2, NC, NB), 256, 0, stream>>>(xconv, Gbuf);
    locstate_kernel<<<dim3(NC, NHEADS, NB), 256, 0, stream>>>(xconv, dtc, clog, Sbuf);
    chunkscan_kernel<<<dim3(NHEADS, NB), 256, 0, stream>>>(clog, Sbuf);
    ychunk_mfma<<<dim3(NC, NHEADS, NB), 256, 0, stream>>>(xconv, dtc, clog, Gbuf, Sbuf, Dvec, ybuf);
    rms_kernel<<<dim3(BLROWS), 128, 0, stream>>>(zxbcdt, norm_w, ybuf, ybf);
    cast_kernel<<<dim3((DMODEL*DINNER/4 + 255)/256), 256, 0, stream>>>(out_proj_w, Wbf_out, DMODEL*DINNER/4);
    gemm_mfma<<<dim3(6, 64), 256, 0, stream>>>(ybf, Wbf_out, out,
                                               BLROWS, DMODEL, DINNER, gate1);
}

// Round 5
// 385.399 us; speedup vs baseline: 7.1536x; 1.1707x over previous
//
#include <hip/hip_runtime.h>
#include <cstddef>

#define NB 4
#define SEQL 2048
#define DMODEL 768
#define DSTATE 128
#define HEADDIM 64
#define NHEADS 24
#define DINNER 1536
#define CONVDIM 1792
#define DINPROJ 3352
#define BLROWS (NB*SEQL)
#define RMS_EPS 1e-5f
#define Q 128
#define NC (SEQL/Q)
#define BOFF DINNER
#define COFF (DINNER + DSTATE)

typedef unsigned int uint;
typedef unsigned short ushort;
typedef __attribute__((ext_vector_type(8))) short bf16x8;
typedef __attribute__((ext_vector_type(4))) float f32x4;

__device__ __forceinline__ float sigmoidf_(float x){ return 1.f/(1.f+expf(-x)); }
__device__ __forceinline__ float siluf_(float x){ return x * sigmoidf_(x); }
__device__ __forceinline__ float softplusf_(float x){ return x > 20.f ? x : log1pf(expf(x)); }

__device__ __forceinline__ ushort f2bf(float f){
    union { float f; uint u; } v; v.f = f;
    uint r = (v.u + 0x7FFFu + ((v.u >> 16) & 1u)) >> 16;
    return (ushort)r;
}
__device__ __forceinline__ float bf2f(ushort s){
    union { uint u; float f; } v; v.u = ((uint)s) << 16;
    return v.f;
}
__device__ __forceinline__ uint pack2(float a, float b){
    return (uint)f2bf(a) | ((uint)f2bf(b) << 16);
}
__device__ __forceinline__ void unpack8(uint4 r, float* o){
    o[0]=bf2f((ushort)(r.x&0xffff)); o[1]=bf2f((ushort)(r.x>>16));
    o[2]=bf2f((ushort)(r.y&0xffff)); o[3]=bf2f((ushort)(r.y>>16));
    o[4]=bf2f((ushort)(r.z&0xffff)); o[5]=bf2f((ushort)(r.z>>16));
    o[6]=bf2f((ushort)(r.w&0xffff)); o[7]=bf2f((ushort)(r.w>>16));
}

#define GLD16(g, l) __builtin_amdgcn_global_load_lds( \
    (const __attribute__((address_space(1))) void*)(g), \
    (__attribute__((address_space(3))) void*)(l), 16, 0, 0)

// ---------------- fp32 -> bf16 cast
__global__ __launch_bounds__(256) void cast_kernel(
    const float* __restrict__ in, ushort* __restrict__ out, int n4)
{
    const int i = blockIdx.x*256 + threadIdx.x;
    if (i < n4) {
        float4 v = ((const float4*)in)[i];
        ushort4 o = make_ushort4(f2bf(v.x), f2bf(v.y), f2bf(v.z), f2bf(v.w));
        ((ushort4*)out)[i] = o;
    }
}

// ---------------- MFMA GEMM: C[M,N] = A[M,K] @ W[N,K]^T  (bf16 in, fp32 out)
__global__ __launch_bounds__(256) void gemm_mfma(
    const ushort* __restrict__ A, const ushort* __restrict__ W,
    float* __restrict__ C, int M, int N, int K, const float* __restrict__ gptr)
{
    __shared__ __align__(16) ushort As[128*32];
    __shared__ __align__(16) ushort Bs[128*32];
    const int tid = threadIdx.x;
    const int wv = tid >> 6, ln = tid & 63;
    const int m0 = blockIdx.y * 128, n0 = blockIdx.x * 128;
    const int wm = (wv >> 1) * 64, wn = (wv & 1) * 64;

    const int srow = ln >> 2;
    const int scol = (ln & 3) * 8;
    const ushort* gA0 = A + (size_t)(m0 + wv*32 +      srow) * K + scol;
    const ushort* gA1 = A + (size_t)(m0 + wv*32 + 16 + srow) * K + scol;
    int wr0 = n0 + wv*32 +      srow; if (wr0 >= N) wr0 = N - 1;
    int wr1 = n0 + wv*32 + 16 + srow; if (wr1 >= N) wr1 = N - 1;
    const ushort* gB0 = W + (size_t)wr0 * K + scol;
    const ushort* gB1 = W + (size_t)wr1 * K + scol;
    ushort* lA0 = &As[(wv*32     ) * 32];
    ushort* lA1 = &As[(wv*32 + 16) * 32];
    ushort* lB0 = &Bs[(wv*32     ) * 32];
    ushort* lB1 = &Bs[(wv*32 + 16) * 32];

    f32x4 acc[4][4];
#pragma unroll
    for (int i = 0; i < 4; ++i)
#pragma unroll
        for (int j = 0; j < 4; ++j) acc[i][j] = (f32x4){0.f, 0.f, 0.f, 0.f};

    const int fr = ln & 15;
    const int fk = (ln >> 4) * 8;

    for (int kt = 0; kt < K; kt += 32) {
        __syncthreads();
        GLD16(gA0 + kt, lA0);
        GLD16(gA1 + kt, lA1);
        GLD16(gB0 + kt, lB0);
        GLD16(gB1 + kt, lB1);
        __syncthreads();
        bf16x8 af[4], bfr[4];
#pragma unroll
        for (int i = 0; i < 4; ++i)
            af[i] = *(const bf16x8*)&As[(wm + i*16 + fr) * 32 + fk];
#pragma unroll
        for (int j = 0; j < 4; ++j)
            bfr[j] = *(const bf16x8*)&Bs[(wn + j*16 + fr) * 32 + fk];
#pragma unroll
        for (int i = 0; i < 4; ++i)
#pragma unroll
            for (int j = 0; j < 4; ++j)
                acc[i][j] = __builtin_amdgcn_mfma_f32_16x16x32_bf16(af[i], bfr[j], acc[i][j], 0, 0, 0);
    }

    float scale = 1.f;
    if (gptr) scale = sigmoidf_(*gptr);
    const int cn = ln & 15;
    const int cr = (ln >> 4) * 4;
#pragma unroll
    for (int i = 0; i < 4; ++i) {
        const int mb = m0 + wm + i*16 + cr;
#pragma unroll
        for (int j = 0; j < 4; ++j) {
            const int n = n0 + wn + j*16 + cn;
            if (n < N) {
                float* cp = C + (size_t)mb * N + n;
                cp[0*(size_t)N] = acc[i][j].x * scale;
                cp[1*(size_t)N] = acc[i][j].y * scale;
                cp[2*(size_t)N] = acc[i][j].z * scale;
                cp[3*(size_t)N] = acc[i][j].w * scale;
            }
        }
    }
}

// ---------------- causal depthwise conv1d + bias + silu
__global__ __launch_bounds__(448) void conv_kernel(
    const float* __restrict__ zxbcdt, const float* __restrict__ conv_w,
    const float* __restrict__ conv_b, float* __restrict__ xconv)
{
    const int c4 = threadIdx.x;
    const int bl = blockIdx.x;
    const int l = bl & (SEQL - 1);
    float w[4][4];
#pragma unroll
    for (int j = 0; j < 4; ++j) {
        float4 wr = *(const float4*)(conv_w + (c4*4 + j)*4);
        w[j][0]=wr.x; w[j][1]=wr.y; w[j][2]=wr.z; w[j][3]=wr.w;
    }
    float4 bias = *(const float4*)(conv_b + c4*4);
    float s[4] = {bias.x, bias.y, bias.z, bias.w};
#pragma unroll
    for (int k = 0; k < 4; ++k) {
        const int ls = l - 3 + k;
        if (ls >= 0) {
            const float4 xv = *(const float4*)(zxbcdt + (size_t)(bl - 3 + k)*DINPROJ + DINNER + c4*4);
            s[0] = fmaf(xv.x, w[0][k], s[0]);
            s[1] = fmaf(xv.y, w[1][k], s[1]);
            s[2] = fmaf(xv.z, w[2][k], s[2]);
            s[3] = fmaf(xv.w, w[3][k], s[3]);
        }
    }
    float4 o = make_float4(siluf_(s[0]), siluf_(s[1]), siluf_(s[2]), siluf_(s[3]));
    *(float4*)(xconv + (size_t)bl*CONVDIM + c4*4) = o;
}

// ---------------- dt = softplus(dt+bias); clog = chunk-local inclusive cumsum of A*dt
__global__ __launch_bounds__(128) void dtscan_kernel(
    const float* __restrict__ zxbcdt, const float* __restrict__ dt_bias,
    const float* __restrict__ A_log, float* __restrict__ dtc, float* __restrict__ clog)
{
    const int c = blockIdx.x, h = blockIdx.y, b = blockIdx.z;
    const int t = threadIdx.x;
    const int bl = b*SEQL + c*Q + t;
    float draw = zxbcdt[(size_t)bl*DINPROJ + DINNER + CONVDIM + h] + dt_bias[h];
    float dtv = softplusf_(draw);
    float la = -expf(A_log[h]) * dtv;
    const int lane = t & 63;
    float v = la;
#pragma unroll
    for (int off = 1; off < 64; off <<= 1) {
        float u = __shfl_up(v, off);
        if (lane >= off) v += u;
    }
    __shared__ float w0tot;
    if (t == 63) w0tot = v;
    __syncthreads();
    if (t >= 64) v += w0tot;
    const int idx = (b*NHEADS + h)*SEQL + c*Q + t;
    dtc[idx] = dtv;
    clog[idx] = v;
}

// ---------------- G[t][s] = C_t . B_s  via MFMA; block covers 64 t x 128 s
__global__ __launch_bounds__(256) void gcb_mfma(
    const float* __restrict__ xconv, ushort* __restrict__ G)
{
    __shared__ __align__(16) ushort Ca[64*32];
    __shared__ __align__(16) ushort Bb[128*32];
    const int thalf = blockIdx.x, c = blockIdx.y, b = blockIdx.z;
    const int tid = threadIdx.x;
    const int wv = tid >> 6, ln = tid & 63;
    const int fr = ln & 15, fq = ln >> 4, fk = fq*8;
    const int bl0 = b*SEQL + c*Q;
    const int th0 = thalf*64;

    const int sat = tid & 63,  sac = (tid >> 6)*8;
    const int sbt = tid & 127, sbh = (tid >> 7)*16;

    f32x4 acc[4][2];
#pragma unroll
    for (int i = 0; i < 4; ++i)
#pragma unroll
        for (int j = 0; j < 2; ++j) acc[i][j] = (f32x4){0.f,0.f,0.f,0.f};

    for (int ks = 0; ks < 4; ++ks) {
        const float* ar = xconv + (size_t)(bl0 + th0 + sat)*CONVDIM + COFF + ks*32 + sac;
        float4 a0 = *(const float4*)ar;
        float4 a1 = *(const float4*)(ar + 4);
        const float* br = xconv + (size_t)(bl0 + sbt)*CONVDIM + BOFF + ks*32 + sbh;
        float4 b0 = *(const float4*)br;
        float4 b1 = *(const float4*)(br + 4);
        float4 b2 = *(const float4*)(br + 8);
        float4 b3 = *(const float4*)(br + 12);
        __syncthreads();
        *(uint4*)&Ca[sat*32 + sac] =
            make_uint4(pack2(a0.x,a0.y), pack2(a0.z,a0.w), pack2(a1.x,a1.y), pack2(a1.z,a1.w));
        *(uint4*)&Bb[sbt*32 + sbh] =
            make_uint4(pack2(b0.x,b0.y), pack2(b0.z,b0.w), pack2(b1.x,b1.y), pack2(b1.z,b1.w));
        *(uint4*)&Bb[sbt*32 + sbh + 8] =
            make_uint4(pack2(b2.x,b2.y), pack2(b2.z,b2.w), pack2(b3.x,b3.y), pack2(b3.z,b3.w));
        __syncthreads();
        bf16x8 av[4], bv[2];
#pragma unroll
        for (int i = 0; i < 4; ++i)
            av[i] = *(const bf16x8*)&Ca[(i*16 + fr)*32 + fk];
#pragma unroll
        for (int j = 0; j < 2; ++j)
            bv[j] = *(const bf16x8*)&Bb[(wv*32 + j*16 + fr)*32 + fk];
#pragma unroll
        for (int i = 0; i < 4; ++i)
#pragma unroll
            for (int j = 0; j < 2; ++j)
                acc[i][j] = __builtin_amdgcn_mfma_f32_16x16x32_bf16(av[i], bv[j], acc[i][j], 0, 0, 0);
    }
    ushort* gout = G + (size_t)(b*NC + c)*(Q*Q);
#pragma unroll
    for (int i = 0; i < 4; ++i) {
#pragma unroll
        for (int j = 0; j < 2; ++j) {
            const int s = wv*32 + j*16 + fr;
#pragma unroll
            for (int r = 0; r < 4; ++r) {
                const int t = th0 + i*16 + fq*4 + r;
                gout[t*Q + s] = f2bf(acc[i][j][r]);
            }
        }
    }
}

// ---------------- local chunk state via MFMA:
// S[p][n] = sum_s (w_s * x_s[p]) * B_s[n]; A = X^T*w [64p x 128s], B-op = B^T [128n x 128s]
#define ASTR 40
#define BSTR 40
__global__ __launch_bounds__(256) void locstate_mfma(
    const float* __restrict__ xconv, const float* __restrict__ dtc,
    const float* __restrict__ clog, ushort* __restrict__ Sloc)
{
    __shared__ __align__(16) ushort Ab[64*ASTR];
    __shared__ __align__(16) ushort Bb[128*BSTR];
    __shared__ float sw[Q];
    const int c = blockIdx.x, h = blockIdx.y, b = blockIdx.z;
    const int tid = threadIdx.x;
    const int wv = tid >> 6, ln = tid & 63;
    const int fr = ln & 15, fq = ln >> 4, fk = fq*8;
    const int bh = b*NHEADS + h;
    const int bl0 = b*SEQL + c*Q;

    if (tid < Q) {
        const float ce = clog[(size_t)bh*SEQL + c*Q + (Q-1)];
        const float cs = clog[(size_t)bh*SEQL + c*Q + tid];
        sw[tid] = dtc[(size_t)bh*SEQL + c*Q + tid] * expf(ce - cs);
    }
    __syncthreads();

    f32x4 acc[4][2];
#pragma unroll
    for (int i = 0; i < 4; ++i)
#pragma unroll
        for (int j = 0; j < 2; ++j) acc[i][j] = (f32x4){0.f,0.f,0.f,0.f};

    const int ap = tid & 63, aoct = tid >> 6;     // A staging: lane=p, 8 s-values
    const int bn = tid & 127, bhalf = tid >> 7;   // B staging: lane=n, 16 s-values

    for (int ks = 0; ks < 4; ++ks) {
        float xv[8];
#pragma unroll
        for (int j = 0; j < 8; ++j) {
            const int s = ks*32 + aoct*8 + j;
            xv[j] = xconv[(size_t)(bl0 + s)*CONVDIM + h*HEADDIM + ap] * sw[s];
        }
        float bv[16];
#pragma unroll
        for (int j = 0; j < 16; ++j) {
            const int s = ks*32 + bhalf*16 + j;
            bv[j] = xconv[(size_t)(bl0 + s)*CONVDIM + BOFF + bn];
        }
        __syncthreads();
        *(uint4*)&Ab[ap*ASTR + aoct*8] =
            make_uint4(pack2(xv[0],xv[1]), pack2(xv[2],xv[3]),
                       pack2(xv[4],xv[5]), pack2(xv[6],xv[7]));
        *(uint4*)&Bb[bn*BSTR + bhalf*16] =
            make_uint4(pack2(bv[0],bv[1]), pack2(bv[2],bv[3]),
                       pack2(bv[4],bv[5]), pack2(bv[6],bv[7]));
        *(uint4*)&Bb[bn*BSTR + bhalf*16 + 8] =
            make_uint4(pack2(bv[8],bv[9]), pack2(bv[10],bv[11]),
                       pack2(bv[12],bv[13]), pack2(bv[14],bv[15]));
        __syncthreads();
        bf16x8 af[4], bf[2];
#pragma unroll
        for (int i = 0; i < 4; ++i)
            af[i] = *(const bf16x8*)&Ab[(i*16 + fr)*ASTR + fk];
#pragma unroll
        for (int j = 0; j < 2; ++j)
            bf[j] = *(const bf16x8*)&Bb[(wv*32 + j*16 + fr)*BSTR + fk];
#pragma unroll
        for (int i = 0; i < 4; ++i)
#pragma unroll
            for (int j = 0; j < 2; ++j)
                acc[i][j] = __builtin_amdgcn_mfma_f32_16x16x32_bf16(af[i], bf[j], acc[i][j], 0, 0, 0);
    }
    ushort* dst = Sloc + (size_t)((b*NC + c)*NHEADS + h) * (HEADDIM*DSTATE);
#pragma unroll
    for (int i = 0; i < 4; ++i) {
#pragma unroll
        for (int j = 0; j < 2; ++j) {
            const int n = wv*32 + j*16 + fr;
#pragma unroll
            for (int r = 0; r < 4; ++r) {
                const int p = i*16 + fq*4 + r;
                dst[p*DSTATE + n] = f2bf(acc[i][j][r]);
            }
        }
    }
}

// ---------------- in-place sequential prefix over chunk states (16 steps)
__global__ __launch_bounds__(256) void chunkscan_kernel(
    const float* __restrict__ clog, ushort* __restrict__ S)
{
    const int h = blockIdx.x, b = blockIdx.y;
    const int tid = threadIdx.x;
    const int p0 = (tid >> 4) * 4, n0 = (tid & 15) * 8;
    const int bh = b*NHEADS + h;
    float st[4][8];
#pragma unroll
    for (int i = 0; i < 4; ++i)
#pragma unroll
        for (int j = 0; j < 8; ++j) st[i][j] = 0.f;

    for (int c = 0; c < NC; ++c) {
        const float tc = expf(clog[(size_t)bh*SEQL + c*Q + (Q-1)]);
        ushort* base = S + (size_t)((b*NC + c)*NHEADS + h) * (HEADDIM*DSTATE);
#pragma unroll
        for (int i = 0; i < 4; ++i) {
            uint4 raw = *(uint4*)(base + (p0 + i)*DSTATE + n0);
            float lv[8];
            unpack8(raw, lv);
            uint4 pre = make_uint4(pack2(st[i][0],st[i][1]), pack2(st[i][2],st[i][3]),
                                   pack2(st[i][4],st[i][5]), pack2(st[i][6],st[i][7]));
            *(uint4*)(base + (p0 + i)*DSTATE + n0) = pre;
#pragma unroll
            for (int j = 0; j < 8; ++j) st[i][j] = fmaf(tc, st[i][j], lv[j]);
        }
    }
}

// ---------------- Y = causal(G.W)@X + exp(clog)*C@Sp^T + D*x  — MFMA version
__global__ __launch_bounds__(256) void ychunk_mfma(
    const float* __restrict__ xconv, const float* __restrict__ dtc,
    const float* __restrict__ clog, const ushort* __restrict__ G,
    const ushort* __restrict__ Sp, const float* __restrict__ Dv,
    float* __restrict__ ybuf)
{
    __shared__ __align__(16) ushort Ab[128*32];
    __shared__ __align__(16) ushort Bb[64*32];
    __shared__ float s_clog[Q];
    __shared__ float s_dtc[Q];
    const int c = blockIdx.x, h = blockIdx.y, b = blockIdx.z;
    const int tid = threadIdx.x;
    const int wv = tid >> 6, ln = tid & 63;
    const int bh = b*NHEADS + h;
    const int bl0 = b*SEQL + c*Q;
    const int fr = ln & 15, fq = ln >> 4, fk = fq*8;

    if (tid < Q) {
        s_clog[tid] = clog[(size_t)bh*SEQL + c*Q + tid];
        s_dtc[tid]  = dtc [(size_t)bh*SEQL + c*Q + tid];
    }

    f32x4 acc[2][4];
#pragma unroll
    for (int i = 0; i < 2; ++i)
#pragma unroll
        for (int j = 0; j < 4; ++j) acc[i][j] = (f32x4){0.f,0.f,0.f,0.f};

    const int sgt = tid & 127, sgh = (tid >> 7)*16;
    const int sbp = tid & 63,  sbc = (tid >> 6)*8;
    const ushort* spb = Sp + (size_t)((b*NC + c)*NHEADS + h)*(HEADDIM*DSTATE);

    for (int ks = 0; ks < 4; ++ks) {
        const float* cr = xconv + (size_t)(bl0 + sgt)*CONVDIM + COFF + ks*32 + sgh;
        float4 c0 = *(const float4*)cr;
        float4 c1 = *(const float4*)(cr + 4);
        float4 c2 = *(const float4*)(cr + 8);
        float4 c3 = *(const float4*)(cr + 12);
        uint4 sv = *(const uint4*)(spb + sbp*DSTATE + ks*32 + sbc);
        __syncthreads();
        *(uint4*)&Ab[sgt*32 + sgh] =
            make_uint4(pack2(c0.x,c0.y), pack2(c0.z,c0.w), pack2(c1.x,c1.y), pack2(c1.z,c1.w));
        *(uint4*)&Ab[sgt*32 + sgh + 8] =
            make_uint4(pack2(c2.x,c2.y), pack2(c2.z,c2.w), pack2(c3.x,c3.y), pack2(c3.z,c3.w));
        *(uint4*)&Bb[sbp*32 + sbc] = sv;
        __syncthreads();
        bf16x8 af[2], bv[4];
        af[0] = *(const bf16x8*)&Ab[(wv*32 +      fr)*32 + fk];
        af[1] = *(const bf16x8*)&Ab[(wv*32 + 16 + fr)*32 + fk];
#pragma unroll
        for (int j = 0; j < 4; ++j)
            bv[j] = *(const bf16x8*)&Bb[(j*16 + fr)*32 + fk];
#pragma unroll
        for (int i = 0; i < 2; ++i)
#pragma unroll
            for (int j = 0; j < 4; ++j)
                acc[i][j] = __builtin_amdgcn_mfma_f32_16x16x32_bf16(af[i], bv[j], acc[i][j], 0, 0, 0);
    }
#pragma unroll
    for (int i = 0; i < 2; ++i) {
        const int tb = wv*32 + i*16 + fq*4;
        float e0 = expf(s_clog[tb+0]), e1 = expf(s_clog[tb+1]);
        float e2 = expf(s_clog[tb+2]), e3 = expf(s_clog[tb+3]);
#pragma unroll
        for (int j = 0; j < 4; ++j) {
            acc[i][j].x *= e0; acc[i][j].y *= e1; acc[i][j].z *= e2; acc[i][j].w *= e3;
        }
    }

    const ushort* gp = G + (size_t)(b*NC + c)*(Q*Q);
    for (int ks = 0; ks < 4; ++ks) {
        uint4 g0 = *(const uint4*)(gp + sgt*Q + ks*32 + sgh);
        uint4 g1 = *(const uint4*)(gp + sgt*Q + ks*32 + sgh + 8);
        float xv[8];
#pragma unroll
        for (int j = 0; j < 8; ++j)
            xv[j] = xconv[(size_t)(bl0 + ks*32 + sbc + j)*CONVDIM + h*HEADDIM + sbp];
        __syncthreads();
        {
            float gvals[16];
            unpack8(g0, gvals);
            unpack8(g1, gvals + 8);
            const float ct = s_clog[sgt];
            ushort gw[16];
#pragma unroll
            for (int j = 0; j < 16; ++j) {
                const int s = ks*32 + sgh + j;
                float w = 0.f;
                if (s <= sgt) w = s_dtc[s] * expf(ct - s_clog[s]);
                gw[j] = f2bf(gvals[j] * w);
            }
            uint4 w0, w1;
            w0.x = (uint)gw[0] | ((uint)gw[1]<<16);  w0.y = (uint)gw[2] | ((uint)gw[3]<<16);
            w0.z = (uint)gw[4] | ((uint)gw[5]<<16);  w0.w = (uint)gw[6] | ((uint)gw[7]<<16);
            w1.x = (uint)gw[8] | ((uint)gw[9]<<16);  w1.y = (uint)gw[10]| ((uint)gw[11]<<16);
            w1.z = (uint)gw[12]| ((uint)gw[13]<<16); w1.w = (uint)gw[14]| ((uint)gw[15]<<16);
            *(uint4*)&Ab[sgt*32 + sgh]     = w0;
            *(uint4*)&Ab[sgt*32 + sgh + 8] = w1;
            *(uint4*)&Bb[sbp*32 + sbc] =
                make_uint4(pack2(xv[0],xv[1]), pack2(xv[2],xv[3]),
                           pack2(xv[4],xv[5]), pack2(xv[6],xv[7]));
        }
        __syncthreads();
        if (ks <= wv) {
            bf16x8 af[2], bv[4];
            af[0] = *(const bf16x8*)&Ab[(wv*32 +      fr)*32 + fk];
            af[1] = *(const bf16x8*)&Ab[(wv*32 + 16 + fr)*32 + fk];
#pragma unroll
            for (int j = 0; j < 4; ++j)
                bv[j] = *(const bf16x8*)&Bb[(j*16 + fr)*32 + fk];
#pragma unroll
            for (int i = 0; i < 2; ++i)
#pragma unroll
                for (int j = 0; j < 4; ++j)
                    acc[i][j] = __builtin_amdgcn_mfma_f32_16x16x32_bf16(af[i], bv[j], acc[i][j], 0, 0, 0);
        }
    }

    const float Dh = Dv[h];
#pragma unroll
    for (int i = 0; i < 2; ++i) {
#pragma unroll
        for (int r = 0; r < 4; ++r) {
            const int t = wv*32 + i*16 + fq*4 + r;
            const float* xr = xconv + (size_t)(bl0 + t)*CONVDIM + h*HEADDIM;
            float* yr = ybuf + (size_t)(bl0 + t)*DINNER + h*HEADDIM;
#pragma unroll
            for (int j = 0; j < 4; ++j) {
                const int p = j*16 + fr;
                yr[p] = acc[i][j][r] + Dh * xr[p];
            }
        }
    }
}

// ---------------- gated RMSNorm -> bf16 output
__global__ __launch_bounds__(128) void rms_kernel(
    const float* __restrict__ zxbcdt, const float* __restrict__ norm_w,
    const float* __restrict__ ybuf, ushort* __restrict__ ybf)
{
    const int row = blockIdx.x;
    const int tid = threadIdx.x;
    const float* zr = zxbcdt + (size_t)row * DINPROJ;
    const float* yr = ybuf + (size_t)row * DINNER;
    ushort* yo = ybf + (size_t)row * DINNER;
    float v[12];
    float ss = 0.f;
#pragma unroll
    for (int i = 0; i < 3; ++i) {
        const int o = (tid + i*128) * 4;
        float4 yv = *(const float4*)(yr + o);
        float4 zv = *(const float4*)(zr + o);
        float a = yv.x * siluf_(zv.x);
        float b = yv.y * siluf_(zv.y);
        float cc = yv.z * siluf_(zv.z);
        float d = yv.w * siluf_(zv.w);
        v[i*4+0]=a; v[i*4+1]=b; v[i*4+2]=cc; v[i*4+3]=d;
        ss += a*a + b*b + cc*cc + d*d;
    }
#pragma unroll
    for (int off = 1; off < 64; off <<= 1) ss += __shfl_xor(ss, off);
    __shared__ float red[2];
    if ((tid & 63) == 0) red[tid >> 6] = ss;
    __syncthreads();
    const float rstd = rsqrtf((red[0] + red[1]) * (1.f/DINNER) + RMS_EPS);
#pragma unroll
    for (int i = 0; i < 3; ++i) {
        const int o = (tid + i*128) * 4;
        float4 wv = *(const float4*)(norm_w + o);
        ushort4 ov = make_ushort4(f2bf(v[i*4+0]*rstd*wv.x), f2bf(v[i*4+1]*rstd*wv.y),
                                  f2bf(v[i*4+2]*rstd*wv.z), f2bf(v[i*4+3]*rstd*wv.w));
        *(ushort4*)(yo + o) = ov;
    }
}

extern "C" void kernel_launch(void* const* d_in, const int* in_sizes, int n_in,
                              void* d_out, int out_size, void* d_ws, size_t ws_size,
                              hipStream_t stream)
{
    const float* feature    = (const float*)d_in[0];
    const float* in_proj_w  = (const float*)d_in[1];
    const float* conv_w     = (const float*)d_in[2];
    const float* conv_b     = (const float*)d_in[3];
    const float* dt_bias    = (const float*)d_in[4];
    const float* A_log      = (const float*)d_in[5];
    const float* Dvec       = (const float*)d_in[6];
    const float* norm_w     = (const float*)d_in[7];
    const float* out_proj_w = (const float*)d_in[8];
    const float* gate1      = (const float*)d_in[9];
    float* out = (float*)d_out;

    float* zxbcdt = (float*)d_ws;                               // 8192*3352 fp32
    float* xconv  = zxbcdt + (size_t)BLROWS * DINPROJ;          // 8192*1792 fp32
    float* ybuf   = xconv  + (size_t)BLROWS * CONVDIM;          // 8192*1536 fp32
    float* dtc    = ybuf   + (size_t)BLROWS * DINNER;
    float* clog   = dtc    + (size_t)NB * NHEADS * SEQL;
    ushort* Gbuf  = (ushort*)(clog + (size_t)NB * NHEADS * SEQL);  // 2 MB
    ushort* Sbuf  = Gbuf + (size_t)NB * NC * Q * Q;                // 25 MB
    ushort* Abf    = Gbuf;
    ushort* Wbf_in = Gbuf + (size_t)BLROWS * DMODEL;
    ushort* ybf    = Gbuf;
    ushort* Wbf_out = (ushort*)zxbcdt;

    cast_kernel<<<dim3((BLROWS*DMODEL/4 + 255)/256), 256, 0, stream>>>(feature, Abf, BLROWS*DMODEL/4);
    cast_kernel<<<dim3((DINPROJ*DMODEL/4 + 255)/256), 256, 0, stream>>>(in_proj_w, Wbf_in, DINPROJ*DMODEL/4);
    gemm_mfma<<<dim3(27, 64), 256, 0, stream>>>(Abf, Wbf_in, zxbcdt,
                                                BLROWS, DINPROJ, DMODEL, nullptr);
    conv_kernel<<<dim3(BLROWS), 448, 0, stream>>>(zxbcdt, conv_w, conv_b, xconv);
    dtscan_kernel<<<dim3(NC, NHEADS, NB), 128, 0, stream>>>(zxbcdt, dt_bias, A_log, dtc, clog);
    gcb_mfma<<<dim3(2, NC, NB), 256, 0, stream>>>(xconv, Gbuf);
    locstate_mfma<<<dim3(NC, NHEADS, NB), 256, 0, stream>>>(xconv, dtc, clog, Sbuf);
    chunkscan_kernel<<<dim3(NHEADS, NB), 256, 0, stream>>>(clog, Sbuf);
    ychunk_mfma<<<dim3(NC, NHEADS, NB), 256, 0, stream>>>(xconv, dtc, clog, Gbuf, Sbuf, Dvec, ybuf);
    rms_kernel<<<dim3(BLROWS), 128, 0, stream>>>(zxbcdt, norm_w, ybuf, ybf);
    cast_kernel<<<dim3((DMODEL*DINNER/4 + 255)/256), 256, 0, stream>>>(out_proj_w, Wbf_out, DMODEL*DINNER/4);
    gemm_mfma<<<dim3(6, 64), 256, 0, stream>>>(ybf, Wbf_out, out,
                                               BLROWS, DMODEL, DINNER, gate1);
}

// Round 6
// 364.758 us; speedup vs baseline: 7.5585x; 1.0566x over previous
//
#include <hip/hip_runtime.h>
#include <cstddef>

#define NB 4
#define SEQL 2048
#define DMODEL 768
#define DSTATE 128
#define HEADDIM 64
#define NHEADS 24
#define DINNER 1536
#define CONVDIM 1792
#define DINPROJ 3352
#define BLROWS (NB*SEQL)
#define RMS_EPS 1e-5f
#define Q 128
#define NC (SEQL/Q)
#define BOFF DINNER
#define COFF (DINNER + DSTATE)

typedef unsigned int uint;
typedef unsigned short ushort;
typedef __attribute__((ext_vector_type(8))) short bf16x8;
typedef __attribute__((ext_vector_type(4))) float f32x4;

__device__ __forceinline__ float sigmoidf_(float x){ return 1.f/(1.f+expf(-x)); }
__device__ __forceinline__ float siluf_(float x){ return x * sigmoidf_(x); }
__device__ __forceinline__ float softplusf_(float x){ return x > 20.f ? x : log1pf(expf(x)); }

__device__ __forceinline__ ushort f2bf(float f){
    union { float f; uint u; } v; v.f = f;
    uint r = (v.u + 0x7FFFu + ((v.u >> 16) & 1u)) >> 16;
    return (ushort)r;
}
__device__ __forceinline__ float bf2f(ushort s){
    union { uint u; float f; } v; v.u = ((uint)s) << 16;
    return v.f;
}
__device__ __forceinline__ uint pack2(float a, float b){
    return (uint)f2bf(a) | ((uint)f2bf(b) << 16);
}
__device__ __forceinline__ void unpack8(uint4 r, float* o){
    o[0]=bf2f((ushort)(r.x&0xffff)); o[1]=bf2f((ushort)(r.x>>16));
    o[2]=bf2f((ushort)(r.y&0xffff)); o[3]=bf2f((ushort)(r.y>>16));
    o[4]=bf2f((ushort)(r.z&0xffff)); o[5]=bf2f((ushort)(r.z>>16));
    o[6]=bf2f((ushort)(r.w&0xffff)); o[7]=bf2f((ushort)(r.w>>16));
}
__device__ __forceinline__ uint packu2(ushort a, ushort b){
    return (uint)a | ((uint)b << 16);
}

#define GLD16(g, l) __builtin_amdgcn_global_load_lds( \
    (const __attribute__((address_space(1))) void*)(g), \
    (__attribute__((address_space(3))) void*)(l), 16, 0, 0)

// ---------------- fp32 -> bf16 cast
__global__ __launch_bounds__(256) void cast_kernel(
    const float* __restrict__ in, ushort* __restrict__ out, int n4)
{
    const int i = blockIdx.x*256 + threadIdx.x;
    if (i < n4) {
        float4 v = ((const float4*)in)[i];
        ushort4 o = make_ushort4(f2bf(v.x), f2bf(v.y), f2bf(v.z), f2bf(v.w));
        ((ushort4*)out)[i] = o;
    }
}

// ---------------- MFMA GEMM, fp32 out (used for out_proj): C = A @ W^T
__global__ __launch_bounds__(256) void gemm_mfma(
    const ushort* __restrict__ A, const ushort* __restrict__ W,
    float* __restrict__ C, int M, int N, int K, const float* __restrict__ gptr)
{
    __shared__ __align__(16) ushort As[128*32];
    __shared__ __align__(16) ushort Bs[128*32];
    const int tid = threadIdx.x;
    const int wv = tid >> 6, ln = tid & 63;
    const int m0 = blockIdx.y * 128, n0 = blockIdx.x * 128;
    const int wm = (wv >> 1) * 64, wn = (wv & 1) * 64;

    const int srow = ln >> 2;
    const int scol = (ln & 3) * 8;
    const ushort* gA0 = A + (size_t)(m0 + wv*32 +      srow) * K + scol;
    const ushort* gA1 = A + (size_t)(m0 + wv*32 + 16 + srow) * K + scol;
    int wr0 = n0 + wv*32 +      srow; if (wr0 >= N) wr0 = N - 1;
    int wr1 = n0 + wv*32 + 16 + srow; if (wr1 >= N) wr1 = N - 1;
    const ushort* gB0 = W + (size_t)wr0 * K + scol;
    const ushort* gB1 = W + (size_t)wr1 * K + scol;
    ushort* lA0 = &As[(wv*32     ) * 32];
    ushort* lA1 = &As[(wv*32 + 16) * 32];
    ushort* lB0 = &Bs[(wv*32     ) * 32];
    ushort* lB1 = &Bs[(wv*32 + 16) * 32];

    f32x4 acc[4][4];
#pragma unroll
    for (int i = 0; i < 4; ++i)
#pragma unroll
        for (int j = 0; j < 4; ++j) acc[i][j] = (f32x4){0.f, 0.f, 0.f, 0.f};

    const int fr = ln & 15;
    const int fk = (ln >> 4) * 8;

    for (int kt = 0; kt < K; kt += 32) {
        __syncthreads();
        GLD16(gA0 + kt, lA0);
        GLD16(gA1 + kt, lA1);
        GLD16(gB0 + kt, lB0);
        GLD16(gB1 + kt, lB1);
        __syncthreads();
        bf16x8 af[4], bfr[4];
#pragma unroll
        for (int i = 0; i < 4; ++i)
            af[i] = *(const bf16x8*)&As[(wm + i*16 + fr) * 32 + fk];
#pragma unroll
        for (int j = 0; j < 4; ++j)
            bfr[j] = *(const bf16x8*)&Bs[(wn + j*16 + fr) * 32 + fk];
#pragma unroll
        for (int i = 0; i < 4; ++i)
#pragma unroll
            for (int j = 0; j < 4; ++j)
                acc[i][j] = __builtin_amdgcn_mfma_f32_16x16x32_bf16(af[i], bfr[j], acc[i][j], 0, 0, 0);
    }

    float scale = 1.f;
    if (gptr) scale = sigmoidf_(*gptr);
    const int cn = ln & 15;
    const int cr = (ln >> 4) * 4;
#pragma unroll
    for (int i = 0; i < 4; ++i) {
        const int mb = m0 + wm + i*16 + cr;
#pragma unroll
        for (int j = 0; j < 4; ++j) {
            const int n = n0 + wn + j*16 + cn;
            if (n < N) {
                float* cp = C + (size_t)mb * N + n;
                cp[0*(size_t)N] = acc[i][j].x * scale;
                cp[1*(size_t)N] = acc[i][j].y * scale;
                cp[2*(size_t)N] = acc[i][j].z * scale;
                cp[3*(size_t)N] = acc[i][j].w * scale;
            }
        }
    }
}

// ---------------- MFMA GEMM, bf16 out via LDS repack (used for in_proj).
// Also side-writes the dt columns [N-24, N) in fp32 to dtraw.
#define RPS 72
__global__ __launch_bounds__(256) void gemm_mfma_bf16o(
    const ushort* __restrict__ A, const ushort* __restrict__ W,
    ushort* __restrict__ C, float* __restrict__ dtraw, int M, int N, int K)
{
    __shared__ __align__(16) ushort sm[4*64*RPS];   // 36864 B; staging aliases head
    ushort* As = sm;            // 128*32
    ushort* Bs = sm + 128*32;   // 128*32
    const int tid = threadIdx.x;
    const int wv = tid >> 6, ln = tid & 63;
    const int m0 = blockIdx.y * 128, n0 = blockIdx.x * 128;
    const int wm = (wv >> 1) * 64, wn = (wv & 1) * 64;

    const int srow = ln >> 2;
    const int scol = (ln & 3) * 8;
    const ushort* gA0 = A + (size_t)(m0 + wv*32 +      srow) * K + scol;
    const ushort* gA1 = A + (size_t)(m0 + wv*32 + 16 + srow) * K + scol;
    int wr0 = n0 + wv*32 +      srow; if (wr0 >= N) wr0 = N - 1;
    int wr1 = n0 + wv*32 + 16 + srow; if (wr1 >= N) wr1 = N - 1;
    const ushort* gB0 = W + (size_t)wr0 * K + scol;
    const ushort* gB1 = W + (size_t)wr1 * K + scol;
    ushort* lA0 = &As[(wv*32     ) * 32];
    ushort* lA1 = &As[(wv*32 + 16) * 32];
    ushort* lB0 = &Bs[(wv*32     ) * 32];
    ushort* lB1 = &Bs[(wv*32 + 16) * 32];

    f32x4 acc[4][4];
#pragma unroll
    for (int i = 0; i < 4; ++i)
#pragma unroll
        for (int j = 0; j < 4; ++j) acc[i][j] = (f32x4){0.f, 0.f, 0.f, 0.f};

    const int fr = ln & 15;
    const int fk = (ln >> 4) * 8;

    for (int kt = 0; kt < K; kt += 32) {
        __syncthreads();
        GLD16(gA0 + kt, lA0);
        GLD16(gA1 + kt, lA1);
        GLD16(gB0 + kt, lB0);
        GLD16(gB1 + kt, lB1);
        __syncthreads();
        bf16x8 af[4], bfr[4];
#pragma unroll
        for (int i = 0; i < 4; ++i)
            af[i] = *(const bf16x8*)&As[(wm + i*16 + fr) * 32 + fk];
#pragma unroll
        for (int j = 0; j < 4; ++j)
            bfr[j] = *(const bf16x8*)&Bs[(wn + j*16 + fr) * 32 + fk];
#pragma unroll
        for (int i = 0; i < 4; ++i)
#pragma unroll
            for (int j = 0; j < 4; ++j)
                acc[i][j] = __builtin_amdgcn_mfma_f32_16x16x32_bf16(af[i], bfr[j], acc[i][j], 0, 0, 0);
    }

    const int cn = ln & 15;
    const int cr = (ln >> 4) * 4;
    __syncthreads();                       // staging LDS now dead
    ushort* rp = sm + wv*(64*RPS);
#pragma unroll
    for (int i = 0; i < 4; ++i)
#pragma unroll
        for (int j = 0; j < 4; ++j) {
            const int col = j*16 + cn;
#pragma unroll
            for (int r = 0; r < 4; ++r)
                rp[(i*16 + cr + r)*RPS + col] = f2bf(acc[i][j][r]);
        }
    __syncthreads();
    // coalesced bf16 stores: 8 lanes x 16B cover one 64-col row
#pragma unroll
    for (int k2 = 0; k2 < 8; ++k2) {
        const int row = k2*8 + (ln >> 3);
        uint4 v = *(const uint4*)&rp[row*RPS + (ln & 7)*8];
        const int gm = m0 + wm + row;
        const int gn = n0 + wn + (ln & 7)*8;
        if (gn + 8 <= N)
            *(uint4*)(C + (size_t)gm*N + gn) = v;
    }
    // dt columns in fp32 (edge tile only)
    if (n0 + 128 > N) {
#pragma unroll
        for (int i = 0; i < 4; ++i) {
            const int mb = m0 + wm + i*16 + cr;
#pragma unroll
            for (int j = 0; j < 4; ++j) {
                const int col = (n0 + wn + j*16 + cn) - (N - 24);
                if (col >= 0 && col < 24) {
                    dtraw[(size_t)(mb+0)*24 + col] = acc[i][j].x;
                    dtraw[(size_t)(mb+1)*24 + col] = acc[i][j].y;
                    dtraw[(size_t)(mb+2)*24 + col] = acc[i][j].z;
                    dtraw[(size_t)(mb+3)*24 + col] = acc[i][j].w;
                }
            }
        }
    }
}

// ---------------- causal depthwise conv1d + bias + silu (bf16 in/out)
__global__ __launch_bounds__(448) void conv_kernel(
    const ushort* __restrict__ zx, const float* __restrict__ conv_w,
    const float* __restrict__ conv_b, ushort* __restrict__ xconv)
{
    const int c4 = threadIdx.x;
    const int bl = blockIdx.x;
    const int l = bl & (SEQL - 1);
    float w[4][4];
#pragma unroll
    for (int j = 0; j < 4; ++j) {
        float4 wr = *(const float4*)(conv_w + (c4*4 + j)*4);
        w[j][0]=wr.x; w[j][1]=wr.y; w[j][2]=wr.z; w[j][3]=wr.w;
    }
    float4 bias = *(const float4*)(conv_b + c4*4);
    float s[4] = {bias.x, bias.y, bias.z, bias.w};
#pragma unroll
    for (int k = 0; k < 4; ++k) {
        const int ls = l - 3 + k;
        if (ls >= 0) {
            ushort4 xv = *(const ushort4*)(zx + (size_t)(bl - 3 + k)*DINPROJ + DINNER + c4*4);
            s[0] = fmaf(bf2f(xv.x), w[0][k], s[0]);
            s[1] = fmaf(bf2f(xv.y), w[1][k], s[1]);
            s[2] = fmaf(bf2f(xv.z), w[2][k], s[2]);
            s[3] = fmaf(bf2f(xv.w), w[3][k], s[3]);
        }
    }
    ushort4 o = make_ushort4(f2bf(siluf_(s[0])), f2bf(siluf_(s[1])),
                             f2bf(siluf_(s[2])), f2bf(siluf_(s[3])));
    *(ushort4*)(xconv + (size_t)bl*CONVDIM + c4*4) = o;
}

// ---------------- dt = softplus(dt+bias); clog = chunk-local inclusive cumsum of A*dt
__global__ __launch_bounds__(128) void dtscan_kernel(
    const float* __restrict__ dtraw, const float* __restrict__ dt_bias,
    const float* __restrict__ A_log, float* __restrict__ dtc, float* __restrict__ clog)
{
    const int c = blockIdx.x, h = blockIdx.y, b = blockIdx.z;
    const int t = threadIdx.x;
    const int bl = b*SEQL + c*Q + t;
    float draw = dtraw[(size_t)bl*24 + h] + dt_bias[h];
    float dtv = softplusf_(draw);
    float la = -expf(A_log[h]) * dtv;
    const int lane = t & 63;
    float v = la;
#pragma unroll
    for (int off = 1; off < 64; off <<= 1) {
        float u = __shfl_up(v, off);
        if (lane >= off) v += u;
    }
    __shared__ float w0tot;
    if (t == 63) w0tot = v;
    __syncthreads();
    if (t >= 64) v += w0tot;
    const int idx = (b*NHEADS + h)*SEQL + c*Q + t;
    dtc[idx] = dtv;
    clog[idx] = v;
}

// ---------------- G[t][s] = C_t . B_s  via MFMA; block covers 64 t x 128 s (bf16 in)
__global__ __launch_bounds__(256) void gcb_mfma(
    const ushort* __restrict__ xconv, ushort* __restrict__ G)
{
    __shared__ __align__(16) ushort Ca[64*32];
    __shared__ __align__(16) ushort Bb[128*32];
    const int thalf = blockIdx.x, c = blockIdx.y, b = blockIdx.z;
    const int tid = threadIdx.x;
    const int wv = tid >> 6, ln = tid & 63;
    const int fr = ln & 15, fq = ln >> 4, fk = fq*8;
    const int bl0 = b*SEQL + c*Q;
    const int th0 = thalf*64;

    const int sat = tid & 63,  sac = (tid >> 6)*8;
    const int sbt = tid & 127, sbh = (tid >> 7)*16;

    f32x4 acc[4][2];
#pragma unroll
    for (int i = 0; i < 4; ++i)
#pragma unroll
        for (int j = 0; j < 2; ++j) acc[i][j] = (f32x4){0.f,0.f,0.f,0.f};

    for (int ks = 0; ks < 4; ++ks) {
        uint4 av = *(const uint4*)(xconv + (size_t)(bl0 + th0 + sat)*CONVDIM + COFF + ks*32 + sac);
        const ushort* br = xconv + (size_t)(bl0 + sbt)*CONVDIM + BOFF + ks*32 + sbh;
        uint4 bv0 = *(const uint4*)br;
        uint4 bv1 = *(const uint4*)(br + 8);
        __syncthreads();
        *(uint4*)&Ca[sat*32 + sac] = av;
        *(uint4*)&Bb[sbt*32 + sbh] = bv0;
        *(uint4*)&Bb[sbt*32 + sbh + 8] = bv1;
        __syncthreads();
        bf16x8 av_[4], bv_[2];
#pragma unroll
        for (int i = 0; i < 4; ++i)
            av_[i] = *(const bf16x8*)&Ca[(i*16 + fr)*32 + fk];
#pragma unroll
        for (int j = 0; j < 2; ++j)
            bv_[j] = *(const bf16x8*)&Bb[(wv*32 + j*16 + fr)*32 + fk];
#pragma unroll
        for (int i = 0; i < 4; ++i)
#pragma unroll
            for (int j = 0; j < 2; ++j)
                acc[i][j] = __builtin_amdgcn_mfma_f32_16x16x32_bf16(av_[i], bv_[j], acc[i][j], 0, 0, 0);
    }
    ushort* gout = G + (size_t)(b*NC + c)*(Q*Q);
#pragma unroll
    for (int i = 0; i < 4; ++i) {
#pragma unroll
        for (int j = 0; j < 2; ++j) {
            const int s = wv*32 + j*16 + fr;
#pragma unroll
            for (int r = 0; r < 4; ++r) {
                const int t = th0 + i*16 + fq*4 + r;
                gout[t*Q + s] = f2bf(acc[i][j][r]);
            }
        }
    }
}

// ---------------- local chunk state via MFMA (bf16 in)
#define ASTR 40
#define BSTR 40
__global__ __launch_bounds__(256) void locstate_mfma(
    const ushort* __restrict__ xconv, const float* __restrict__ dtc,
    const float* __restrict__ clog, ushort* __restrict__ Sloc)
{
    __shared__ __align__(16) ushort Ab[64*ASTR];
    __shared__ __align__(16) ushort Bb[128*BSTR];
    __shared__ float sw[Q];
    const int c = blockIdx.x, h = blockIdx.y, b = blockIdx.z;
    const int tid = threadIdx.x;
    const int wv = tid >> 6, ln = tid & 63;
    const int fr = ln & 15, fq = ln >> 4, fk = fq*8;
    const int bh = b*NHEADS + h;
    const int bl0 = b*SEQL + c*Q;

    if (tid < Q) {
        const float ce = clog[(size_t)bh*SEQL + c*Q + (Q-1)];
        const float cs = clog[(size_t)bh*SEQL + c*Q + tid];
        sw[tid] = dtc[(size_t)bh*SEQL + c*Q + tid] * expf(ce - cs);
    }
    __syncthreads();

    f32x4 acc[4][2];
#pragma unroll
    for (int i = 0; i < 4; ++i)
#pragma unroll
        for (int j = 0; j < 2; ++j) acc[i][j] = (f32x4){0.f,0.f,0.f,0.f};

    const int ap = tid & 63, aoct = tid >> 6;
    const int bn = tid & 127, bhalf = tid >> 7;

    for (int ks = 0; ks < 4; ++ks) {
        float xv[8];
#pragma unroll
        for (int j = 0; j < 8; ++j) {
            const int s = ks*32 + aoct*8 + j;
            xv[j] = bf2f(xconv[(size_t)(bl0 + s)*CONVDIM + h*HEADDIM + ap]) * sw[s];
        }
        ushort bu[16];
#pragma unroll
        for (int j = 0; j < 16; ++j) {
            const int s = ks*32 + bhalf*16 + j;
            bu[j] = xconv[(size_t)(bl0 + s)*CONVDIM + BOFF + bn];
        }
        __syncthreads();
        *(uint4*)&Ab[ap*ASTR + aoct*8] =
            make_uint4(pack2(xv[0],xv[1]), pack2(xv[2],xv[3]),
                       pack2(xv[4],xv[5]), pack2(xv[6],xv[7]));
        *(uint4*)&Bb[bn*BSTR + bhalf*16] =
            make_uint4(packu2(bu[0],bu[1]), packu2(bu[2],bu[3]),
                       packu2(bu[4],bu[5]), packu2(bu[6],bu[7]));
        *(uint4*)&Bb[bn*BSTR + bhalf*16 + 8] =
            make_uint4(packu2(bu[8],bu[9]), packu2(bu[10],bu[11]),
                       packu2(bu[12],bu[13]), packu2(bu[14],bu[15]));
        __syncthreads();
        bf16x8 af[4], bf[2];
#pragma unroll
        for (int i = 0; i < 4; ++i)
            af[i] = *(const bf16x8*)&Ab[(i*16 + fr)*ASTR + fk];
#pragma unroll
        for (int j = 0; j < 2; ++j)
            bf[j] = *(const bf16x8*)&Bb[(wv*32 + j*16 + fr)*BSTR + fk];
#pragma unroll
        for (int i = 0; i < 4; ++i)
#pragma unroll
            for (int j = 0; j < 2; ++j)
                acc[i][j] = __builtin_amdgcn_mfma_f32_16x16x32_bf16(af[i], bf[j], acc[i][j], 0, 0, 0);
    }
    ushort* dst = Sloc + (size_t)((b*NC + c)*NHEADS + h) * (HEADDIM*DSTATE);
#pragma unroll
    for (int i = 0; i < 4; ++i) {
#pragma unroll
        for (int j = 0; j < 2; ++j) {
            const int n = wv*32 + j*16 + fr;
#pragma unroll
            for (int r = 0; r < 4; ++r) {
                const int p = i*16 + fq*4 + r;
                dst[p*DSTATE + n] = f2bf(acc[i][j][r]);
            }
        }
    }
}

// ---------------- in-place sequential prefix over chunk states (16 steps)
__global__ __launch_bounds__(256) void chunkscan_kernel(
    const float* __restrict__ clog, ushort* __restrict__ S)
{
    const int h = blockIdx.x, b = blockIdx.y;
    const int tid = threadIdx.x;
    const int p0 = (tid >> 4) * 4, n0 = (tid & 15) * 8;
    const int bh = b*NHEADS + h;
    float st[4][8];
#pragma unroll
    for (int i = 0; i < 4; ++i)
#pragma unroll
        for (int j = 0; j < 8; ++j) st[i][j] = 0.f;

    for (int c = 0; c < NC; ++c) {
        const float tc = expf(clog[(size_t)bh*SEQL + c*Q + (Q-1)]);
        ushort* base = S + (size_t)((b*NC + c)*NHEADS + h) * (HEADDIM*DSTATE);
#pragma unroll
        for (int i = 0; i < 4; ++i) {
            uint4 raw = *(uint4*)(base + (p0 + i)*DSTATE + n0);
            float lv[8];
            unpack8(raw, lv);
            uint4 pre = make_uint4(pack2(st[i][0],st[i][1]), pack2(st[i][2],st[i][3]),
                                   pack2(st[i][4],st[i][5]), pack2(st[i][6],st[i][7]));
            *(uint4*)(base + (p0 + i)*DSTATE + n0) = pre;
#pragma unroll
            for (int j = 0; j < 8; ++j) st[i][j] = fmaf(tc, st[i][j], lv[j]);
        }
    }
}

// ---------------- Y = causal(G.W)@X + exp(clog)*C@Sp^T + D*x  — MFMA (bf16 in)
__global__ __launch_bounds__(256) void ychunk_mfma(
    const ushort* __restrict__ xconv, const float* __restrict__ dtc,
    const float* __restrict__ clog, const ushort* __restrict__ G,
    const ushort* __restrict__ Sp, const float* __restrict__ Dv,
    float* __restrict__ ybuf)
{
    __shared__ __align__(16) ushort Ab[128*32];
    __shared__ __align__(16) ushort Bb[64*32];
    __shared__ float s_clog[Q];
    __shared__ float s_dtc[Q];
    const int c = blockIdx.x, h = blockIdx.y, b = blockIdx.z;
    const int tid = threadIdx.x;
    const int wv = tid >> 6, ln = tid & 63;
    const int bh = b*NHEADS + h;
    const int bl0 = b*SEQL + c*Q;
    const int fr = ln & 15, fq = ln >> 4, fk = fq*8;

    if (tid < Q) {
        s_clog[tid] = clog[(size_t)bh*SEQL + c*Q + tid];
        s_dtc[tid]  = dtc [(size_t)bh*SEQL + c*Q + tid];
    }

    f32x4 acc[2][4];
#pragma unroll
    for (int i = 0; i < 2; ++i)
#pragma unroll
        for (int j = 0; j < 4; ++j) acc[i][j] = (f32x4){0.f,0.f,0.f,0.f};

    const int sgt = tid & 127, sgh = (tid >> 7)*16;
    const int sbp = tid & 63,  sbc = (tid >> 6)*8;
    const ushort* spb = Sp + (size_t)((b*NC + c)*NHEADS + h)*(HEADDIM*DSTATE);

    // phase 1: acc = C @ Sp^T
    for (int ks = 0; ks < 4; ++ks) {
        const ushort* cr = xconv + (size_t)(bl0 + sgt)*CONVDIM + COFF + ks*32 + sgh;
        uint4 cv0 = *(const uint4*)cr;
        uint4 cv1 = *(const uint4*)(cr + 8);
        uint4 sv = *(const uint4*)(spb + sbp*DSTATE + ks*32 + sbc);
        __syncthreads();
        *(uint4*)&Ab[sgt*32 + sgh]     = cv0;
        *(uint4*)&Ab[sgt*32 + sgh + 8] = cv1;
        *(uint4*)&Bb[sbp*32 + sbc] = sv;
        __syncthreads();
        bf16x8 af[2], bv[4];
        af[0] = *(const bf16x8*)&Ab[(wv*32 +      fr)*32 + fk];
        af[1] = *(const bf16x8*)&Ab[(wv*32 + 16 + fr)*32 + fk];
#pragma unroll
        for (int j = 0; j < 4; ++j)
            bv[j] = *(const bf16x8*)&Bb[(j*16 + fr)*32 + fk];
#pragma unroll
        for (int i = 0; i < 2; ++i)
#pragma unroll
            for (int j = 0; j < 4; ++j)
                acc[i][j] = __builtin_amdgcn_mfma_f32_16x16x32_bf16(af[i], bv[j], acc[i][j], 0, 0, 0);
    }
#pragma unroll
    for (int i = 0; i < 2; ++i) {
        const int tb = wv*32 + i*16 + fq*4;
        float e0 = expf(s_clog[tb+0]), e1 = expf(s_clog[tb+1]);
        float e2 = expf(s_clog[tb+2]), e3 = expf(s_clog[tb+3]);
#pragma unroll
        for (int j = 0; j < 4; ++j) {
            acc[i][j].x *= e0; acc[i][j].y *= e1; acc[i][j].z *= e2; acc[i][j].w *= e3;
        }
    }

    // phase 2: acc += (G .* W) @ X (causal)
    const ushort* gp = G + (size_t)(b*NC + c)*(Q*Q);
    for (int ks = 0; ks < 4; ++ks) {
        uint4 g0 = *(const uint4*)(gp + sgt*Q + ks*32 + sgh);
        uint4 g1 = *(const uint4*)(gp + sgt*Q + ks*32 + sgh + 8);
        ushort xu[8];
#pragma unroll
        for (int j = 0; j < 8; ++j)
            xu[j] = xconv[(size_t)(bl0 + ks*32 + sbc + j)*CONVDIM + h*HEADDIM + sbp];
        __syncthreads();
        {
            float gvals[16];
            unpack8(g0, gvals);
            unpack8(g1, gvals + 8);
            const float ct = s_clog[sgt];
            ushort gw[16];
#pragma unroll
            for (int j = 0; j < 16; ++j) {
                const int s = ks*32 + sgh + j;
                float w = 0.f;
                if (s <= sgt) w = s_dtc[s] * expf(ct - s_clog[s]);
                gw[j] = f2bf(gvals[j] * w);
            }
            *(uint4*)&Ab[sgt*32 + sgh] =
                make_uint4(packu2(gw[0],gw[1]), packu2(gw[2],gw[3]),
                           packu2(gw[4],gw[5]), packu2(gw[6],gw[7]));
            *(uint4*)&Ab[sgt*32 + sgh + 8] =
                make_uint4(packu2(gw[8],gw[9]), packu2(gw[10],gw[11]),
                           packu2(gw[12],gw[13]), packu2(gw[14],gw[15]));
            *(uint4*)&Bb[sbp*32 + sbc] =
                make_uint4(packu2(xu[0],xu[1]), packu2(xu[2],xu[3]),
                           packu2(xu[4],xu[5]), packu2(xu[6],xu[7]));
        }
        __syncthreads();
        if (ks <= wv) {
            bf16x8 af[2], bv[4];
            af[0] = *(const bf16x8*)&Ab[(wv*32 +      fr)*32 + fk];
            af[1] = *(const bf16x8*)&Ab[(wv*32 + 16 + fr)*32 + fk];
#pragma unroll
            for (int j = 0; j < 4; ++j)
                bv[j] = *(const bf16x8*)&Bb[(j*16 + fr)*32 + fk];
#pragma unroll
            for (int i = 0; i < 2; ++i)
#pragma unroll
                for (int j = 0; j < 4; ++j)
                    acc[i][j] = __builtin_amdgcn_mfma_f32_16x16x32_bf16(af[i], bv[j], acc[i][j], 0, 0, 0);
        }
    }

    const float Dh = Dv[h];
#pragma unroll
    for (int i = 0; i < 2; ++i) {
#pragma unroll
        for (int r = 0; r < 4; ++r) {
            const int t = wv*32 + i*16 + fq*4 + r;
            const ushort* xr = xconv + (size_t)(bl0 + t)*CONVDIM + h*HEADDIM;
            float* yr = ybuf + (size_t)(bl0 + t)*DINNER + h*HEADDIM;
#pragma unroll
            for (int j = 0; j < 4; ++j) {
                const int p = j*16 + fr;
                yr[p] = acc[i][j][r] + Dh * bf2f(xr[p]);
            }
        }
    }
}

// ---------------- gated RMSNorm -> bf16 output (z read as bf16)
__global__ __launch_bounds__(128) void rms_kernel(
    const ushort* __restrict__ zx, const float* __restrict__ norm_w,
    const float* __restrict__ ybuf, ushort* __restrict__ ybf)
{
    const int row = blockIdx.x;
    const int tid = threadIdx.x;
    const ushort* zr = zx + (size_t)row * DINPROJ;
    const float* yr = ybuf + (size_t)row * DINNER;
    ushort* yo = ybf + (size_t)row * DINNER;
    float v[12];
    float ss = 0.f;
#pragma unroll
    for (int i = 0; i < 3; ++i) {
        const int o = (tid + i*128) * 4;
        float4 yv = *(const float4*)(yr + o);
        ushort4 zv = *(const ushort4*)(zr + o);
        float a = yv.x * siluf_(bf2f(zv.x));
        float b = yv.y * siluf_(bf2f(zv.y));
        float cc = yv.z * siluf_(bf2f(zv.z));
        float d = yv.w * siluf_(bf2f(zv.w));
        v[i*4+0]=a; v[i*4+1]=b; v[i*4+2]=cc; v[i*4+3]=d;
        ss += a*a + b*b + cc*cc + d*d;
    }
#pragma unroll
    for (int off = 1; off < 64; off <<= 1) ss += __shfl_xor(ss, off);
    __shared__ float red[2];
    if ((tid & 63) == 0) red[tid >> 6] = ss;
    __syncthreads();
    const float rstd = rsqrtf((red[0] + red[1]) * (1.f/DINNER) + RMS_EPS);
#pragma unroll
    for (int i = 0; i < 3; ++i) {
        const int o = (tid + i*128) * 4;
        float4 wv = *(const float4*)(norm_w + o);
        ushort4 ov = make_ushort4(f2bf(v[i*4+0]*rstd*wv.x), f2bf(v[i*4+1]*rstd*wv.y),
                                  f2bf(v[i*4+2]*rstd*wv.z), f2bf(v[i*4+3]*rstd*wv.w));
        *(ushort4*)(yo + o) = ov;
    }
}

extern "C" void kernel_launch(void* const* d_in, const int* in_sizes, int n_in,
                              void* d_out, int out_size, void* d_ws, size_t ws_size,
                              hipStream_t stream)
{
    const float* feature    = (const float*)d_in[0];
    const float* in_proj_w  = (const float*)d_in[1];
    const float* conv_w     = (const float*)d_in[2];
    const float* conv_b     = (const float*)d_in[3];
    const float* dt_bias    = (const float*)d_in[4];
    const float* A_log      = (const float*)d_in[5];
    const float* Dvec       = (const float*)d_in[6];
    const float* norm_w     = (const float*)d_in[7];
    const float* out_proj_w = (const float*)d_in[8];
    const float* gate1      = (const float*)d_in[9];
    float* out = (float*)d_out;

    ushort* zx    = (ushort*)d_ws;                              // [8192,3352] bf16
    ushort* xconv = zx + (size_t)BLROWS * DINPROJ;              // [8192,1792] bf16
    float* ybuf   = (float*)(xconv + (size_t)BLROWS * CONVDIM); // [8192,1536] fp32
    float* dtraw  = ybuf + (size_t)BLROWS * DINNER;             // [8192,24]
    float* dtc    = dtraw + (size_t)BLROWS * 24;
    float* clog   = dtc + (size_t)NB * NHEADS * SEQL;
    ushort* Gbuf  = (ushort*)(clog + (size_t)NB * NHEADS * SEQL);  // 2 MB
    ushort* Sbuf  = Gbuf + (size_t)NB * NC * Q * Q;                // 25 MB
    ushort* Abf    = Gbuf;                            // feature bf16 (dead after gemm1)
    ushort* Wbf_in = Gbuf + (size_t)BLROWS * DMODEL;  // in_proj_w bf16 (dead after gemm1)
    ushort* ybf    = Gbuf;                            // y bf16 (after ychunk)
    ushort* Wbf_out = zx;                             // out_proj_w bf16 (after rms)

    cast_kernel<<<dim3((BLROWS*DMODEL/4 + 255)/256), 256, 0, stream>>>(feature, Abf, BLROWS*DMODEL/4);
    cast_kernel<<<dim3((DINPROJ*DMODEL/4 + 255)/256), 256, 0, stream>>>(in_proj_w, Wbf_in, DINPROJ*DMODEL/4);
    gemm_mfma_bf16o<<<dim3(27, 64), 256, 0, stream>>>(Abf, Wbf_in, zx, dtraw,
                                                      BLROWS, DINPROJ, DMODEL);
    conv_kernel<<<dim3(BLROWS), 448, 0, stream>>>(zx, conv_w, conv_b, xconv);
    dtscan_kernel<<<dim3(NC, NHEADS, NB), 128, 0, stream>>>(dtraw, dt_bias, A_log, dtc, clog);
    gcb_mfma<<<dim3(2, NC, NB), 256, 0, stream>>>(xconv, Gbuf);
    locstate_mfma<<<dim3(NC, NHEADS, NB), 256, 0, stream>>>(xconv, dtc, clog, Sbuf);
    chunkscan_kernel<<<dim3(NHEADS, NB), 256, 0, stream>>>(clog, Sbuf);
    ychunk_mfma<<<dim3(NC, NHEADS, NB), 256, 0, stream>>>(xconv, dtc, clog, Gbuf, Sbuf, Dvec, ybuf);
    rms_kernel<<<dim3(BLROWS), 128, 0, stream>>>(zx, norm_w, ybuf, ybf);
    cast_kernel<<<dim3((DMODEL*DINNER/4 + 255)/256), 256, 0, stream>>>(out_proj_w, Wbf_out, DMODEL*DINNER/4);
    gemm_mfma<<<dim3(6, 64), 256, 0, stream>>>(ybf, Wbf_out, out,
                                               BLROWS, DMODEL, DINNER, gate1);
}

// Round 7
// 347.320 us; speedup vs baseline: 7.9380x; 1.0502x over previous
//
#include <hip/hip_runtime.h>
#include <cstddef>

#define NB 4
#define SEQL 2048
#define DMODEL 768
#define DSTATE 128
#define HEADDIM 64
#define NHEADS 24
#define DINNER 1536
#define CONVDIM 1792
#define DINPROJ 3352
#define BLROWS (NB*SEQL)
#define RMS_EPS 1e-5f
#define Q 128
#define NC (SEQL/Q)
#define BOFF DINNER
#define COFF (DINNER + DSTATE)
#define BK 64

typedef unsigned int uint;
typedef unsigned short ushort;
typedef __attribute__((ext_vector_type(8))) short bf16x8;
typedef __attribute__((ext_vector_type(4))) float f32x4;

__device__ __forceinline__ float sigmoidf_(float x){ return 1.f/(1.f+expf(-x)); }
__device__ __forceinline__ float siluf_(float x){ return x * sigmoidf_(x); }
__device__ __forceinline__ float softplusf_(float x){ return x > 20.f ? x : log1pf(expf(x)); }

__device__ __forceinline__ ushort f2bf(float f){
    union { float f; uint u; } v; v.f = f;
    uint r = (v.u + 0x7FFFu + ((v.u >> 16) & 1u)) >> 16;
    return (ushort)r;
}
__device__ __forceinline__ float bf2f(ushort s){
    union { uint u; float f; } v; v.u = ((uint)s) << 16;
    return v.f;
}
__device__ __forceinline__ uint pack2(float a, float b){
    return (uint)f2bf(a) | ((uint)f2bf(b) << 16);
}
__device__ __forceinline__ void unpack8(uint4 r, float* o){
    o[0]=bf2f((ushort)(r.x&0xffff)); o[1]=bf2f((ushort)(r.x>>16));
    o[2]=bf2f((ushort)(r.y&0xffff)); o[3]=bf2f((ushort)(r.y>>16));
    o[4]=bf2f((ushort)(r.z&0xffff)); o[5]=bf2f((ushort)(r.z>>16));
    o[6]=bf2f((ushort)(r.w&0xffff)); o[7]=bf2f((ushort)(r.w>>16));
}
__device__ __forceinline__ uint packu2(ushort a, ushort b){
    return (uint)a | ((uint)b << 16);
}

#define GLD16(g, l) __builtin_amdgcn_global_load_lds( \
    (const __attribute__((address_space(1))) void*)(g), \
    (__attribute__((address_space(3))) void*)(l), 16, 0, 0)

// ---------------- fp32 -> bf16 cast
__global__ __launch_bounds__(256) void cast_kernel(
    const float* __restrict__ in, ushort* __restrict__ out, int n4)
{
    const int i = blockIdx.x*256 + threadIdx.x;
    if (i < n4) {
        float4 v = ((const float4*)in)[i];
        ushort4 o = make_ushort4(f2bf(v.x), f2bf(v.y), f2bf(v.z), f2bf(v.w));
        ((ushort4*)out)[i] = o;
    }
}

// ---------------- MFMA GEMM, fp32 out (out_proj): C = A @ W^T.
// BK=64, XOR-swizzled LDS cols: LDS[r][cg] = global[r][cg ^ (r&7)].
__global__ __launch_bounds__(256) void gemm_mfma(
    const ushort* __restrict__ A, const ushort* __restrict__ W,
    float* __restrict__ C, int M, int N, int K, const float* __restrict__ gptr)
{
    __shared__ __align__(16) ushort As[128*BK];
    __shared__ __align__(16) ushort Bs[128*BK];
    const int tid = threadIdx.x;
    const int wv = tid >> 6, ln = tid & 63;
    const int m0 = blockIdx.y * 128, n0 = blockIdx.x * 128;
    const int wm = (wv >> 1) * 64, wn = (wv & 1) * 64;

    const int sr = ln >> 3;                // row within 8-row staging group
    const int scol = ((ln & 7) ^ sr) * 8;  // swizzled col
    const ushort* gA[4]; const ushort* gB[4];
    ushort* lA[4]; ushort* lB[4];
#pragma unroll
    for (int iss = 0; iss < 4; ++iss) {
        const int ra = m0 + wv*32 + iss*8 + sr;
        gA[iss] = A + (size_t)ra * K + scol;
        int rb = n0 + wv*32 + iss*8 + sr; if (rb >= N) rb = N - 1;
        gB[iss] = W + (size_t)rb * K + scol;
        lA[iss] = &As[(wv*32 + iss*8) * BK];
        lB[iss] = &Bs[(wv*32 + iss*8) * BK];
    }

    f32x4 acc[4][4];
#pragma unroll
    for (int i = 0; i < 4; ++i)
#pragma unroll
        for (int j = 0; j < 4; ++j) acc[i][j] = (f32x4){0.f, 0.f, 0.f, 0.f};

    const int fr = ln & 15;
    const int fq = ln >> 4;

    for (int kt = 0; kt < K; kt += BK) {
        __syncthreads();
#pragma unroll
        for (int iss = 0; iss < 4; ++iss) {
            GLD16(gA[iss] + kt, lA[iss]);
            GLD16(gB[iss] + kt, lB[iss]);
        }
        __syncthreads();
#pragma unroll
        for (int kh = 0; kh < 2; ++kh) {
            const int sw = ((kh*4 + fq) ^ (fr & 7)) * 8;
            bf16x8 af[4], bfr[4];
#pragma unroll
            for (int i = 0; i < 4; ++i)
                af[i] = *(const bf16x8*)&As[(wm + i*16 + fr)*BK + sw];
#pragma unroll
            for (int j = 0; j < 4; ++j)
                bfr[j] = *(const bf16x8*)&Bs[(wn + j*16 + fr)*BK + sw];
#pragma unroll
            for (int i = 0; i < 4; ++i)
#pragma unroll
                for (int j = 0; j < 4; ++j)
                    acc[i][j] = __builtin_amdgcn_mfma_f32_16x16x32_bf16(af[i], bfr[j], acc[i][j], 0, 0, 0);
        }
    }

    float scale = 1.f;
    if (gptr) scale = sigmoidf_(*gptr);
    const int cn = ln & 15;
    const int cr = (ln >> 4) * 4;
#pragma unroll
    for (int i = 0; i < 4; ++i) {
        const int mb = m0 + wm + i*16 + cr;
#pragma unroll
        for (int j = 0; j < 4; ++j) {
            const int n = n0 + wn + j*16 + cn;
            if (n < N) {
                float* cp = C + (size_t)mb * N + n;
                cp[0*(size_t)N] = acc[i][j].x * scale;
                cp[1*(size_t)N] = acc[i][j].y * scale;
                cp[2*(size_t)N] = acc[i][j].z * scale;
                cp[3*(size_t)N] = acc[i][j].w * scale;
            }
        }
    }
}

// ---------------- MFMA GEMM, bf16 out via LDS repack (in_proj); dt cols -> fp32 dtraw.
__global__ __launch_bounds__(256) void gemm_mfma_bf16o(
    const ushort* __restrict__ A, const ushort* __restrict__ W,
    ushort* __restrict__ C, float* __restrict__ dtraw, int M, int N, int K)
{
    __shared__ __align__(16) ushort sm[128*BK*2];   // 32 KB: staging; repack aliases
    ushort* As = sm;
    ushort* Bs = sm + 128*BK;
    const int tid = threadIdx.x;
    const int wv = tid >> 6, ln = tid & 63;
    const int m0 = blockIdx.y * 128, n0 = blockIdx.x * 128;
    const int wm = (wv >> 1) * 64, wn = (wv & 1) * 64;

    const int sr = ln >> 3;
    const int scol = ((ln & 7) ^ sr) * 8;
    const ushort* gA[4]; const ushort* gB[4];
    ushort* lA[4]; ushort* lB[4];
#pragma unroll
    for (int iss = 0; iss < 4; ++iss) {
        const int ra = m0 + wv*32 + iss*8 + sr;
        gA[iss] = A + (size_t)ra * K + scol;
        int rb = n0 + wv*32 + iss*8 + sr; if (rb >= N) rb = N - 1;
        gB[iss] = W + (size_t)rb * K + scol;
        lA[iss] = &As[(wv*32 + iss*8) * BK];
        lB[iss] = &Bs[(wv*32 + iss*8) * BK];
    }

    f32x4 acc[4][4];
#pragma unroll
    for (int i = 0; i < 4; ++i)
#pragma unroll
        for (int j = 0; j < 4; ++j) acc[i][j] = (f32x4){0.f, 0.f, 0.f, 0.f};

    const int fr = ln & 15;
    const int fq = ln >> 4;

    for (int kt = 0; kt < K; kt += BK) {
        __syncthreads();
#pragma unroll
        for (int iss = 0; iss < 4; ++iss) {
            GLD16(gA[iss] + kt, lA[iss]);
            GLD16(gB[iss] + kt, lB[iss]);
        }
        __syncthreads();
#pragma unroll
        for (int kh = 0; kh < 2; ++kh) {
            const int sw = ((kh*4 + fq) ^ (fr & 7)) * 8;
            bf16x8 af[4], bfr[4];
#pragma unroll
            for (int i = 0; i < 4; ++i)
                af[i] = *(const bf16x8*)&As[(wm + i*16 + fr)*BK + sw];
#pragma unroll
            for (int j = 0; j < 4; ++j)
                bfr[j] = *(const bf16x8*)&Bs[(wn + j*16 + fr)*BK + sw];
#pragma unroll
            for (int i = 0; i < 4; ++i)
#pragma unroll
                for (int j = 0; j < 4; ++j)
                    acc[i][j] = __builtin_amdgcn_mfma_f32_16x16x32_bf16(af[i], bfr[j], acc[i][j], 0, 0, 0);
        }
    }

    const int cn = ln & 15;
    const int cr = (ln >> 4) * 4;
    __syncthreads();                       // staging LDS dead -> repack
    ushort* rp = sm + wv*4096;             // 64 rows x 64 cols per wave
#pragma unroll
    for (int i = 0; i < 4; ++i)
#pragma unroll
        for (int j = 0; j < 4; ++j) {
            const int col = j*16 + cn;
#pragma unroll
            for (int r = 0; r < 4; ++r)
                rp[(i*16 + cr + r)*64 + col] = f2bf(acc[i][j][r]);
        }
    __syncthreads();
#pragma unroll
    for (int k2 = 0; k2 < 8; ++k2) {
        const int row = k2*8 + (ln >> 3);
        uint4 v = *(const uint4*)&rp[row*64 + (ln & 7)*8];
        const int gm = m0 + wm + row;
        const int gn = n0 + wn + (ln & 7)*8;
        if (gn + 8 <= N)
            *(uint4*)(C + (size_t)gm*N + gn) = v;
    }
    if (n0 + 128 > N) {
#pragma unroll
        for (int i = 0; i < 4; ++i) {
            const int mb = m0 + wm + i*16 + cr;
#pragma unroll
            for (int j = 0; j < 4; ++j) {
                const int col = (n0 + wn + j*16 + cn) - (N - 24);
                if (col >= 0 && col < 24) {
                    dtraw[(size_t)(mb+0)*24 + col] = acc[i][j].x;
                    dtraw[(size_t)(mb+1)*24 + col] = acc[i][j].y;
                    dtraw[(size_t)(mb+2)*24 + col] = acc[i][j].z;
                    dtraw[(size_t)(mb+3)*24 + col] = acc[i][j].w;
                }
            }
        }
    }
}

// ---------------- causal depthwise conv1d + bias + silu (bf16 in/out)
__global__ __launch_bounds__(448) void conv_kernel(
    const ushort* __restrict__ zx, const float* __restrict__ conv_w,
    const float* __restrict__ conv_b, ushort* __restrict__ xconv)
{
    const int c4 = threadIdx.x;
    const int bl = blockIdx.x;
    const int l = bl & (SEQL - 1);
    float w[4][4];
#pragma unroll
    for (int j = 0; j < 4; ++j) {
        float4 wr = *(const float4*)(conv_w + (c4*4 + j)*4);
        w[j][0]=wr.x; w[j][1]=wr.y; w[j][2]=wr.z; w[j][3]=wr.w;
    }
    float4 bias = *(const float4*)(conv_b + c4*4);
    float s[4] = {bias.x, bias.y, bias.z, bias.w};
#pragma unroll
    for (int k = 0; k < 4; ++k) {
        const int ls = l - 3 + k;
        if (ls >= 0) {
            ushort4 xv = *(const ushort4*)(zx + (size_t)(bl - 3 + k)*DINPROJ + DINNER + c4*4);
            s[0] = fmaf(bf2f(xv.x), w[0][k], s[0]);
            s[1] = fmaf(bf2f(xv.y), w[1][k], s[1]);
            s[2] = fmaf(bf2f(xv.z), w[2][k], s[2]);
            s[3] = fmaf(bf2f(xv.w), w[3][k], s[3]);
        }
    }
    ushort4 o = make_ushort4(f2bf(siluf_(s[0])), f2bf(siluf_(s[1])),
                             f2bf(siluf_(s[2])), f2bf(siluf_(s[3])));
    *(ushort4*)(xconv + (size_t)bl*CONVDIM + c4*4) = o;
}

// ---------------- dt = softplus(dt+bias); clog = chunk-local inclusive cumsum of A*dt
__global__ __launch_bounds__(128) void dtscan_kernel(
    const float* __restrict__ dtraw, const float* __restrict__ dt_bias,
    const float* __restrict__ A_log, float* __restrict__ dtc, float* __restrict__ clog)
{
    const int c = blockIdx.x, h = blockIdx.y, b = blockIdx.z;
    const int t = threadIdx.x;
    const int bl = b*SEQL + c*Q + t;
    float draw = dtraw[(size_t)bl*24 + h] + dt_bias[h];
    float dtv = softplusf_(draw);
    float la = -expf(A_log[h]) * dtv;
    const int lane = t & 63;
    float v = la;
#pragma unroll
    for (int off = 1; off < 64; off <<= 1) {
        float u = __shfl_up(v, off);
        if (lane >= off) v += u;
    }
    __shared__ float w0tot;
    if (t == 63) w0tot = v;
    __syncthreads();
    if (t >= 64) v += w0tot;
    const int idx = (b*NHEADS + h)*SEQL + c*Q + t;
    dtc[idx] = dtv;
    clog[idx] = v;
}

// ---------------- G[t][s] = C_t . B_s  via MFMA; block covers 64 t x 128 s (bf16 in)
__global__ __launch_bounds__(256) void gcb_mfma(
    const ushort* __restrict__ xconv, ushort* __restrict__ G)
{
    __shared__ __align__(16) ushort Ca[64*32];
    __shared__ __align__(16) ushort Bb[128*32];
    const int thalf = blockIdx.x, c = blockIdx.y, b = blockIdx.z;
    const int tid = threadIdx.x;
    const int wv = tid >> 6, ln = tid & 63;
    const int fr = ln & 15, fq = ln >> 4, fk = fq*8;
    const int bl0 = b*SEQL + c*Q;
    const int th0 = thalf*64;

    const int sat = tid & 63,  sac = (tid >> 6)*8;
    const int sbt = tid & 127, sbh = (tid >> 7)*16;

    f32x4 acc[4][2];
#pragma unroll
    for (int i = 0; i < 4; ++i)
#pragma unroll
        for (int j = 0; j < 2; ++j) acc[i][j] = (f32x4){0.f,0.f,0.f,0.f};

    for (int ks = 0; ks < 4; ++ks) {
        uint4 av = *(const uint4*)(xconv + (size_t)(bl0 + th0 + sat)*CONVDIM + COFF + ks*32 + sac);
        const ushort* br = xconv + (size_t)(bl0 + sbt)*CONVDIM + BOFF + ks*32 + sbh;
        uint4 bv0 = *(const uint4*)br;
        uint4 bv1 = *(const uint4*)(br + 8);
        __syncthreads();
        *(uint4*)&Ca[sat*32 + sac] = av;
        *(uint4*)&Bb[sbt*32 + sbh] = bv0;
        *(uint4*)&Bb[sbt*32 + sbh + 8] = bv1;
        __syncthreads();
        bf16x8 av_[4], bv_[2];
#pragma unroll
        for (int i = 0; i < 4; ++i)
            av_[i] = *(const bf16x8*)&Ca[(i*16 + fr)*32 + fk];
#pragma unroll
        for (int j = 0; j < 2; ++j)
            bv_[j] = *(const bf16x8*)&Bb[(wv*32 + j*16 + fr)*32 + fk];
#pragma unroll
        for (int i = 0; i < 4; ++i)
#pragma unroll
            for (int j = 0; j < 2; ++j)
                acc[i][j] = __builtin_amdgcn_mfma_f32_16x16x32_bf16(av_[i], bv_[j], acc[i][j], 0, 0, 0);
    }
    ushort* gout = G + (size_t)(b*NC + c)*(Q*Q);
#pragma unroll
    for (int i = 0; i < 4; ++i) {
#pragma unroll
        for (int j = 0; j < 2; ++j) {
            const int s = wv*32 + j*16 + fr;
#pragma unroll
            for (int r = 0; r < 4; ++r) {
                const int t = th0 + i*16 + fq*4 + r;
                gout[t*Q + s] = f2bf(acc[i][j][r]);
            }
        }
    }
}

// ---------------- local chunk state via MFMA (bf16 in)
#define ASTR 40
#define BSTR 40
__global__ __launch_bounds__(256) void locstate_mfma(
    const ushort* __restrict__ xconv, const float* __restrict__ dtc,
    const float* __restrict__ clog, ushort* __restrict__ Sloc)
{
    __shared__ __align__(16) ushort Ab[64*ASTR];
    __shared__ __align__(16) ushort Bb[128*BSTR];
    __shared__ float sw[Q];
    const int c = blockIdx.x, h = blockIdx.y, b = blockIdx.z;
    const int tid = threadIdx.x;
    const int wv = tid >> 6, ln = tid & 63;
    const int fr = ln & 15, fq = ln >> 4, fk = fq*8;
    const int bh = b*NHEADS + h;
    const int bl0 = b*SEQL + c*Q;

    if (tid < Q) {
        const float ce = clog[(size_t)bh*SEQL + c*Q + (Q-1)];
        const float cs = clog[(size_t)bh*SEQL + c*Q + tid];
        sw[tid] = dtc[(size_t)bh*SEQL + c*Q + tid] * expf(ce - cs);
    }
    __syncthreads();

    f32x4 acc[4][2];
#pragma unroll
    for (int i = 0; i < 4; ++i)
#pragma unroll
        for (int j = 0; j < 2; ++j) acc[i][j] = (f32x4){0.f,0.f,0.f,0.f};

    const int ap = tid & 63, aoct = tid >> 6;
    const int bn = tid & 127, bhalf = tid >> 7;

    for (int ks = 0; ks < 4; ++ks) {
        float xv[8];
#pragma unroll
        for (int j = 0; j < 8; ++j) {
            const int s = ks*32 + aoct*8 + j;
            xv[j] = bf2f(xconv[(size_t)(bl0 + s)*CONVDIM + h*HEADDIM + ap]) * sw[s];
        }
        ushort bu[16];
#pragma unroll
        for (int j = 0; j < 16; ++j) {
            const int s = ks*32 + bhalf*16 + j;
            bu[j] = xconv[(size_t)(bl0 + s)*CONVDIM + BOFF + bn];
        }
        __syncthreads();
        *(uint4*)&Ab[ap*ASTR + aoct*8] =
            make_uint4(pack2(xv[0],xv[1]), pack2(xv[2],xv[3]),
                       pack2(xv[4],xv[5]), pack2(xv[6],xv[7]));
        *(uint4*)&Bb[bn*BSTR + bhalf*16] =
            make_uint4(packu2(bu[0],bu[1]), packu2(bu[2],bu[3]),
                       packu2(bu[4],bu[5]), packu2(bu[6],bu[7]));
        *(uint4*)&Bb[bn*BSTR + bhalf*16 + 8] =
            make_uint4(packu2(bu[8],bu[9]), packu2(bu[10],bu[11]),
                       packu2(bu[12],bu[13]), packu2(bu[14],bu[15]));
        __syncthreads();
        bf16x8 af[4], bf[2];
#pragma unroll
        for (int i = 0; i < 4; ++i)
            af[i] = *(const bf16x8*)&Ab[(i*16 + fr)*ASTR + fk];
#pragma unroll
        for (int j = 0; j < 2; ++j)
            bf[j] = *(const bf16x8*)&Bb[(wv*32 + j*16 + fr)*BSTR + fk];
#pragma unroll
        for (int i = 0; i < 4; ++i)
#pragma unroll
            for (int j = 0; j < 2; ++j)
                acc[i][j] = __builtin_amdgcn_mfma_f32_16x16x32_bf16(af[i], bf[j], acc[i][j], 0, 0, 0);
    }
    ushort* dst = Sloc + (size_t)((b*NC + c)*NHEADS + h) * (HEADDIM*DSTATE);
#pragma unroll
    for (int i = 0; i < 4; ++i) {
#pragma unroll
        for (int j = 0; j < 2; ++j) {
            const int n = wv*32 + j*16 + fr;
#pragma unroll
            for (int r = 0; r < 4; ++r) {
                const int p = i*16 + fq*4 + r;
                dst[p*DSTATE + n] = f2bf(acc[i][j][r]);
            }
        }
    }
}

// ---------------- in-place sequential prefix over chunk states; 4x p-split
__global__ __launch_bounds__(256) void chunkscan_kernel(
    const float* __restrict__ clog, ushort* __restrict__ S)
{
    const int h = blockIdx.x, b = blockIdx.y, pg = blockIdx.z;
    const int tid = threadIdx.x;
    const int p = pg*16 + (tid >> 4);
    const int n0 = (tid & 15) * 8;
    const int bh = b*NHEADS + h;
    float st[8];
#pragma unroll
    for (int j = 0; j < 8; ++j) st[j] = 0.f;

    for (int c = 0; c < NC; ++c) {
        const float tc = expf(clog[(size_t)bh*SEQL + c*Q + (Q-1)]);
        ushort* base = S + (size_t)((b*NC + c)*NHEADS + h) * (HEADDIM*DSTATE);
        uint4 raw = *(uint4*)(base + p*DSTATE + n0);
        float lv[8];
        unpack8(raw, lv);
        uint4 pre = make_uint4(pack2(st[0],st[1]), pack2(st[2],st[3]),
                               pack2(st[4],st[5]), pack2(st[6],st[7]));
        *(uint4*)(base + p*DSTATE + n0) = pre;
#pragma unroll
        for (int j = 0; j < 8; ++j) st[j] = fmaf(tc, st[j], lv[j]);
    }
}

// ---------------- Y = causal(G.W)@X + exp(clog)*C@Sp^T + D*x  — MFMA, bf16 out
__global__ __launch_bounds__(256) void ychunk_mfma(
    const ushort* __restrict__ xconv, const float* __restrict__ dtc,
    const float* __restrict__ clog, const ushort* __restrict__ G,
    const ushort* __restrict__ Sp, const float* __restrict__ Dv,
    ushort* __restrict__ ybf)
{
    __shared__ __align__(16) ushort smu[8192];  // Ab[128*32] + Bb[64*32]; rp aliases all
    ushort* Ab = smu;
    ushort* Bb = smu + 4096;
    __shared__ float s_clog[Q];
    __shared__ float s_dtc[Q];
    const int c = blockIdx.x, h = blockIdx.y, b = blockIdx.z;
    const int tid = threadIdx.x;
    const int wv = tid >> 6, ln = tid & 63;
    const int bh = b*NHEADS + h;
    const int bl0 = b*SEQL + c*Q;
    const int fr = ln & 15, fq = ln >> 4, fk = fq*8;

    if (tid < Q) {
        s_clog[tid] = clog[(size_t)bh*SEQL + c*Q + tid];
        s_dtc[tid]  = dtc [(size_t)bh*SEQL + c*Q + tid];
    }

    f32x4 acc[2][4];
#pragma unroll
    for (int i = 0; i < 2; ++i)
#pragma unroll
        for (int j = 0; j < 4; ++j) acc[i][j] = (f32x4){0.f,0.f,0.f,0.f};

    const int sgt = tid & 127, sgh = (tid >> 7)*16;
    const int sbp = tid & 63,  sbc = (tid >> 6)*8;
    const ushort* spb = Sp + (size_t)((b*NC + c)*NHEADS + h)*(HEADDIM*DSTATE);

    // phase 1: acc = C @ Sp^T
    for (int ks = 0; ks < 4; ++ks) {
        const ushort* cr = xconv + (size_t)(bl0 + sgt)*CONVDIM + COFF + ks*32 + sgh;
        uint4 cv0 = *(const uint4*)cr;
        uint4 cv1 = *(const uint4*)(cr + 8);
        uint4 sv = *(const uint4*)(spb + sbp*DSTATE + ks*32 + sbc);
        __syncthreads();
        *(uint4*)&Ab[sgt*32 + sgh]     = cv0;
        *(uint4*)&Ab[sgt*32 + sgh + 8] = cv1;
        *(uint4*)&Bb[sbp*32 + sbc] = sv;
        __syncthreads();
        bf16x8 af[2], bv[4];
        af[0] = *(const bf16x8*)&Ab[(wv*32 +      fr)*32 + fk];
        af[1] = *(const bf16x8*)&Ab[(wv*32 + 16 + fr)*32 + fk];
#pragma unroll
        for (int j = 0; j < 4; ++j)
            bv[j] = *(const bf16x8*)&Bb[(j*16 + fr)*32 + fk];
#pragma unroll
        for (int i = 0; i < 2; ++i)
#pragma unroll
            for (int j = 0; j < 4; ++j)
                acc[i][j] = __builtin_amdgcn_mfma_f32_16x16x32_bf16(af[i], bv[j], acc[i][j], 0, 0, 0);
    }
#pragma unroll
    for (int i = 0; i < 2; ++i) {
        const int tb = wv*32 + i*16 + fq*4;
        float e0 = expf(s_clog[tb+0]), e1 = expf(s_clog[tb+1]);
        float e2 = expf(s_clog[tb+2]), e3 = expf(s_clog[tb+3]);
#pragma unroll
        for (int j = 0; j < 4; ++j) {
            acc[i][j].x *= e0; acc[i][j].y *= e1; acc[i][j].z *= e2; acc[i][j].w *= e3;
        }
    }

    // phase 2: acc += (G .* W) @ X (causal)
    const ushort* gp = G + (size_t)(b*NC + c)*(Q*Q);
    for (int ks = 0; ks < 4; ++ks) {
        uint4 g0 = *(const uint4*)(gp + sgt*Q + ks*32 + sgh);
        uint4 g1 = *(const uint4*)(gp + sgt*Q + ks*32 + sgh + 8);
        ushort xu[8];
#pragma unroll
        for (int j = 0; j < 8; ++j)
            xu[j] = xconv[(size_t)(bl0 + ks*32 + sbc + j)*CONVDIM + h*HEADDIM + sbp];
        __syncthreads();
        {
            float gvals[16];
            unpack8(g0, gvals);
            unpack8(g1, gvals + 8);
            const float ct = s_clog[sgt];
            ushort gw[16];
#pragma unroll
            for (int j = 0; j < 16; ++j) {
                const int s = ks*32 + sgh + j;
                float w = 0.f;
                if (s <= sgt) w = s_dtc[s] * expf(ct - s_clog[s]);
                gw[j] = f2bf(gvals[j] * w);
            }
            *(uint4*)&Ab[sgt*32 + sgh] =
                make_uint4(packu2(gw[0],gw[1]), packu2(gw[2],gw[3]),
                           packu2(gw[4],gw[5]), packu2(gw[6],gw[7]));
            *(uint4*)&Ab[sgt*32 + sgh + 8] =
                make_uint4(packu2(gw[8],gw[9]), packu2(gw[10],gw[11]),
                           packu2(gw[12],gw[13]), packu2(gw[14],gw[15]));
            *(uint4*)&Bb[sbp*32 + sbc] =
                make_uint4(packu2(xu[0],xu[1]), packu2(xu[2],xu[3]),
                           packu2(xu[4],xu[5]), packu2(xu[6],xu[7]));
        }
        __syncthreads();
        if (ks <= wv) {
            bf16x8 af[2], bv[4];
            af[0] = *(const bf16x8*)&Ab[(wv*32 +      fr)*32 + fk];
            af[1] = *(const bf16x8*)&Ab[(wv*32 + 16 + fr)*32 + fk];
#pragma unroll
            for (int j = 0; j < 4; ++j)
                bv[j] = *(const bf16x8*)&Bb[(j*16 + fr)*32 + fk];
#pragma unroll
            for (int i = 0; i < 2; ++i)
#pragma unroll
                for (int j = 0; j < 4; ++j)
                    acc[i][j] = __builtin_amdgcn_mfma_f32_16x16x32_bf16(af[i], bv[j], acc[i][j], 0, 0, 0);
        }
    }

    // epilogue: + D*x, repack to bf16 via LDS (aliases Ab/Bb -> barrier first)
    const float Dh = Dv[h];
    __syncthreads();
    ushort* rp = smu;                      // 128 rows x 64 cols
#pragma unroll
    for (int i = 0; i < 2; ++i) {
#pragma unroll
        for (int r = 0; r < 4; ++r) {
            const int t = wv*32 + i*16 + fq*4 + r;
            const ushort* xr = xconv + (size_t)(bl0 + t)*CONVDIM + h*HEADDIM;
#pragma unroll
            for (int j = 0; j < 4; ++j) {
                const int p = j*16 + fr;
                rp[t*64 + p] = f2bf(acc[i][j][r] + Dh * bf2f(xr[p]));
            }
        }
    }
    // readback rows are this wave's own -> no barrier needed
#pragma unroll
    for (int k2 = 0; k2 < 4; ++k2) {
        const int row = wv*32 + k2*8 + (ln >> 3);
        uint4 v = *(const uint4*)&rp[row*64 + (ln & 7)*8];
        *(uint4*)(ybf + (size_t)(bl0 + row)*DINNER + h*HEADDIM + (ln & 7)*8) = v;
    }
}

// ---------------- gated RMSNorm, bf16 in/out (in place on ybf)
__global__ __launch_bounds__(128) void rms_kernel(
    const ushort* __restrict__ zx, const float* __restrict__ norm_w,
    ushort* __restrict__ ybf)
{
    const int row = blockIdx.x;
    const int tid = threadIdx.x;
    const ushort* zr = zx + (size_t)row * DINPROJ;
    ushort* yr = ybf + (size_t)row * DINNER;
    float v[12];
    float ss = 0.f;
#pragma unroll
    for (int i = 0; i < 3; ++i) {
        const int o = (tid + i*128) * 4;
        ushort4 yv = *(const ushort4*)(yr + o);
        ushort4 zv = *(const ushort4*)(zr + o);
        float a = bf2f(yv.x) * siluf_(bf2f(zv.x));
        float b = bf2f(yv.y) * siluf_(bf2f(zv.y));
        float cc = bf2f(yv.z) * siluf_(bf2f(zv.z));
        float d = bf2f(yv.w) * siluf_(bf2f(zv.w));
        v[i*4+0]=a; v[i*4+1]=b; v[i*4+2]=cc; v[i*4+3]=d;
        ss += a*a + b*b + cc*cc + d*d;
    }
#pragma unroll
    for (int off = 1; off < 64; off <<= 1) ss += __shfl_xor(ss, off);
    __shared__ float red[2];
    if ((tid & 63) == 0) red[tid >> 6] = ss;
    __syncthreads();
    const float rstd = rsqrtf((red[0] + red[1]) * (1.f/DINNER) + RMS_EPS);
#pragma unroll
    for (int i = 0; i < 3; ++i) {
        const int o = (tid + i*128) * 4;
        float4 wv = *(const float4*)(norm_w + o);
        ushort4 ov = make_ushort4(f2bf(v[i*4+0]*rstd*wv.x), f2bf(v[i*4+1]*rstd*wv.y),
                                  f2bf(v[i*4+2]*rstd*wv.z), f2bf(v[i*4+3]*rstd*wv.w));
        *(ushort4*)(yr + o) = ov;
    }
}

extern "C" void kernel_launch(void* const* d_in, const int* in_sizes, int n_in,
                              void* d_out, int out_size, void* d_ws, size_t ws_size,
                              hipStream_t stream)
{
    const float* feature    = (const float*)d_in[0];
    const float* in_proj_w  = (const float*)d_in[1];
    const float* conv_w     = (const float*)d_in[2];
    const float* conv_b     = (const float*)d_in[3];
    const float* dt_bias    = (const float*)d_in[4];
    const float* A_log      = (const float*)d_in[5];
    const float* Dvec       = (const float*)d_in[6];
    const float* norm_w     = (const float*)d_in[7];
    const float* out_proj_w = (const float*)d_in[8];
    const float* gate1      = (const float*)d_in[9];
    float* out = (float*)d_out;

    ushort* zx    = (ushort*)d_ws;                              // [8192,3352] bf16
    ushort* xconv = zx + (size_t)BLROWS * DINPROJ;              // [8192,1792] bf16
    ushort* ybf   = xconv + (size_t)BLROWS * CONVDIM;           // [8192,1536] bf16
    float* dtraw  = (float*)(ybf + (size_t)BLROWS * DINNER);    // [8192,24]
    float* dtc    = dtraw + (size_t)BLROWS * 24;
    float* clog   = dtc + (size_t)NB * NHEADS * SEQL;
    ushort* Gbuf  = (ushort*)(clog + (size_t)NB * NHEADS * SEQL);  // 2 MB
    ushort* Sbuf  = Gbuf + (size_t)NB * NC * Q * Q;                // 25 MB
    ushort* Abf    = Gbuf;                            // feature bf16 (dead after gemm1)
    ushort* Wbf_in = Gbuf + (size_t)BLROWS * DMODEL;  // in_proj_w bf16 (dead after gemm1)
    ushort* Wbf_out = zx;                             // out_proj_w bf16 (after rms)

    cast_kernel<<<dim3((BLROWS*DMODEL/4 + 255)/256), 256, 0, stream>>>(feature, Abf, BLROWS*DMODEL/4);
    cast_kernel<<<dim3((DINPROJ*DMODEL/4 + 255)/256), 256, 0, stream>>>(in_proj_w, Wbf_in, DINPROJ*DMODEL/4);
    gemm_mfma_bf16o<<<dim3(27, 64), 256, 0, stream>>>(Abf, Wbf_in, zx, dtraw,
                                                      BLROWS, DINPROJ, DMODEL);
    conv_kernel<<<dim3(BLROWS), 448, 0, stream>>>(zx, conv_w, conv_b, xconv);
    dtscan_kernel<<<dim3(NC, NHEADS, NB), 128, 0, stream>>>(dtraw, dt_bias, A_log, dtc, clog);
    gcb_mfma<<<dim3(2, NC, NB), 256, 0, stream>>>(xconv, Gbuf);
    locstate_mfma<<<dim3(NC, NHEADS, NB), 256, 0, stream>>>(xconv, dtc, clog, Sbuf);
    chunkscan_kernel<<<dim3(NHEADS, NB, 4), 256, 0, stream>>>(clog, Sbuf);
    ychunk_mfma<<<dim3(NC, NHEADS, NB), 256, 0, stream>>>(xconv, dtc, clog, Gbuf, Sbuf, Dvec, ybf);
    rms_kernel<<<dim3(BLROWS), 128, 0, stream>>>(zx, norm_w, ybf);
    cast_kernel<<<dim3((DMODEL*DINNER/4 + 255)/256), 256, 0, stream>>>(out_proj_w, Wbf_out, DMODEL*DINNER/4);
    gemm_mfma<<<dim3(6, 64), 256, 0, stream>>>(ybf, Wbf_out, out,
                                               BLROWS, DMODEL, DINNER, gate1);
}